// Round 1
// baseline (1577.644 us; speedup 1.0000x reference)
//
#include <hip/hip_runtime.h>
#include <hip/hip_bf16.h>

#define N_TOK 4800
#define NH 8
#define HD 32
#define DP 40          // padded vc/T' leading dim (D=38 -> 40)
#define DD 38
#define SCALE 0.17677669529663687f   // 32^-0.5

// ---------------------------------------------------------------------------
// GEMM: y = x @ qkv_w^T  (4800x256 @ 256x768), scatter epilogue into
// q (pre-scaled by SCALE), k, and vc[...,0:32] per-head layouts.
// ---------------------------------------------------------------------------
__global__ __launch_bounds__(256) void qkv_kernel(
    const float* __restrict__ x, const float* __restrict__ w,
    float* __restrict__ qb, float* __restrict__ kb, float* __restrict__ vcb)
{
    __shared__ __align__(16) float al[16][68];
    __shared__ __align__(16) float bl[16][68];
    const int n0 = blockIdx.x * 64, j0 = blockIdx.y * 64;
    const int t = threadIdx.x;
    const int tx = t & 15, ty = t >> 4;
    const int lr = t >> 2, lc = (t & 3) * 4;
    float acc[4][4] = {};
    for (int k0 = 0; k0 < 256; k0 += 16) {
        const float4 av = *(const float4*)&x[(n0 + lr) * 256 + k0 + lc];
        const float4 bv = *(const float4*)&w[(j0 + lr) * 256 + k0 + lc];
        __syncthreads();
        al[lc + 0][lr] = av.x; al[lc + 1][lr] = av.y;
        al[lc + 2][lr] = av.z; al[lc + 3][lr] = av.w;
        bl[lc + 0][lr] = bv.x; bl[lc + 1][lr] = bv.y;
        bl[lc + 2][lr] = bv.z; bl[lc + 3][lr] = bv.w;
        __syncthreads();
#pragma unroll
        for (int kk = 0; kk < 16; ++kk) {
            const float4 a4 = *(const float4*)&al[kk][ty * 4];
            const float4 b4 = *(const float4*)&bl[kk][tx * 4];
            const float af[4] = {a4.x, a4.y, a4.z, a4.w};
            const float bf[4] = {b4.x, b4.y, b4.z, b4.w};
#pragma unroll
            for (int i = 0; i < 4; ++i)
#pragma unroll
                for (int j = 0; j < 4; ++j) acc[i][j] += af[i] * bf[j];
        }
    }
#pragma unroll
    for (int i = 0; i < 4; ++i) {
        const int n = n0 + ty * 4 + i;
#pragma unroll
        for (int j = 0; j < 4; ++j) {
            const int col = j0 + tx * 4 + j;
            const int s = col >> 8, h = (col >> 5) & 7, d = col & 31;
            const float v = acc[i][j];
            if (s == 0)      qb[(size_t)(h * N_TOK + n) * HD + d] = v * SCALE;
            else if (s == 1) kb[(size_t)(h * N_TOK + n) * HD + d] = v;
            else             vcb[(size_t)(h * N_TOK + n) * DP + d] = v;
        }
    }
}

// ---------------------------------------------------------------------------
// Fill vc[..., 32:40] with positional encodings (cols 38,39 zero pad).
// pos = [p3^2, p4^2, p3*p4, p3, p4, 1], p3 = y*240/517, p4 = x*360/517
// ---------------------------------------------------------------------------
__global__ void pos_kernel(float* __restrict__ vc1, float* __restrict__ vc2)
{
    const int n = blockIdx.x * 256 + threadIdx.x;
    if (n >= N_TOK) return;
    const int row = n / 80, col = n % 80;
    const float y = -1.0f + 2.0f * (float)row / 59.0f;
    const float x = -1.0f + 2.0f * (float)col / 79.0f;
    const float p3 = y * (240.0f / 517.0f);
    const float p4 = x * (360.0f / 517.0f);
    const float pv[8] = {p3 * p3, p4 * p4, p3 * p4, p3, p4, 1.0f, 0.0f, 0.0f};
#pragma unroll
    for (int h = 0; h < NH; ++h) {
        const size_t base = (size_t)(h * N_TOK + n) * DP + 32;
#pragma unroll
        for (int p = 0; p < 8; ++p) {
            vc1[base + p] = pv[p];
            vc2[base + p] = pv[p];
        }
    }
}

// ---------------------------------------------------------------------------
// Pass 1: a = Q·K^T (Q pre-scaled); accumulate rs[n] += sum_m exp(a),
// cs[m] += sum_n exp(a) via global atomics. 64x64 tile per block.
// ---------------------------------------------------------------------------
__global__ __launch_bounds__(256) void sums_kernel(
    const float* __restrict__ Q, const float* __restrict__ K,
    float* __restrict__ rs, float* __restrict__ cs)
{
    __shared__ __align__(16) float ql[32][68];
    __shared__ __align__(16) float kl[32][68];
    __shared__ float cps[4][64];
    const int n0 = blockIdx.x * 64, m0 = blockIdx.y * 64, h = blockIdx.z;
    const int t = threadIdx.x;
    const int tx = t & 15, ty = t >> 4;
    const int lr = t >> 2, lc = (t & 3) * 8;
    const float* qbase = Q + (size_t)(h * N_TOK + n0) * HD;
    const float* kbase = K + (size_t)(h * N_TOK + m0) * HD;
    {
        const float4 a0 = *(const float4*)&qbase[lr * HD + lc];
        const float4 a1 = *(const float4*)&qbase[lr * HD + lc + 4];
        const float4 b0 = *(const float4*)&kbase[lr * HD + lc];
        const float4 b1 = *(const float4*)&kbase[lr * HD + lc + 4];
        ql[lc + 0][lr] = a0.x; ql[lc + 1][lr] = a0.y;
        ql[lc + 2][lr] = a0.z; ql[lc + 3][lr] = a0.w;
        ql[lc + 4][lr] = a1.x; ql[lc + 5][lr] = a1.y;
        ql[lc + 6][lr] = a1.z; ql[lc + 7][lr] = a1.w;
        kl[lc + 0][lr] = b0.x; kl[lc + 1][lr] = b0.y;
        kl[lc + 2][lr] = b0.z; kl[lc + 3][lr] = b0.w;
        kl[lc + 4][lr] = b1.x; kl[lc + 5][lr] = b1.y;
        kl[lc + 6][lr] = b1.z; kl[lc + 7][lr] = b1.w;
    }
    __syncthreads();
    float acc[4][4] = {};
#pragma unroll
    for (int d = 0; d < 32; ++d) {
        const float4 q4 = *(const float4*)&ql[d][ty * 4];
        const float4 k4 = *(const float4*)&kl[d][tx * 4];
        const float qf[4] = {q4.x, q4.y, q4.z, q4.w};
        const float kf[4] = {k4.x, k4.y, k4.z, k4.w};
#pragma unroll
        for (int i = 0; i < 4; ++i)
#pragma unroll
            for (int j = 0; j < 4; ++j) acc[i][j] += qf[i] * kf[j];
    }
    float rp[4] = {0.f, 0.f, 0.f, 0.f}, cp[4] = {0.f, 0.f, 0.f, 0.f};
#pragma unroll
    for (int i = 0; i < 4; ++i)
#pragma unroll
        for (int j = 0; j < 4; ++j) {
            const float e = __expf(acc[i][j]);
            rp[i] += e; cp[j] += e;
        }
    // row reduce across tx (16-lane groups inside the wave)
#pragma unroll
    for (int i = 0; i < 4; ++i) {
        rp[i] += __shfl_xor(rp[i], 1);
        rp[i] += __shfl_xor(rp[i], 2);
        rp[i] += __shfl_xor(rp[i], 4);
        rp[i] += __shfl_xor(rp[i], 8);
    }
    if (tx == 0) {
#pragma unroll
        for (int i = 0; i < 4; ++i)
            atomicAdd(&rs[(size_t)h * N_TOK + n0 + ty * 4 + i], rp[i]);
    }
    // col reduce across ty groups within wave, then across the 4 waves in LDS
#pragma unroll
    for (int j = 0; j < 4; ++j) {
        cp[j] += __shfl_xor(cp[j], 16);
        cp[j] += __shfl_xor(cp[j], 32);
    }
    const int wave = t >> 6, lane = t & 63;
    if (lane < 16) {
#pragma unroll
        for (int j = 0; j < 4; ++j) cps[wave][tx * 4 + j] = cp[j];
    }
    __syncthreads();
    if (t < 64) {
        const float s = cps[0][t] + cps[1][t] + cps[2][t] + cps[3][t];
        atomicAdd(&cs[(size_t)h * N_TOK + m0 + t], s);
    }
}

// ---------------------------------------------------------------------------
// Pass 2: T'[n,c] = sum_m exp(2a[n,m]) * u[m] * vc[m,c]; recomputes a.
// Block: 64 n-rows, 25 m-tiles (grid.y=3 chunks), accumulates via atomics.
// ---------------------------------------------------------------------------
__global__ __launch_bounds__(256) void tprime_kernel(
    const float* __restrict__ Q, const float* __restrict__ K,
    const float* __restrict__ VC, const float* __restrict__ cs,
    float* __restrict__ T)
{
    __shared__ __align__(16) float ql[32][68];
    __shared__ __align__(16) float kl[32][68];
    __shared__ __align__(16) float plT[64][68];   // plT[m][n] = exp(2a)*u[m]
    __shared__ __align__(16) float vcl[64 * DP];
    __shared__ float ul[64];
    const int n0 = blockIdx.x * 64, h = blockIdx.z;
    const int mt0 = blockIdx.y * 25;
    const int t = threadIdx.x;
    const int tx = t & 15, ty = t >> 4;
    const int lr = t >> 2, lc = (t & 3) * 8;
    const float* qbase = Q + (size_t)(h * N_TOK + n0) * HD;
    {
        const float4 a0 = *(const float4*)&qbase[lr * HD + lc];
        const float4 a1 = *(const float4*)&qbase[lr * HD + lc + 4];
        ql[lc + 0][lr] = a0.x; ql[lc + 1][lr] = a0.y;
        ql[lc + 2][lr] = a0.z; ql[lc + 3][lr] = a0.w;
        ql[lc + 4][lr] = a1.x; ql[lc + 5][lr] = a1.y;
        ql[lc + 6][lr] = a1.z; ql[lc + 7][lr] = a1.w;
    }
    const bool act = t < 160;
    const int r0 = (t / 10) * 4;    // only meaningful when act
    const int c0 = (t % 10) * 4;
    float accT[4][4] = {};
    for (int mt = 0; mt < 25; ++mt) {
        const int m0 = (mt0 + mt) * 64;
        __syncthreads();   // previous iter readers done (also orders ql stores)
        const float* kbase = K + (size_t)(h * N_TOK + m0) * HD;
        {
            const float4 b0 = *(const float4*)&kbase[lr * HD + lc];
            const float4 b1 = *(const float4*)&kbase[lr * HD + lc + 4];
            kl[lc + 0][lr] = b0.x; kl[lc + 1][lr] = b0.y;
            kl[lc + 2][lr] = b0.z; kl[lc + 3][lr] = b0.w;
            kl[lc + 4][lr] = b1.x; kl[lc + 5][lr] = b1.y;
            kl[lc + 6][lr] = b1.z; kl[lc + 7][lr] = b1.w;
        }
        const float* vcbase = VC + (size_t)(h * N_TOK + m0) * DP;
        for (int e = t; e < 640; e += 256)
            *(float4*)&vcl[e * 4] = *(const float4*)&vcbase[e * 4];
        if (t < 64) ul[t] = 1.0f / cs[(size_t)h * N_TOK + m0 + t];
        __syncthreads();
        // phase A: 64x64 scores, write P' transposed
        float acc[4][4] = {};
#pragma unroll
        for (int d = 0; d < 32; ++d) {
            const float4 q4 = *(const float4*)&ql[d][ty * 4];
            const float4 k4 = *(const float4*)&kl[d][tx * 4];
            const float qf[4] = {q4.x, q4.y, q4.z, q4.w};
            const float kf[4] = {k4.x, k4.y, k4.z, k4.w};
#pragma unroll
            for (int i = 0; i < 4; ++i)
#pragma unroll
                for (int j = 0; j < 4; ++j) acc[i][j] += qf[i] * kf[j];
        }
#pragma unroll
        for (int j = 0; j < 4; ++j) {
            const int c = tx * 4 + j;
            const float u = ul[c];
#pragma unroll
            for (int i = 0; i < 4; ++i)
                plT[c][ty * 4 + i] = __expf(2.0f * acc[i][j]) * u;
        }
        __syncthreads();
        // phase B: T'_tile += P'^T-outer-products with vc rows
        if (act) {
#pragma unroll 4
            for (int mm = 0; mm < 64; ++mm) {
                const float4 p4 = *(const float4*)&plT[mm][r0];
                const float4 v4 = *(const float4*)&vcl[mm * DP + c0];
                const float pf[4] = {p4.x, p4.y, p4.z, p4.w};
                const float vf[4] = {v4.x, v4.y, v4.z, v4.w};
#pragma unroll
                for (int i = 0; i < 4; ++i)
#pragma unroll
                    for (int j = 0; j < 4; ++j) accT[i][j] += pf[i] * vf[j];
            }
        }
    }
    if (act) {
#pragma unroll
        for (int i = 0; i < 4; ++i)
#pragma unroll
            for (int j = 0; j < 4; ++j)
                atomicAdd(&T[(size_t)(h * N_TOK + n0 + r0 + i) * DP + c0 + j],
                          accT[i][j]);
    }
}

// ---------------------------------------------------------------------------
// f[h,c,d] = sum_n (vc[n,c]/rs[n]) * T'[n,d]  -- partial per 64-row chunk.
// ---------------------------------------------------------------------------
__global__ __launch_bounds__(256) void fgemm_kernel(
    const float* __restrict__ VC, const float* __restrict__ rs,
    const float* __restrict__ T, float* __restrict__ f)
{
    __shared__ __align__(16) float wvcl[64 * DP];
    __shared__ __align__(16) float tl[64 * DP];
    __shared__ float wl[64];
    const int h = blockIdx.x, n0 = blockIdx.y * 64;
    const int t = threadIdx.x;
    if (t < 64) wl[t] = 1.0f / rs[(size_t)h * N_TOK + n0 + t];
    __syncthreads();
    const float* vcbase = VC + (size_t)(h * N_TOK + n0) * DP;
    const float* tbase = T + (size_t)(h * N_TOK + n0) * DP;
    for (int e = t; e < 64 * DP; e += 256) {
        wvcl[e] = vcbase[e] * wl[e / DP];
        tl[e] = tbase[e];
    }
    __syncthreads();
    for (int p = t; p < DD * DD; p += 256) {
        const int c = p / DD, d = p % DD;
        float s = 0.f;
#pragma unroll 8
        for (int n = 0; n < 64; ++n) s += wvcl[n * DP + c] * tl[n * DP + d];
        atomicAdd(&f[(size_t)(h * DD + c) * DP + d], s);
    }
}

// ---------------------------------------------------------------------------
// out[d,e] = sum_j f[j,d] * proj_w[e,j] + proj_b[e], j = h*38+c (304 total)
// ---------------------------------------------------------------------------
__global__ __launch_bounds__(256) void out_kernel(
    const float* __restrict__ f, const float* __restrict__ pw,
    const float* __restrict__ pb, float* __restrict__ out)
{
    __shared__ __align__(16) float flds[304];
    const int d = blockIdx.x, t = threadIdx.x;
    for (int j = t; j < 304; j += 256) flds[j] = f[(size_t)j * DP + d];
    __syncthreads();
    float acc = pb[t];
    const float* pwrow = pw + (size_t)t * 304;
#pragma unroll 4
    for (int j = 0; j < 304; j += 4) {
        const float4 p4 = *(const float4*)&pwrow[j];
        const float4 f4 = *(const float4*)&flds[j];
        acc += p4.x * f4.x + p4.y * f4.y + p4.z * f4.z + p4.w * f4.w;
    }
    out[(size_t)d * 256 + t] = acc;
}

extern "C" void kernel_launch(void* const* d_in, const int* in_sizes, int n_in,
                              void* d_out, int out_size, void* d_ws, size_t ws_size,
                              hipStream_t stream)
{
    const float* x1 = (const float*)d_in[0];
    const float* x2 = (const float*)d_in[1];
    const float* qkv_w = (const float*)d_in[2];
    const float* proj_w = (const float*)d_in[3];
    const float* proj_b = (const float*)d_in[4];
    float* out = (float*)d_out;

    const size_t QSZ = (size_t)NH * N_TOK * HD;   // 1,228,800
    const size_t VSZ = (size_t)NH * N_TOK * DP;   // 1,536,000
    const size_t SSZ = (size_t)NH * N_TOK;        //    38,400
    const size_t FSZ = (size_t)NH * DD * DP;      //    12,160

    float* q1 = (float*)d_ws;
    float* k1 = q1 + QSZ;
    float* q2 = k1 + QSZ;
    float* k2 = q2 + QSZ;
    float* vc1 = k2 + QSZ;
    float* vc2 = vc1 + VSZ;
    float* rs1 = vc2 + VSZ;   // zeroed region starts here
    float* cs1 = rs1 + SSZ;
    float* rs2 = cs1 + SSZ;
    float* cs2 = rs2 + SSZ;
    float* T1 = cs2 + SSZ;
    float* T2 = T1 + VSZ;
    float* f1 = T2 + VSZ;
    float* f2 = f1 + FSZ;
    const size_t zbytes = (4 * SSZ + 2 * VSZ + 2 * FSZ) * sizeof(float);
    hipMemsetAsync(rs1, 0, zbytes, stream);

    const dim3 gq(75, 12);
    qkv_kernel<<<gq, 256, 0, stream>>>(x1, qkv_w, q1, k1, vc1);
    qkv_kernel<<<gq, 256, 0, stream>>>(x2, qkv_w, q2, k2, vc2);
    pos_kernel<<<19, 256, 0, stream>>>(vc1, vc2);

    const dim3 gs(75, 75, 8);
    const dim3 gt(75, 3, 8);
    const dim3 gf(8, 75);
    // fundamental_1 = f(q2, k1, vc1) -> second half of out
    sums_kernel<<<gs, 256, 0, stream>>>(q2, k1, rs1, cs1);
    tprime_kernel<<<gt, 256, 0, stream>>>(q2, k1, vc1, cs1, T1);
    fgemm_kernel<<<gf, 256, 0, stream>>>(vc1, rs1, T1, f1);
    out_kernel<<<38, 256, 0, stream>>>(f1, proj_w, proj_b, out + DD * 256);
    // fundamental_2 = f(q1, k2, vc2) -> first half of out
    sums_kernel<<<gs, 256, 0, stream>>>(q1, k2, rs2, cs2);
    tprime_kernel<<<gt, 256, 0, stream>>>(q1, k2, vc2, cs2, T2);
    fgemm_kernel<<<gf, 256, 0, stream>>>(vc2, rs2, T2, f2);
    out_kernel<<<38, 256, 0, stream>>>(f2, proj_w, proj_b, out);
}

// Round 2
// 586.043 us; speedup vs baseline: 2.6920x; 2.6920x over previous
//
#include <hip/hip_runtime.h>
#include <stdint.h>

#define N_TOK 4800
#define NH 8
#define HD 32
#define DP 40          // padded vc/T' leading dim (D=38 -> 40)
#define DD 38
#define VCT_ROWS 64    // transposed-VC padded row count (d-dim) for 2x 32-wide MFMA tiles
#define SCALE 0.17677669529663687f   // 32^-0.5

typedef float f32x16 __attribute__((ext_vector_type(16)));
typedef short s8v __attribute__((ext_vector_type(8)));
typedef int i2v __attribute__((ext_vector_type(2)));

__device__ __forceinline__ unsigned short f2bf(float x) {
    union { float f; uint32_t u; } v; v.f = x;
    uint32_t r = v.u + 0x7FFFu + ((v.u >> 16) & 1u);
    return (unsigned short)(r >> 16);
}
__device__ __forceinline__ float bf2f(unsigned short h) {
    union { uint32_t u; float f; } v; v.u = ((uint32_t)h) << 16;
    return v.f;
}
__device__ __forceinline__ int cvtpk(float lo, float hi) {
    int r;
    asm("v_cvt_pk_bf16_f32 %0, %1, %2" : "=v"(r) : "v"(lo), "v"(hi));
    return r;
}
__device__ __forceinline__ s8v mk_s8(int a, int b, int c, int d) {
    union { int i[4]; s8v s; } u;
    u.i[0] = a; u.i[1] = b; u.i[2] = c; u.i[3] = d;
    return u.s;
}

#define MFMA(a, b, c) __builtin_amdgcn_mfma_f32_32x32x16_bf16((a), (b), (c), 0, 0, 0)

// ---------------------------------------------------------------------------
// split fp32 -> bf16 hi + bf16 lo (x ~= hi + lo, rel err ~2^-16), x4 vectorized
// ---------------------------------------------------------------------------
__global__ __launch_bounds__(256) void split_kernel(
    const float* __restrict__ src, unsigned short* __restrict__ hi,
    unsigned short* __restrict__ lo, int n4)
{
    const int i = blockIdx.x * 256 + threadIdx.x;
    if (i >= n4) return;
    const float4 v = ((const float4*)src)[i];
    ushort4 h, l;
    h.x = f2bf(v.x); l.x = f2bf(v.x - bf2f(h.x));
    h.y = f2bf(v.y); l.y = f2bf(v.y - bf2f(h.y));
    h.z = f2bf(v.z); l.z = f2bf(v.z - bf2f(h.z));
    h.w = f2bf(v.w); l.w = f2bf(v.w - bf2f(h.w));
    ((ushort4*)hi)[i] = h;
    ((ushort4*)lo)[i] = l;
}

// ---------------------------------------------------------------------------
// QKV GEMM via split-bf16 MFMA: y = x @ qkv_w^T (4800x256 @ 256x768),
// scatter epilogue into q (pre-scaled), k, vc[...,0:32] per-head fp32 layouts.
// 2 waves/block, each wave one 32x32 output tile. grid (75, 24).
// ---------------------------------------------------------------------------
__global__ __launch_bounds__(128) void qkv_mfma_kernel(
    const unsigned short* __restrict__ xh, const unsigned short* __restrict__ xl,
    const unsigned short* __restrict__ wh, const unsigned short* __restrict__ wl,
    float* __restrict__ qb, float* __restrict__ kb, float* __restrict__ vcb)
{
    const int lane = threadIdx.x & 63;
    const int wid = threadIdx.x >> 6;
    const int n0 = blockIdx.x * 64 + wid * 32;
    const int j0 = blockIdx.y * 32;
    const int lr = lane & 31, hi5 = lane >> 5;
    const unsigned short* xhp = xh + (n0 + lr) * 256 + 8 * hi5;
    const unsigned short* xlp = xl + (n0 + lr) * 256 + 8 * hi5;
    const unsigned short* whp = wh + (j0 + lr) * 256 + 8 * hi5;
    const unsigned short* wlp = wl + (j0 + lr) * 256 + 8 * hi5;
    f32x16 acc = {};
#pragma unroll 4
    for (int c = 0; c < 16; ++c) {
        const s8v aH = *(const s8v*)(xhp + 16 * c);
        const s8v aL = *(const s8v*)(xlp + 16 * c);
        const s8v bH = *(const s8v*)(whp + 16 * c);
        const s8v bL = *(const s8v*)(wlp + 16 * c);
        acc = MFMA(aH, bH, acc);
        acc = MFMA(aH, bL, acc);
        acc = MFMA(aL, bH, acc);
    }
    const int s = j0 >> 8, h = (j0 >> 5) & 7, d = lr;
    const float mult = (s == 0) ? SCALE : 1.0f;
#pragma unroll
    for (int r = 0; r < 16; ++r) {
        const int n = n0 + (r & 3) + 8 * (r >> 2) + 4 * hi5;
        const float v = acc[r] * mult;
        if (s == 2)      vcb[(h * N_TOK + n) * DP + d] = v;
        else if (s == 0) qb[(h * N_TOK + n) * HD + d] = v;
        else             kb[(h * N_TOK + n) * HD + d] = v;
    }
}

// ---------------------------------------------------------------------------
// Fill vc[..., 32:40] with positional encodings (cols 38,39 zero pad).
// ---------------------------------------------------------------------------
__global__ void pos_kernel(float* __restrict__ vc1, float* __restrict__ vc2)
{
    const int n = blockIdx.x * 256 + threadIdx.x;
    if (n >= N_TOK) return;
    const int row = n / 80, col = n % 80;
    const float y = -1.0f + 2.0f * (float)row / 59.0f;
    const float x = -1.0f + 2.0f * (float)col / 79.0f;
    const float p3 = y * (240.0f / 517.0f);
    const float p4 = x * (360.0f / 517.0f);
    const float pv[8] = {p3 * p3, p4 * p4, p3 * p4, p3, p4, 1.0f, 0.0f, 0.0f};
#pragma unroll
    for (int h = 0; h < NH; ++h) {
        const size_t base = (size_t)(h * N_TOK + n) * DP + 32;
#pragma unroll
        for (int p = 0; p < 8; ++p) {
            vc1[base + p] = pv[p];
            vc2[base + p] = pv[p];
        }
    }
}

// ---------------------------------------------------------------------------
// vc fp32 [h][4800][40] -> VCT bf16 [h][64][4800] (rows 40..63 zero).
// grid (75, 8), 256 threads.
// ---------------------------------------------------------------------------
__global__ __launch_bounds__(256) void vct_kernel(
    const float* __restrict__ vc, unsigned short* __restrict__ vct)
{
    __shared__ float vl[64][41];
    const int m0 = blockIdx.x * 64;
    const int h = blockIdx.y;
    const int t = threadIdx.x;
    const float* vcbase = vc + (size_t)(h * N_TOK + m0) * DP;
    for (int e = t; e < 64 * DP; e += 256) vl[e / DP][e % DP] = vcbase[e];
    __syncthreads();
    const int j = t & 63, dg = t >> 6;
    unsigned short* obase = vct + (size_t)h * VCT_ROWS * N_TOK + m0 + j;
#pragma unroll
    for (int i = 0; i < 16; ++i) {
        const int d = dg * 16 + i;
        const float v = (d < DP) ? vl[j][d] : 0.0f;
        obase[(size_t)d * N_TOK] = f2bf(v);
    }
}

// ---------------------------------------------------------------------------
// Pass 1: S = Q.K^T via split-bf16 MFMA (normal orientation: col=lane=m).
// cs[m] += sum_n exp(S) -- in-lane reduce over regs, atomic once per wave.
// grid (75 m-blocks, 5 n-chunks, 8 heads), 128 threads (2 waves).
// ---------------------------------------------------------------------------
__global__ __launch_bounds__(128) void cs_kernel(
    const unsigned short* __restrict__ qh, const unsigned short* __restrict__ ql,
    const unsigned short* __restrict__ kh, const unsigned short* __restrict__ kl,
    float* __restrict__ cs)
{
    const int lane = threadIdx.x & 63;
    const int wid = threadIdx.x >> 6;
    const int h = blockIdx.z;
    const int m0 = blockIdx.x * 64 + wid * 32;
    const int lr = lane & 31, hi5 = lane >> 5;
    const int hbase = h * N_TOK;
    const unsigned short* khp = kh + (hbase + m0 + lr) * HD + 8 * hi5;
    const unsigned short* klp = kl + (hbase + m0 + lr) * HD + 8 * hi5;
    const s8v bH0 = *(const s8v*)(khp);
    const s8v bH1 = *(const s8v*)(khp + 16);
    const s8v bL0 = *(const s8v*)(klp);
    const s8v bL1 = *(const s8v*)(klp + 16);
    float csacc = 0.f;
    const int nt0 = blockIdx.y * 30;
    for (int it = 0; it < 30; ++it) {
        const int n0 = (nt0 + it) * 32;
        const unsigned short* qhp = qh + (hbase + n0 + lr) * HD + 8 * hi5;
        const unsigned short* qlp = ql + (hbase + n0 + lr) * HD + 8 * hi5;
        const s8v aH0 = *(const s8v*)(qhp);
        const s8v aH1 = *(const s8v*)(qhp + 16);
        const s8v aL0 = *(const s8v*)(qlp);
        const s8v aL1 = *(const s8v*)(qlp + 16);
        f32x16 acc = {};
        acc = MFMA(aH0, bH0, acc);
        acc = MFMA(aH1, bH1, acc);
        acc = MFMA(aL0, bH0, acc);
        acc = MFMA(aL1, bH1, acc);
        acc = MFMA(aH0, bL0, acc);
        acc = MFMA(aH1, bL1, acc);
#pragma unroll
        for (int r = 0; r < 16; ++r) csacc += __expf(acc[r]);
    }
    csacc += __shfl_xor(csacc, 32);
    if (lane < 32) atomicAdd(&cs[hbase + m0 + lane], csacc);
}

__global__ void inv_kernel(const float* __restrict__ cs, float* __restrict__ u, int n)
{
    const int i = blockIdx.x * 256 + threadIdx.x;
    if (i < n) u[i] = 1.0f / cs[i];
}

// ---------------------------------------------------------------------------
// Pass 2: S^T = K.Q^T via split-bf16 MFMA (col=lane=n). Per tile:
// e=exp(S), rs partial in-lane; P' = e*e*u[m] packed to bf16 in-register
// (cvt_pk + permlane32_swap) as A-fragments; T'[n,d] += P'.VCT via MFMA.
// grid (75 n-blocks, 5 m-chunks, 8 heads), 128 threads (2 waves).
// ---------------------------------------------------------------------------
__global__ __launch_bounds__(128) void tprime_mfma_kernel(
    const unsigned short* __restrict__ qh, const unsigned short* __restrict__ ql,
    const unsigned short* __restrict__ kh, const unsigned short* __restrict__ kl,
    const unsigned short* __restrict__ vct, const float* __restrict__ u,
    float* __restrict__ rs, float* __restrict__ T)
{
    const int lane = threadIdx.x & 63;
    const int wid = threadIdx.x >> 6;
    const int h = blockIdx.z;
    const int n0 = blockIdx.x * 64 + wid * 32;
    const int lr = lane & 31, hi5 = lane >> 5;
    const int hbase = h * N_TOK;
    // Q as B operand (hoisted across the m-loop)
    const unsigned short* qhp = qh + (hbase + n0 + lr) * HD + 8 * hi5;
    const unsigned short* qlp = ql + (hbase + n0 + lr) * HD + 8 * hi5;
    const s8v bH0 = *(const s8v*)(qhp);
    const s8v bH1 = *(const s8v*)(qhp + 16);
    const s8v bL0 = *(const s8v*)(qlp);
    const s8v bL1 = *(const s8v*)(qlp + 16);
    const unsigned short* vbase = vct + (size_t)h * VCT_ROWS * N_TOK;
    f32x16 t0 = {}, t1 = {};
    float rsacc = 0.f;
    const int mt0 = blockIdx.y * 30;
    for (int it = 0; it < 30; ++it) {
        const int m0 = (mt0 + it) * 32;
        const unsigned short* khp = kh + (hbase + m0 + lr) * HD + 8 * hi5;
        const unsigned short* klp = kl + (hbase + m0 + lr) * HD + 8 * hi5;
        const s8v aH0 = *(const s8v*)(khp);
        const s8v aH1 = *(const s8v*)(khp + 16);
        const s8v aL0 = *(const s8v*)(klp);
        const s8v aL1 = *(const s8v*)(klp + 16);
        f32x16 s = {};
        s = MFMA(aH0, bH0, s);
        s = MFMA(aH1, bH1, s);
        s = MFMA(aL0, bH0, s);
        s = MFMA(aL1, bH1, s);
        s = MFMA(aH0, bL0, s);
        s = MFMA(aH1, bL1, s);
        // u for this lane's 16 m-rows: m = m0 + 8g + 4*hi5 + (0..3)
        const float4 u0 = *(const float4*)&u[hbase + m0 + 0 + 4 * hi5];
        const float4 u1 = *(const float4*)&u[hbase + m0 + 8 + 4 * hi5];
        const float4 u2 = *(const float4*)&u[hbase + m0 + 16 + 4 * hi5];
        const float4 u3 = *(const float4*)&u[hbase + m0 + 24 + 4 * hi5];
        const float ue[16] = {u0.x, u0.y, u0.z, u0.w, u1.x, u1.y, u1.z, u1.w,
                              u2.x, u2.y, u2.z, u2.w, u3.x, u3.y, u3.z, u3.w};
        float p[16];
#pragma unroll
        for (int r = 0; r < 16; ++r) {
            const float e = __expf(s[r]);
            rsacc += e;
            p[r] = e * e * ue[r];
        }
        // pack P' to bf16 A-fragments in-register (chunk = 16 k-values)
        const int L0 = cvtpk(p[0], p[1]),  L1 = cvtpk(p[2], p[3]);
        const int H0 = cvtpk(p[4], p[5]),  H1 = cvtpk(p[6], p[7]);
        const int L2 = cvtpk(p[8], p[9]),  L3 = cvtpk(p[10], p[11]);
        const int H2 = cvtpk(p[12], p[13]), H3 = cvtpk(p[14], p[15]);
        const i2v s0 = __builtin_amdgcn_permlane32_swap(L0, H0, false, false);
        const i2v s1 = __builtin_amdgcn_permlane32_swap(L1, H1, false, false);
        const i2v s2 = __builtin_amdgcn_permlane32_swap(L2, H2, false, false);
        const i2v s3 = __builtin_amdgcn_permlane32_swap(L3, H3, false, false);
        const s8v pa0 = mk_s8(s0[0], s1[0], s0[1], s1[1]);   // k = m0+0..15
        const s8v pa1 = mk_s8(s2[0], s3[0], s2[1], s3[1]);   // k = m0+16..31
        // VCT B-fragments: row d = lane&31 (+32 for dtile1), k contiguous in m
        const unsigned short* vp = vbase + (size_t)lr * N_TOK + m0 + 8 * hi5;
        const s8v v00 = *(const s8v*)(vp);
        const s8v v01 = *(const s8v*)(vp + 16);
        const s8v v10 = *(const s8v*)(vp + (size_t)32 * N_TOK);
        const s8v v11 = *(const s8v*)(vp + (size_t)32 * N_TOK + 16);
        t0 = MFMA(pa0, v00, t0);
        t0 = MFMA(pa1, v01, t0);
        t1 = MFMA(pa0, v10, t1);
        t1 = MFMA(pa1, v11, t1);
    }
    rsacc += __shfl_xor(rsacc, 32);
    if (lane < 32) atomicAdd(&rs[hbase + n0 + lane], rsacc);
#pragma unroll
    for (int r = 0; r < 16; ++r) {
        const int n = n0 + (r & 3) + 8 * (r >> 2) + 4 * hi5;
        atomicAdd(&T[(size_t)(hbase + n) * DP + lr], t0[r]);
    }
    if (lr < 8) {
#pragma unroll
        for (int r = 0; r < 16; ++r) {
            const int n = n0 + (r & 3) + 8 * (r >> 2) + 4 * hi5;
            atomicAdd(&T[(size_t)(hbase + n) * DP + 32 + lr], t1[r]);
        }
    }
}

// ---------------------------------------------------------------------------
// f[h,c,d] = sum_n (vc[n,c]/rs[n]) * T'[n,d]  -- partial per 64-row chunk.
// ---------------------------------------------------------------------------
__global__ __launch_bounds__(256) void fgemm_kernel(
    const float* __restrict__ VC, const float* __restrict__ rs,
    const float* __restrict__ T, float* __restrict__ f)
{
    __shared__ __align__(16) float wvcl[64 * DP];
    __shared__ __align__(16) float tl[64 * DP];
    __shared__ float wl[64];
    const int h = blockIdx.x, n0 = blockIdx.y * 64;
    const int t = threadIdx.x;
    if (t < 64) wl[t] = 1.0f / rs[(size_t)h * N_TOK + n0 + t];
    __syncthreads();
    const float* vcbase = VC + (size_t)(h * N_TOK + n0) * DP;
    const float* tbase = T + (size_t)(h * N_TOK + n0) * DP;
    for (int e = t; e < 64 * DP; e += 256) {
        wvcl[e] = vcbase[e] * wl[e / DP];
        tl[e] = tbase[e];
    }
    __syncthreads();
    for (int p = t; p < DD * DD; p += 256) {
        const int c = p / DD, d = p % DD;
        float s = 0.f;
#pragma unroll 8
        for (int n = 0; n < 64; ++n) s += wvcl[n * DP + c] * tl[n * DP + d];
        atomicAdd(&f[(size_t)(h * DD + c) * DP + d], s);
    }
}

// ---------------------------------------------------------------------------
// out[d,e] = sum_j f[j,d] * proj_w[e,j] + proj_b[e], j = h*38+c (304 total)
// ---------------------------------------------------------------------------
__global__ __launch_bounds__(256) void out_kernel(
    const float* __restrict__ f, const float* __restrict__ pw,
    const float* __restrict__ pb, float* __restrict__ out)
{
    __shared__ __align__(16) float flds[304];
    const int d = blockIdx.x, t = threadIdx.x;
    for (int j = t; j < 304; j += 256) flds[j] = f[(size_t)j * DP + d];
    __syncthreads();
    float acc = pb[t];
    const float* pwrow = pw + (size_t)t * 304;
#pragma unroll 4
    for (int j = 0; j < 304; j += 4) {
        const float4 p4 = *(const float4*)&pwrow[j];
        const float4 f4 = *(const float4*)&flds[j];
        acc += p4.x * f4.x + p4.y * f4.y + p4.z * f4.z + p4.w * f4.w;
    }
    out[(size_t)d * 256 + t] = acc;
}

extern "C" void kernel_launch(void* const* d_in, const int* in_sizes, int n_in,
                              void* d_out, int out_size, void* d_ws, size_t ws_size,
                              hipStream_t stream)
{
    const float* x1 = (const float*)d_in[0];
    const float* x2 = (const float*)d_in[1];
    const float* qkv_w = (const float*)d_in[2];
    const float* proj_w = (const float*)d_in[3];
    const float* proj_b = (const float*)d_in[4];
    float* out = (float*)d_out;

    const size_t QSZ = (size_t)NH * N_TOK * HD;          // 1,228,800
    const size_t VSZ = (size_t)NH * N_TOK * DP;          // 1,536,000
    const size_t SSZ = (size_t)NH * N_TOK;               //    38,400
    const size_t FSZ = (size_t)NH * DD * DP;             //    12,160
    const size_t XSZ = (size_t)N_TOK * 256;              // 1,228,800
    const size_t WSZ = (size_t)768 * 256;                //   196,608
    const size_t VTSZ = (size_t)NH * VCT_ROWS * N_TOK;   // 2,457,600

    // fp32 region
    float* q1 = (float*)d_ws;
    float* k1 = q1 + QSZ;
    float* q2 = k1 + QSZ;
    float* k2 = q2 + QSZ;
    float* vc1 = k2 + QSZ;
    float* vc2 = vc1 + VSZ;
    float* rs1 = vc2 + VSZ;   // zeroed region starts here
    float* cs1 = rs1 + SSZ;
    float* rs2 = cs1 + SSZ;
    float* cs2 = rs2 + SSZ;
    float* T1 = cs2 + SSZ;
    float* T2 = T1 + VSZ;
    float* f1 = T2 + VSZ;
    float* f2 = f1 + FSZ;     // zeroed region ends at f2 + FSZ
    float* u1 = f2 + FSZ;
    float* u2 = u1 + SSZ;
    // bf16 region
    unsigned short* xh1 = (unsigned short*)(u2 + SSZ);
    unsigned short* xl1 = xh1 + XSZ;
    unsigned short* xh2 = xl1 + XSZ;
    unsigned short* xl2 = xh2 + XSZ;
    unsigned short* wh = xl2 + XSZ;
    unsigned short* wl = wh + WSZ;
    unsigned short* qh1 = wl + WSZ;
    unsigned short* ql1 = qh1 + QSZ;
    unsigned short* kh1 = ql1 + QSZ;
    unsigned short* kl1 = kh1 + QSZ;
    unsigned short* qh2 = kl1 + QSZ;
    unsigned short* ql2 = qh2 + QSZ;
    unsigned short* kh2 = ql2 + QSZ;
    unsigned short* kl2 = kh2 + QSZ;
    unsigned short* vct1 = kl2 + QSZ;
    unsigned short* vct2 = vct1 + VTSZ;

    const size_t zbytes = (4 * SSZ + 2 * VSZ + 2 * FSZ) * sizeof(float);
    hipMemsetAsync(rs1, 0, zbytes, stream);

    split_kernel<<<1200, 256, 0, stream>>>(x1, xh1, xl1, (int)(XSZ / 4));
    split_kernel<<<1200, 256, 0, stream>>>(x2, xh2, xl2, (int)(XSZ / 4));
    split_kernel<<<192, 256, 0, stream>>>(qkv_w, wh, wl, (int)(WSZ / 4));

    qkv_mfma_kernel<<<dim3(75, 24), 128, 0, stream>>>(xh1, xl1, wh, wl, q1, k1, vc1);
    qkv_mfma_kernel<<<dim3(75, 24), 128, 0, stream>>>(xh2, xl2, wh, wl, q2, k2, vc2);
    pos_kernel<<<19, 256, 0, stream>>>(vc1, vc2);

    split_kernel<<<1200, 256, 0, stream>>>(q1, qh1, ql1, (int)(QSZ / 4));
    split_kernel<<<1200, 256, 0, stream>>>(k1, kh1, kl1, (int)(QSZ / 4));
    split_kernel<<<1200, 256, 0, stream>>>(q2, qh2, ql2, (int)(QSZ / 4));
    split_kernel<<<1200, 256, 0, stream>>>(k2, kh2, kl2, (int)(QSZ / 4));
    vct_kernel<<<dim3(75, 8), 256, 0, stream>>>(vc1, vct1);
    vct_kernel<<<dim3(75, 8), 256, 0, stream>>>(vc2, vct2);

    // fundamental_1 = f(q2, k1, vc1) -> second half of out
    cs_kernel<<<dim3(75, 5, 8), 128, 0, stream>>>(qh2, ql2, kh1, kl1, cs1);
    inv_kernel<<<150, 256, 0, stream>>>(cs1, u1, (int)SSZ);
    tprime_mfma_kernel<<<dim3(75, 5, 8), 128, 0, stream>>>(qh2, ql2, kh1, kl1,
                                                           vct1, u1, rs1, T1);
    fgemm_kernel<<<dim3(8, 75), 256, 0, stream>>>(vc1, rs1, T1, f1);
    out_kernel<<<38, 256, 0, stream>>>(f1, proj_w, proj_b, out + DD * 256);

    // fundamental_2 = f(q1, k2, vc2) -> first half of out
    cs_kernel<<<dim3(75, 5, 8), 128, 0, stream>>>(qh1, ql1, kh2, kl2, cs2);
    inv_kernel<<<150, 256, 0, stream>>>(cs2, u2, (int)SSZ);
    tprime_mfma_kernel<<<dim3(75, 5, 8), 128, 0, stream>>>(qh1, ql1, kh2, kl2,
                                                           vct2, u2, rs2, T2);
    fgemm_kernel<<<dim3(8, 75), 256, 0, stream>>>(vc2, rs2, T2, f2);
    out_kernel<<<38, 256, 0, stream>>>(f2, proj_w, proj_b, out);
}

// Round 3
// 487.570 us; speedup vs baseline: 3.2357x; 1.2020x over previous
//
#include <hip/hip_runtime.h>
#include <stdint.h>
#include <math.h>

#define N_TOK 4800
#define NH 8
#define HD 32
#define DP 40          // padded vc/T' leading dim (D=38 -> 40)
#define DD 38
#define VCT_ROWS 64    // transposed-VC padded row count (d-dim)
#define SCALE 0.17677669529663687f            // 32^-0.5
#define QSCALE (0.17677669529663687f * 1.4426950408889634f)  // SCALE*log2(e)

typedef float f32x16 __attribute__((ext_vector_type(16)));
typedef short s8v __attribute__((ext_vector_type(8)));
typedef int i2v __attribute__((ext_vector_type(2)));

__device__ __forceinline__ unsigned short f2bf(float x) {
    union { float f; uint32_t u; } v; v.f = x;
    uint32_t r = v.u + 0x7FFFu + ((v.u >> 16) & 1u);
    return (unsigned short)(r >> 16);
}
__device__ __forceinline__ float bf2f(unsigned short h) {
    union { uint32_t u; float f; } v; v.u = ((uint32_t)h) << 16;
    return v.f;
}
__device__ __forceinline__ int cvtpk(float lo, float hi) {
    int r;
    asm("v_cvt_pk_bf16_f32 %0, %1, %2" : "=v"(r) : "v"(lo), "v"(hi));
    return r;
}
__device__ __forceinline__ s8v mk_s8(int a, int b, int c, int d) {
    union { int i[4]; s8v s; } u;
    u.i[0] = a; u.i[1] = b; u.i[2] = c; u.i[3] = d;
    return u.s;
}

#define MFMA(a, b, c) __builtin_amdgcn_mfma_f32_32x32x16_bf16((a), (b), (c), 0, 0, 0)

// ---------------------------------------------------------------------------
// split fp32 -> bf16 hi + bf16 lo (for the qkv GEMM inputs only)
// ---------------------------------------------------------------------------
__global__ __launch_bounds__(256) void split_kernel(
    const float* __restrict__ src, unsigned short* __restrict__ hi,
    unsigned short* __restrict__ lo, int n4)
{
    const int i = blockIdx.x * 256 + threadIdx.x;
    if (i >= n4) return;
    const float4 v = ((const float4*)src)[i];
    ushort4 h, l;
    h.x = f2bf(v.x); l.x = f2bf(v.x - bf2f(h.x));
    h.y = f2bf(v.y); l.y = f2bf(v.y - bf2f(h.y));
    h.z = f2bf(v.z); l.z = f2bf(v.z - bf2f(h.z));
    h.w = f2bf(v.w); l.w = f2bf(v.w - bf2f(h.w));
    ((ushort4*)hi)[i] = h;
    ((ushort4*)lo)[i] = l;
}

// ---------------------------------------------------------------------------
// QKV GEMM via split-bf16 MFMA: y = x @ qkv_w^T (4800x256 @ 256x768).
// Epilogue: q -> bf16 scaled by SCALE*log2e; k -> bf16; v -> vc fp32 [.,0:32].
// ---------------------------------------------------------------------------
__global__ __launch_bounds__(128) void qkv_mfma_kernel(
    const unsigned short* __restrict__ xh, const unsigned short* __restrict__ xl,
    const unsigned short* __restrict__ wh, const unsigned short* __restrict__ wl,
    unsigned short* __restrict__ qb, unsigned short* __restrict__ kb,
    float* __restrict__ vcb)
{
    const int lane = threadIdx.x & 63;
    const int wid = threadIdx.x >> 6;
    const int n0 = blockIdx.x * 64 + wid * 32;
    const int j0 = blockIdx.y * 32;
    const int lr = lane & 31, hi5 = lane >> 5;
    const unsigned short* xhp = xh + (n0 + lr) * 256 + 8 * hi5;
    const unsigned short* xlp = xl + (n0 + lr) * 256 + 8 * hi5;
    const unsigned short* whp = wh + (j0 + lr) * 256 + 8 * hi5;
    const unsigned short* wlp = wl + (j0 + lr) * 256 + 8 * hi5;
    f32x16 acc = {};
#pragma unroll 4
    for (int c = 0; c < 16; ++c) {
        const s8v aH = *(const s8v*)(xhp + 16 * c);
        const s8v aL = *(const s8v*)(xlp + 16 * c);
        const s8v bH = *(const s8v*)(whp + 16 * c);
        const s8v bL = *(const s8v*)(wlp + 16 * c);
        acc = MFMA(aH, bH, acc);
        acc = MFMA(aH, bL, acc);
        acc = MFMA(aL, bH, acc);
    }
    const int s = j0 >> 8, h = (j0 >> 5) & 7, d = lr;
#pragma unroll
    for (int r = 0; r < 16; ++r) {
        const int n = n0 + (r & 3) + 8 * (r >> 2) + 4 * hi5;
        const float v = acc[r];
        if (s == 2)      vcb[(h * N_TOK + n) * DP + d] = v;
        else if (s == 0) qb[(h * N_TOK + n) * HD + d] = f2bf(v * QSCALE);
        else             kb[(h * N_TOK + n) * HD + d] = f2bf(v);
    }
}

// ---------------------------------------------------------------------------
// Fill vc[..., 32:40] with positional encodings (cols 38,39 zero pad).
// ---------------------------------------------------------------------------
__global__ void pos_kernel(float* __restrict__ vc1, float* __restrict__ vc2)
{
    const int n = blockIdx.x * 256 + threadIdx.x;
    if (n >= N_TOK) return;
    const int row = n / 80, col = n % 80;
    const float y = -1.0f + 2.0f * (float)row / 59.0f;
    const float x = -1.0f + 2.0f * (float)col / 79.0f;
    const float p3 = y * (240.0f / 517.0f);
    const float p4 = x * (360.0f / 517.0f);
    const float pv[8] = {p3 * p3, p4 * p4, p3 * p4, p3, p4, 1.0f, 0.0f, 0.0f};
#pragma unroll
    for (int h = 0; h < NH; ++h) {
        const size_t base = (size_t)(h * N_TOK + n) * DP + 32;
#pragma unroll
        for (int p = 0; p < 8; ++p) {
            vc1[base + p] = pv[p];
            vc2[base + p] = pv[p];
        }
    }
}

// ---------------------------------------------------------------------------
// vc fp32 [h][4800][40] -> vctU bf16 [h][64][4800], u[m]=1/cs[m] folded in.
// Rows 40..63 zeroed. grid (75, 8), 256 threads.
// ---------------------------------------------------------------------------
__global__ __launch_bounds__(256) void vctu_kernel(
    const float* __restrict__ vc, const float* __restrict__ cs,
    unsigned short* __restrict__ vct)
{
    __shared__ float vl[64][41];
    __shared__ float ul[64];
    const int m0 = blockIdx.x * 64;
    const int h = blockIdx.y;
    const int t = threadIdx.x;
    const float* vcbase = vc + (size_t)(h * N_TOK + m0) * DP;
    for (int e = t; e < 64 * DP; e += 256) vl[e / DP][e % DP] = vcbase[e];
    if (t < 64) ul[t] = 1.0f / cs[(size_t)h * N_TOK + m0 + t];
    __syncthreads();
    const int j = t & 63, dg = t >> 6;
    const float uj = ul[j];
    unsigned short* obase = vct + (size_t)h * VCT_ROWS * N_TOK + m0 + j;
#pragma unroll
    for (int i = 0; i < 16; ++i) {
        const int d = dg * 16 + i;
        const float v = (d < DP) ? vl[j][d] * uj : 0.0f;
        obase[(size_t)d * N_TOK] = f2bf(v);
    }
}

// ---------------------------------------------------------------------------
// Pass 1: S' = Q'.K^T (Q' pre-scaled by SCALE*log2e) via bf16 MFMA.
// cs[m] += sum_n 2^S' ; in-lane reduce, one atomic per wave.
// grid (75 m-blocks, 5 n-chunks, 8 heads), 128 threads (2 waves).
// ---------------------------------------------------------------------------
__global__ __launch_bounds__(128) void cs_kernel(
    const unsigned short* __restrict__ qb, const unsigned short* __restrict__ kb,
    float* __restrict__ cs)
{
    const int lane = threadIdx.x & 63;
    const int wid = threadIdx.x >> 6;
    const int h = blockIdx.z;
    const int m0 = blockIdx.x * 64 + wid * 32;
    const int lr = lane & 31, hi5 = lane >> 5;
    const int hbase = h * N_TOK;
    const unsigned short* kp = kb + (hbase + m0 + lr) * HD + 8 * hi5;
    const s8v bK0 = *(const s8v*)(kp);
    const s8v bK1 = *(const s8v*)(kp + 16);
    const int nt0 = blockIdx.y * 30;
    const unsigned short* qp = qb + (hbase + nt0 * 32 + lr) * HD + 8 * hi5;
    s8v a0 = *(const s8v*)(qp);
    s8v a1 = *(const s8v*)(qp + 16);
    float csa = 0.f, csb = 0.f;
    for (int it = 0; it < 30; ++it) {
        const int adv = (it < 29) ? (32 * HD) : 0;
        const unsigned short* qpn = qp + adv;
        const s8v na0 = *(const s8v*)(qpn);
        const s8v na1 = *(const s8v*)(qpn + 16);
        f32x16 acc = {};
        acc = MFMA(a0, bK0, acc);
        acc = MFMA(a1, bK1, acc);
#pragma unroll
        for (int r = 0; r < 16; r += 2) {
            csa += exp2f(acc[r]);
            csb += exp2f(acc[r + 1]);
        }
        a0 = na0; a1 = na1; qp = qpn;
    }
    float csacc = csa + csb;
    csacc += __shfl_xor(csacc, 32);
    if (lane < 32) atomicAdd(&cs[hbase + m0 + lane], csacc);
}

// ---------------------------------------------------------------------------
// Pass 2: S'^T = K.Q'^T (col=lane=n). e = 2^S'; rs += e in-lane;
// P' = e*e packed to bf16 in-register (cvt_pk + permlane32_swap);
// T'[n,d] += P'.vctU via MFMA (u already folded into vctU).
// grid (75 n-blocks, 5 m-chunks, 8 heads), 128 threads (2 waves).
// ---------------------------------------------------------------------------
__global__ __launch_bounds__(128) void tprime_mfma_kernel(
    const unsigned short* __restrict__ qb, const unsigned short* __restrict__ kb,
    const unsigned short* __restrict__ vctu,
    float* __restrict__ rs, float* __restrict__ T)
{
    const int lane = threadIdx.x & 63;
    const int wid = threadIdx.x >> 6;
    const int h = blockIdx.z;
    const int n0 = blockIdx.x * 64 + wid * 32;
    const int lr = lane & 31, hi5 = lane >> 5;
    const int hbase = h * N_TOK;
    // Q as B operand (hoisted across the m-loop)
    const unsigned short* qp = qb + (hbase + n0 + lr) * HD + 8 * hi5;
    const s8v bQ0 = *(const s8v*)(qp);
    const s8v bQ1 = *(const s8v*)(qp + 16);
    const unsigned short* vbase = vctu + (size_t)h * VCT_ROWS * N_TOK;
    f32x16 t0 = {}, t1 = {};
    float rsa = 0.f, rsb = 0.f;
    const int mt0 = blockIdx.y * 30;
    const unsigned short* kp = kb + (hbase + mt0 * 32 + lr) * HD + 8 * hi5;
    const unsigned short* vp = vbase + (size_t)lr * N_TOK + mt0 * 32 + 8 * hi5;
    s8v a0 = *(const s8v*)(kp);
    s8v a1 = *(const s8v*)(kp + 16);
    for (int it = 0; it < 30; ++it) {
        // current-tile VCT loads: latency hides under S-MFMA + exp/pack
        const s8v v00 = *(const s8v*)(vp);
        const s8v v01 = *(const s8v*)(vp + 16);
        const s8v v10 = *(const s8v*)(vp + (size_t)32 * N_TOK);
        const s8v v11 = *(const s8v*)(vp + (size_t)32 * N_TOK + 16);
        // next-tile K prefetch: hides under PV MFMAs
        const int adv = (it < 29) ? 1 : 0;
        const unsigned short* kpn = kp + adv * 32 * HD;
        const s8v na0 = *(const s8v*)(kpn);
        const s8v na1 = *(const s8v*)(kpn + 16);
        f32x16 s = {};
        s = MFMA(a0, bQ0, s);
        s = MFMA(a1, bQ1, s);
        float p[16];
#pragma unroll
        for (int r = 0; r < 16; r += 2) {
            const float e0 = exp2f(s[r]);
            const float e1 = exp2f(s[r + 1]);
            rsa += e0; rsb += e1;
            p[r] = e0 * e0; p[r + 1] = e1 * e1;
        }
        const int L0 = cvtpk(p[0], p[1]),   L1 = cvtpk(p[2], p[3]);
        const int H0 = cvtpk(p[4], p[5]),   H1 = cvtpk(p[6], p[7]);
        const int L2 = cvtpk(p[8], p[9]),   L3 = cvtpk(p[10], p[11]);
        const int H2 = cvtpk(p[12], p[13]), H3 = cvtpk(p[14], p[15]);
        const i2v s0 = __builtin_amdgcn_permlane32_swap(L0, H0, false, false);
        const i2v s1 = __builtin_amdgcn_permlane32_swap(L1, H1, false, false);
        const i2v s2 = __builtin_amdgcn_permlane32_swap(L2, H2, false, false);
        const i2v s3 = __builtin_amdgcn_permlane32_swap(L3, H3, false, false);
        const s8v pa0 = mk_s8(s0[0], s1[0], s0[1], s1[1]);   // k = m0+0..15
        const s8v pa1 = mk_s8(s2[0], s3[0], s2[1], s3[1]);   // k = m0+16..31
        t0 = MFMA(pa0, v00, t0);
        t0 = MFMA(pa1, v01, t0);
        t1 = MFMA(pa0, v10, t1);
        t1 = MFMA(pa1, v11, t1);
        a0 = na0; a1 = na1; kp = kpn; vp += adv * 32;
    }
    float rsacc = rsa + rsb;
    rsacc += __shfl_xor(rsacc, 32);
    if (lane < 32) atomicAdd(&rs[hbase + n0 + lane], rsacc);
#pragma unroll
    for (int r = 0; r < 16; ++r) {
        const int n = n0 + (r & 3) + 8 * (r >> 2) + 4 * hi5;
        atomicAdd(&T[(size_t)(hbase + n) * DP + lr], t0[r]);
    }
    if (lr < 8) {
#pragma unroll
        for (int r = 0; r < 16; ++r) {
            const int n = n0 + (r & 3) + 8 * (r >> 2) + 4 * hi5;
            atomicAdd(&T[(size_t)(hbase + n) * DP + 32 + lr], t1[r]);
        }
    }
}

// ---------------------------------------------------------------------------
// f[h,c,d] = sum_n (vc[n,c]/rs[n]) * T'[n,d]  -- partial per 64-row chunk.
// ---------------------------------------------------------------------------
__global__ __launch_bounds__(256) void fgemm_kernel(
    const float* __restrict__ VC, const float* __restrict__ rs,
    const float* __restrict__ T, float* __restrict__ f)
{
    __shared__ __align__(16) float wvcl[64 * DP];
    __shared__ __align__(16) float tl[64 * DP];
    __shared__ float wl[64];
    const int h = blockIdx.x, n0 = blockIdx.y * 64;
    const int t = threadIdx.x;
    if (t < 64) wl[t] = 1.0f / rs[(size_t)h * N_TOK + n0 + t];
    __syncthreads();
    const float* vcbase = VC + (size_t)(h * N_TOK + n0) * DP;
    const float* tbase = T + (size_t)(h * N_TOK + n0) * DP;
    for (int e = t; e < 64 * DP; e += 256) {
        wvcl[e] = vcbase[e] * wl[e / DP];
        tl[e] = tbase[e];
    }
    __syncthreads();
    for (int p = t; p < DD * DD; p += 256) {
        const int c = p / DD, d = p % DD;
        float s = 0.f;
#pragma unroll 8
        for (int n = 0; n < 64; ++n) s += wvcl[n * DP + c] * tl[n * DP + d];
        atomicAdd(&f[(size_t)(h * DD + c) * DP + d], s);
    }
}

// ---------------------------------------------------------------------------
// out[d,e] = sum_j f[j,d] * proj_w[e,j] + proj_b[e], j = h*38+c (304 total)
// ---------------------------------------------------------------------------
__global__ __launch_bounds__(256) void out_kernel(
    const float* __restrict__ f, const float* __restrict__ pw,
    const float* __restrict__ pb, float* __restrict__ out)
{
    __shared__ __align__(16) float flds[304];
    const int d = blockIdx.x, t = threadIdx.x;
    for (int j = t; j < 304; j += 256) flds[j] = f[(size_t)j * DP + d];
    __syncthreads();
    float acc = pb[t];
    const float* pwrow = pw + (size_t)t * 304;
#pragma unroll 4
    for (int j = 0; j < 304; j += 4) {
        const float4 p4 = *(const float4*)&pwrow[j];
        const float4 f4 = *(const float4*)&flds[j];
        acc += p4.x * f4.x + p4.y * f4.y + p4.z * f4.z + p4.w * f4.w;
    }
    out[(size_t)d * 256 + t] = acc;
}

extern "C" void kernel_launch(void* const* d_in, const int* in_sizes, int n_in,
                              void* d_out, int out_size, void* d_ws, size_t ws_size,
                              hipStream_t stream)
{
    const float* x1 = (const float*)d_in[0];
    const float* x2 = (const float*)d_in[1];
    const float* qkv_w = (const float*)d_in[2];
    const float* proj_w = (const float*)d_in[3];
    const float* proj_b = (const float*)d_in[4];
    float* out = (float*)d_out;

    const size_t QSZ = (size_t)NH * N_TOK * HD;          // 1,228,800
    const size_t VSZ = (size_t)NH * N_TOK * DP;          // 1,536,000
    const size_t SSZ = (size_t)NH * N_TOK;               //    38,400
    const size_t FSZ = (size_t)NH * DD * DP;             //    12,160
    const size_t XSZ = (size_t)N_TOK * 256;              // 1,228,800
    const size_t WSZ = (size_t)768 * 256;                //   196,608
    const size_t VTSZ = (size_t)NH * VCT_ROWS * N_TOK;   // 2,457,600

    // fp32 region
    float* vc1 = (float*)d_ws;
    float* vc2 = vc1 + VSZ;
    float* rs1 = vc2 + VSZ;   // zeroed region starts here
    float* cs1 = rs1 + SSZ;
    float* rs2 = cs1 + SSZ;
    float* cs2 = rs2 + SSZ;
    float* T1 = cs2 + SSZ;
    float* T2 = T1 + VSZ;
    float* f1 = T2 + VSZ;
    float* f2 = f1 + FSZ;     // zeroed region ends at f2 + FSZ
    // bf16 region
    unsigned short* xh1 = (unsigned short*)(f2 + FSZ);
    unsigned short* xl1 = xh1 + XSZ;
    unsigned short* xh2 = xl1 + XSZ;
    unsigned short* xl2 = xh2 + XSZ;
    unsigned short* wh = xl2 + XSZ;
    unsigned short* wl = wh + WSZ;
    unsigned short* qb1 = wl + WSZ;
    unsigned short* kb1 = qb1 + QSZ;
    unsigned short* qb2 = kb1 + QSZ;
    unsigned short* kb2 = qb2 + QSZ;
    unsigned short* vct1 = kb2 + QSZ;
    unsigned short* vct2 = vct1 + VTSZ;

    const size_t zbytes = (4 * SSZ + 2 * VSZ + 2 * FSZ) * sizeof(float);
    hipMemsetAsync(rs1, 0, zbytes, stream);

    split_kernel<<<1200, 256, 0, stream>>>(x1, xh1, xl1, (int)(XSZ / 4));
    split_kernel<<<1200, 256, 0, stream>>>(x2, xh2, xl2, (int)(XSZ / 4));
    split_kernel<<<192, 256, 0, stream>>>(qkv_w, wh, wl, (int)(WSZ / 4));

    qkv_mfma_kernel<<<dim3(75, 24), 128, 0, stream>>>(xh1, xl1, wh, wl, qb1, kb1, vc1);
    qkv_mfma_kernel<<<dim3(75, 24), 128, 0, stream>>>(xh2, xl2, wh, wl, qb2, kb2, vc2);
    pos_kernel<<<19, 256, 0, stream>>>(vc1, vc2);

    // fundamental_1 = f(q2, k1, vc1) -> second half of out
    cs_kernel<<<dim3(75, 5, 8), 128, 0, stream>>>(qb2, kb1, cs1);
    vctu_kernel<<<dim3(75, 8), 256, 0, stream>>>(vc1, cs1, vct1);
    tprime_mfma_kernel<<<dim3(75, 5, 8), 128, 0, stream>>>(qb2, kb1, vct1, rs1, T1);
    fgemm_kernel<<<dim3(8, 75), 256, 0, stream>>>(vc1, rs1, T1, f1);
    out_kernel<<<38, 256, 0, stream>>>(f1, proj_w, proj_b, out + DD * 256);

    // fundamental_2 = f(q1, k2, vc2) -> first half of out
    cs_kernel<<<dim3(75, 5, 8), 128, 0, stream>>>(qb1, kb2, cs2);
    vctu_kernel<<<dim3(75, 8), 256, 0, stream>>>(vc2, cs2, vct2);
    tprime_mfma_kernel<<<dim3(75, 5, 8), 128, 0, stream>>>(qb1, kb2, vct2, rs2, T2);
    fgemm_kernel<<<dim3(8, 75), 256, 0, stream>>>(vc2, rs2, T2, f2);
    out_kernel<<<38, 256, 0, stream>>>(f2, proj_w, proj_b, out);
}

// Round 4
// 413.134 us; speedup vs baseline: 3.8187x; 1.1802x over previous
//
#include <hip/hip_runtime.h>
#include <stdint.h>
#include <math.h>

#define N_TOK 4800
#define NH 8
#define HD 32
#define DP 40          // padded vc/T' leading dim (D=38 -> 40)
#define DD 38
#define VCT_ROWS 64    // transposed-VC padded row count (d-dim)
#define SCALE 0.17677669529663687f            // 32^-0.5
#define QSCALE (0.17677669529663687f * 1.4426950408889634f)  // SCALE*log2(e)

typedef float f32x16 __attribute__((ext_vector_type(16)));
typedef short s8v __attribute__((ext_vector_type(8)));
typedef int i2v __attribute__((ext_vector_type(2)));

#if __has_builtin(__builtin_amdgcn_exp2f)
#define EXP2F(x) __builtin_amdgcn_exp2f(x)
#else
#define EXP2F(x) exp2f(x)
#endif

__device__ __forceinline__ unsigned short f2bf(float x) {
    union { float f; uint32_t u; } v; v.f = x;
    uint32_t r = v.u + 0x7FFFu + ((v.u >> 16) & 1u);
    return (unsigned short)(r >> 16);
}
__device__ __forceinline__ float bf2f(unsigned short h) {
    union { uint32_t u; float f; } v; v.u = ((uint32_t)h) << 16;
    return v.f;
}
__device__ __forceinline__ int cvtpk(float lo, float hi) {
    int r;
    asm("v_cvt_pk_bf16_f32 %0, %1, %2" : "=v"(r) : "v"(lo), "v"(hi));
    return r;
}
__device__ __forceinline__ s8v mk_s8(int a, int b, int c, int d) {
    union { int i[4]; s8v s; } u;
    u.i[0] = a; u.i[1] = b; u.i[2] = c; u.i[3] = d;
    return u.s;
}

#define MFMA(a, b, c) __builtin_amdgcn_mfma_f32_32x32x16_bf16((a), (b), (c), 0, 0, 0)

// ---------------------------------------------------------------------------
// split fp32 -> bf16 hi + lo for two tensors in one launch (x1, x2)
// ---------------------------------------------------------------------------
__global__ __launch_bounds__(256) void split2_kernel(
    const float* __restrict__ s1, unsigned short* __restrict__ h1,
    unsigned short* __restrict__ l1,
    const float* __restrict__ s2, unsigned short* __restrict__ h2,
    unsigned short* __restrict__ l2, int n4)
{
    int i = blockIdx.x * 256 + threadIdx.x;
    const float* src; unsigned short* hi; unsigned short* lo;
    if (i >= n4) { i -= n4; src = s2; hi = h2; lo = l2; }
    else         { src = s1; hi = h1; lo = l1; }
    if (i >= n4) return;
    const float4 v = ((const float4*)src)[i];
    ushort4 h, l;
    h.x = f2bf(v.x); l.x = f2bf(v.x - bf2f(h.x));
    h.y = f2bf(v.y); l.y = f2bf(v.y - bf2f(h.y));
    h.z = f2bf(v.z); l.z = f2bf(v.z - bf2f(h.z));
    h.w = f2bf(v.w); l.w = f2bf(v.w - bf2f(h.w));
    ((ushort4*)hi)[i] = h;
    ((ushort4*)lo)[i] = l;
}

__global__ __launch_bounds__(256) void split_kernel(
    const float* __restrict__ src, unsigned short* __restrict__ hi,
    unsigned short* __restrict__ lo, int n4)
{
    const int i = blockIdx.x * 256 + threadIdx.x;
    if (i >= n4) return;
    const float4 v = ((const float4*)src)[i];
    ushort4 h, l;
    h.x = f2bf(v.x); l.x = f2bf(v.x - bf2f(h.x));
    h.y = f2bf(v.y); l.y = f2bf(v.y - bf2f(h.y));
    h.z = f2bf(v.z); l.z = f2bf(v.z - bf2f(h.z));
    h.w = f2bf(v.w); l.w = f2bf(v.w - bf2f(h.w));
    ((ushort4*)hi)[i] = h;
    ((ushort4*)lo)[i] = l;
}

// ---------------------------------------------------------------------------
// QKV GEMM via split-bf16 MFMA, both inputs in one launch (blockIdx.z).
// Epilogue: q -> bf16 scaled by SCALE*log2e; k -> bf16; v -> vc fp32 [.,0:32].
// ---------------------------------------------------------------------------
__global__ __launch_bounds__(128) void qkv_mfma_kernel(
    const unsigned short* __restrict__ xhA, const unsigned short* __restrict__ xlA,
    unsigned short* __restrict__ qbA, unsigned short* __restrict__ kbA,
    float* __restrict__ vcbA,
    const unsigned short* __restrict__ xhB, const unsigned short* __restrict__ xlB,
    unsigned short* __restrict__ qbB, unsigned short* __restrict__ kbB,
    float* __restrict__ vcbB,
    const unsigned short* __restrict__ wh, const unsigned short* __restrict__ wl)
{
    const int sel = blockIdx.z;
    const unsigned short* xh = sel ? xhB : xhA;
    const unsigned short* xl = sel ? xlB : xlA;
    unsigned short* qb = sel ? qbB : qbA;
    unsigned short* kb = sel ? kbB : kbA;
    float* vcb = sel ? vcbB : vcbA;
    const int lane = threadIdx.x & 63;
    const int wid = threadIdx.x >> 6;
    const int n0 = blockIdx.x * 64 + wid * 32;
    const int j0 = blockIdx.y * 32;
    const int lr = lane & 31, hi5 = lane >> 5;
    const unsigned short* xhp = xh + (n0 + lr) * 256 + 8 * hi5;
    const unsigned short* xlp = xl + (n0 + lr) * 256 + 8 * hi5;
    const unsigned short* whp = wh + (j0 + lr) * 256 + 8 * hi5;
    const unsigned short* wlp = wl + (j0 + lr) * 256 + 8 * hi5;
    f32x16 acc = {};
#pragma unroll 4
    for (int c = 0; c < 16; ++c) {
        const s8v aH = *(const s8v*)(xhp + 16 * c);
        const s8v aL = *(const s8v*)(xlp + 16 * c);
        const s8v bH = *(const s8v*)(whp + 16 * c);
        const s8v bL = *(const s8v*)(wlp + 16 * c);
        acc = MFMA(aH, bH, acc);
        acc = MFMA(aH, bL, acc);
        acc = MFMA(aL, bH, acc);
    }
    const int s = j0 >> 8, h = (j0 >> 5) & 7, d = lr;
#pragma unroll
    for (int r = 0; r < 16; ++r) {
        const int n = n0 + (r & 3) + 8 * (r >> 2) + 4 * hi5;
        const float v = acc[r];
        if (s == 2)      vcb[(h * N_TOK + n) * DP + d] = v;
        else if (s == 0) qb[(h * N_TOK + n) * HD + d] = f2bf(v * QSCALE);
        else             kb[(h * N_TOK + n) * HD + d] = f2bf(v);
    }
}

// ---------------------------------------------------------------------------
// Fill vc[..., 32:40] with positional encodings (cols 38,39 zero pad).
// ---------------------------------------------------------------------------
__global__ void pos_kernel(float* __restrict__ vc1, float* __restrict__ vc2)
{
    const int n = blockIdx.x * 256 + threadIdx.x;
    if (n >= N_TOK) return;
    const int row = n / 80, col = n % 80;
    const float y = -1.0f + 2.0f * (float)row / 59.0f;
    const float x = -1.0f + 2.0f * (float)col / 79.0f;
    const float p3 = y * (240.0f / 517.0f);
    const float p4 = x * (360.0f / 517.0f);
    const float pv[8] = {p3 * p3, p4 * p4, p3 * p4, p3, p4, 1.0f, 0.0f, 0.0f};
#pragma unroll
    for (int h = 0; h < NH; ++h) {
        const size_t base = (size_t)(h * N_TOK + n) * DP + 32;
#pragma unroll
        for (int p = 0; p < 8; ++p) {
            vc1[base + p] = pv[p];
            vc2[base + p] = pv[p];
        }
    }
}

// ---------------------------------------------------------------------------
// Pass 1 (both fundamentals): S' = Q'.K^T via bf16 MFMA; cs[m] += sum_n 2^S'.
// grid (75 m-blocks, 5 n-chunks, 16), 128 threads (2 waves).
// ---------------------------------------------------------------------------
__global__ __launch_bounds__(128) void cs_kernel(
    const unsigned short* __restrict__ qbA, const unsigned short* __restrict__ kbA,
    float* __restrict__ csA,
    const unsigned short* __restrict__ qbB, const unsigned short* __restrict__ kbB,
    float* __restrict__ csB)
{
    const int sel = blockIdx.z >> 3;
    const unsigned short* qb = sel ? qbB : qbA;
    const unsigned short* kb = sel ? kbB : kbA;
    float* cs = sel ? csB : csA;
    const int lane = threadIdx.x & 63;
    const int wid = threadIdx.x >> 6;
    const int h = blockIdx.z & 7;
    const int m0 = blockIdx.x * 64 + wid * 32;
    const int lr = lane & 31, hi5 = lane >> 5;
    const int hbase = h * N_TOK;
    const unsigned short* kp = kb + (hbase + m0 + lr) * HD + 8 * hi5;
    const s8v bK0 = *(const s8v*)(kp);
    const s8v bK1 = *(const s8v*)(kp + 16);
    const int nt0 = blockIdx.y * 30;
    const unsigned short* qp = qb + (hbase + nt0 * 32 + lr) * HD + 8 * hi5;
    s8v a0 = *(const s8v*)(qp);
    s8v a1 = *(const s8v*)(qp + 16);
    float csa = 0.f, csb = 0.f;
#pragma unroll 2
    for (int it = 0; it < 30; ++it) {
        const int adv = (it < 29) ? (32 * HD) : 0;
        const unsigned short* qpn = qp + adv;
        const s8v na0 = *(const s8v*)(qpn);
        const s8v na1 = *(const s8v*)(qpn + 16);
        f32x16 acc = {};
        acc = MFMA(a0, bK0, acc);
        acc = MFMA(a1, bK1, acc);
#pragma unroll
        for (int r = 0; r < 16; r += 2) {
            csa += EXP2F(acc[r]);
            csb += EXP2F(acc[r + 1]);
        }
        a0 = na0; a1 = na1; qp = qpn;
    }
    float csacc = csa + csb;
    csacc += __shfl_xor(csacc, 32);
    if (lane < 32) atomicAdd(&cs[hbase + m0 + lane], csacc);
}

// ---------------------------------------------------------------------------
// vc fp32 [h][4800][40] -> vctU bf16 [h][64][4800] with u=1/cs folded in.
// Both fundamentals in one launch: grid (75, 16).
// ---------------------------------------------------------------------------
__global__ __launch_bounds__(256) void vctu_kernel(
    const float* __restrict__ vcA, const float* __restrict__ csA,
    unsigned short* __restrict__ vctA,
    const float* __restrict__ vcB, const float* __restrict__ csB,
    unsigned short* __restrict__ vctB)
{
    const int sel = blockIdx.y >> 3;
    const float* vc = sel ? vcB : vcA;
    const float* cs = sel ? csB : csA;
    unsigned short* vct = sel ? vctB : vctA;
    __shared__ float vl[64][41];
    __shared__ float ul[64];
    const int m0 = blockIdx.x * 64;
    const int h = blockIdx.y & 7;
    const int t = threadIdx.x;
    const float* vcbase = vc + (size_t)(h * N_TOK + m0) * DP;
    for (int e = t; e < 64 * DP; e += 256) vl[e / DP][e % DP] = vcbase[e];
    if (t < 64) ul[t] = 1.0f / cs[(size_t)h * N_TOK + m0 + t];
    __syncthreads();
    const int j = t & 63, dg = t >> 6;
    const float uj = ul[j];
    unsigned short* obase = vct + (size_t)h * VCT_ROWS * N_TOK + m0 + j;
#pragma unroll
    for (int i = 0; i < 16; ++i) {
        const int d = dg * 16 + i;
        const float v = (d < DP) ? vl[j][d] * uj : 0.0f;
        obase[(size_t)d * N_TOK] = f2bf(v);
    }
}

// ---------------------------------------------------------------------------
// Pass 2 (both fundamentals): S'^T = K.Q'^T; e = 2^S'; rs += e in-lane;
// P' = e*e packed in-register; T' += P'.vctU via MFMA.
// grid (75 n-blocks, 5 m-chunks, 16), 128 threads (2 waves).
// ---------------------------------------------------------------------------
__global__ __launch_bounds__(128, 3) void tprime_mfma_kernel(
    const unsigned short* __restrict__ qbA, const unsigned short* __restrict__ kbA,
    const unsigned short* __restrict__ vctuA,
    float* __restrict__ rsA, float* __restrict__ TA,
    const unsigned short* __restrict__ qbB, const unsigned short* __restrict__ kbB,
    const unsigned short* __restrict__ vctuB,
    float* __restrict__ rsB, float* __restrict__ TB)
{
    const int sel = blockIdx.z >> 3;
    const unsigned short* qb = sel ? qbB : qbA;
    const unsigned short* kb = sel ? kbB : kbA;
    const unsigned short* vctu = sel ? vctuB : vctuA;
    float* rs = sel ? rsB : rsA;
    float* T = sel ? TB : TA;
    const int lane = threadIdx.x & 63;
    const int wid = threadIdx.x >> 6;
    const int h = blockIdx.z & 7;
    const int n0 = blockIdx.x * 64 + wid * 32;
    const int lr = lane & 31, hi5 = lane >> 5;
    const int hbase = h * N_TOK;
    // Q as B operand (hoisted across the m-loop)
    const unsigned short* qp = qb + (hbase + n0 + lr) * HD + 8 * hi5;
    const s8v bQ0 = *(const s8v*)(qp);
    const s8v bQ1 = *(const s8v*)(qp + 16);
    f32x16 t0 = {}, t1 = {};
    float rsa = 0.f, rsb = 0.f;
    const int mt0 = blockIdx.y * 30;
    const unsigned short* kp = kb + (hbase + mt0 * 32 + lr) * HD + 8 * hi5;
    const unsigned short* vpA = vctu + (size_t)h * VCT_ROWS * N_TOK
                               + (size_t)lr * N_TOK + mt0 * 32 + 8 * hi5;
    const unsigned short* vpB = vpA + (size_t)32 * N_TOK;
    s8v a0 = *(const s8v*)(kp);
    s8v a1 = *(const s8v*)(kp + 16);
    s8v v00 = *(const s8v*)(vpA);
    s8v v01 = *(const s8v*)(vpA + 16);
    s8v v10 = *(const s8v*)(vpB);
    s8v v11 = *(const s8v*)(vpB + 16);
#pragma unroll 2
    for (int it = 0; it < 30; ++it) {
        // prefetch next tile's K and V fragments (full-iteration latency hiding)
        const int adv = (it < 29) ? 1 : 0;
        const unsigned short* kpn = kp + adv * 32 * HD;
        const unsigned short* vpAn = vpA + adv * 32;
        const unsigned short* vpBn = vpB + adv * 32;
        const s8v na0 = *(const s8v*)(kpn);
        const s8v na1 = *(const s8v*)(kpn + 16);
        const s8v nv00 = *(const s8v*)(vpAn);
        const s8v nv01 = *(const s8v*)(vpAn + 16);
        const s8v nv10 = *(const s8v*)(vpBn);
        const s8v nv11 = *(const s8v*)(vpBn + 16);
        f32x16 s = {};
        s = MFMA(a0, bQ0, s);
        s = MFMA(a1, bQ1, s);
        float p[16];
#pragma unroll
        for (int r = 0; r < 16; r += 2) {
            const float e0 = EXP2F(s[r]);
            const float e1 = EXP2F(s[r + 1]);
            rsa += e0; rsb += e1;
            p[r] = e0 * e0; p[r + 1] = e1 * e1;
        }
        const int L0 = cvtpk(p[0], p[1]),   L1 = cvtpk(p[2], p[3]);
        const int H0 = cvtpk(p[4], p[5]),   H1 = cvtpk(p[6], p[7]);
        const int L2 = cvtpk(p[8], p[9]),   L3 = cvtpk(p[10], p[11]);
        const int H2 = cvtpk(p[12], p[13]), H3 = cvtpk(p[14], p[15]);
        const i2v s0 = __builtin_amdgcn_permlane32_swap(L0, H0, false, false);
        const i2v s1 = __builtin_amdgcn_permlane32_swap(L1, H1, false, false);
        const i2v s2 = __builtin_amdgcn_permlane32_swap(L2, H2, false, false);
        const i2v s3 = __builtin_amdgcn_permlane32_swap(L3, H3, false, false);
        const s8v pa0 = mk_s8(s0[0], s1[0], s0[1], s1[1]);   // k = m0+0..15
        const s8v pa1 = mk_s8(s2[0], s3[0], s2[1], s3[1]);   // k = m0+16..31
        t0 = MFMA(pa0, v00, t0);
        t0 = MFMA(pa1, v01, t0);
        t1 = MFMA(pa0, v10, t1);
        t1 = MFMA(pa1, v11, t1);
        a0 = na0; a1 = na1; kp = kpn;
        v00 = nv00; v01 = nv01; v10 = nv10; v11 = nv11;
        vpA = vpAn; vpB = vpBn;
    }
    float rsacc = rsa + rsb;
    rsacc += __shfl_xor(rsacc, 32);
    if (lane < 32) atomicAdd(&rs[hbase + n0 + lane], rsacc);
#pragma unroll
    for (int r = 0; r < 16; ++r) {
        const int n = n0 + (r & 3) + 8 * (r >> 2) + 4 * hi5;
        atomicAdd(&T[(size_t)(hbase + n) * DP + lr], t0[r]);
    }
    if (lr < 8) {
#pragma unroll
        for (int r = 0; r < 16; ++r) {
            const int n = n0 + (r & 3) + 8 * (r >> 2) + 4 * hi5;
            atomicAdd(&T[(size_t)(hbase + n) * DP + 32 + lr], t1[r]);
        }
    }
}

// ---------------------------------------------------------------------------
// f[h,c,d] = sum_n (vc[n,c]/rs[n]) * T'[n,d] -- partial per 64-row chunk.
// Both fundamentals: grid (16, 75).
// ---------------------------------------------------------------------------
__global__ __launch_bounds__(256) void fgemm_kernel(
    const float* __restrict__ VCA, const float* __restrict__ rsA,
    const float* __restrict__ TA, float* __restrict__ fA,
    const float* __restrict__ VCB, const float* __restrict__ rsB,
    const float* __restrict__ TB, float* __restrict__ fB)
{
    const int sel = blockIdx.x >> 3;
    const float* VC = sel ? VCB : VCA;
    const float* rs = sel ? rsB : rsA;
    const float* T = sel ? TB : TA;
    float* f = sel ? fB : fA;
    __shared__ __align__(16) float wvcl[64 * DP];
    __shared__ __align__(16) float tl[64 * DP];
    __shared__ float wl[64];
    const int h = blockIdx.x & 7, n0 = blockIdx.y * 64;
    const int t = threadIdx.x;
    if (t < 64) wl[t] = 1.0f / rs[(size_t)h * N_TOK + n0 + t];
    __syncthreads();
    const float* vcbase = VC + (size_t)(h * N_TOK + n0) * DP;
    const float* tbase = T + (size_t)(h * N_TOK + n0) * DP;
    for (int e = t; e < 64 * DP; e += 256) {
        wvcl[e] = vcbase[e] * wl[e / DP];
        tl[e] = tbase[e];
    }
    __syncthreads();
    for (int p = t; p < DD * DD; p += 256) {
        const int c = p / DD, d = p % DD;
        float s = 0.f;
#pragma unroll 8
        for (int n = 0; n < 64; ++n) s += wvcl[n * DP + c] * tl[n * DP + d];
        atomicAdd(&f[(size_t)(h * DD + c) * DP + d], s);
    }
}

// ---------------------------------------------------------------------------
// out[d,e] = sum_j f[j,d] * proj_w[e,j] + proj_b[e]. Both fundamentals:
// grid (38, 2); y=0 -> f1 -> out+DD*256, y=1 -> f2 -> out.
// ---------------------------------------------------------------------------
__global__ __launch_bounds__(256) void out_kernel(
    const float* __restrict__ f1, const float* __restrict__ f2,
    const float* __restrict__ pw, const float* __restrict__ pb,
    float* __restrict__ out)
{
    const int sel = blockIdx.y;
    const float* f = sel ? f2 : f1;
    float* dst = sel ? out : (out + DD * 256);
    __shared__ __align__(16) float flds[304];
    const int d = blockIdx.x, t = threadIdx.x;
    for (int j = t; j < 304; j += 256) flds[j] = f[(size_t)j * DP + d];
    __syncthreads();
    float acc = pb[t];
    const float* pwrow = pw + (size_t)t * 304;
#pragma unroll 4
    for (int j = 0; j < 304; j += 4) {
        const float4 p4 = *(const float4*)&pwrow[j];
        const float4 f4 = *(const float4*)&flds[j];
        acc += p4.x * f4.x + p4.y * f4.y + p4.z * f4.z + p4.w * f4.w;
    }
    dst[(size_t)d * 256 + t] = acc;
}

extern "C" void kernel_launch(void* const* d_in, const int* in_sizes, int n_in,
                              void* d_out, int out_size, void* d_ws, size_t ws_size,
                              hipStream_t stream)
{
    const float* x1 = (const float*)d_in[0];
    const float* x2 = (const float*)d_in[1];
    const float* qkv_w = (const float*)d_in[2];
    const float* proj_w = (const float*)d_in[3];
    const float* proj_b = (const float*)d_in[4];
    float* out = (float*)d_out;

    const size_t QSZ = (size_t)NH * N_TOK * HD;          // 1,228,800
    const size_t VSZ = (size_t)NH * N_TOK * DP;          // 1,536,000
    const size_t SSZ = (size_t)NH * N_TOK;               //    38,400
    const size_t FSZ = (size_t)NH * DD * DP;             //    12,160
    const size_t XSZ = (size_t)N_TOK * 256;              // 1,228,800
    const size_t WSZ = (size_t)768 * 256;                //   196,608
    const size_t VTSZ = (size_t)NH * VCT_ROWS * N_TOK;   // 2,457,600

    // fp32 region
    float* vc1 = (float*)d_ws;
    float* vc2 = vc1 + VSZ;
    float* rs1 = vc2 + VSZ;   // zeroed region starts here
    float* cs1 = rs1 + SSZ;
    float* rs2 = cs1 + SSZ;
    float* cs2 = rs2 + SSZ;
    float* T1 = cs2 + SSZ;
    float* T2 = T1 + VSZ;
    float* f1 = T2 + VSZ;
    float* f2 = f1 + FSZ;     // zeroed region ends at f2 + FSZ
    // bf16 region
    unsigned short* xh1 = (unsigned short*)(f2 + FSZ);
    unsigned short* xl1 = xh1 + XSZ;
    unsigned short* xh2 = xl1 + XSZ;
    unsigned short* xl2 = xh2 + XSZ;
    unsigned short* wh = xl2 + XSZ;
    unsigned short* wl = wh + WSZ;
    unsigned short* qb1 = wl + WSZ;
    unsigned short* kb1 = qb1 + QSZ;
    unsigned short* qb2 = kb1 + QSZ;
    unsigned short* kb2 = qb2 + QSZ;
    unsigned short* vct1 = kb2 + QSZ;
    unsigned short* vct2 = vct1 + VTSZ;

    const size_t zbytes = (4 * SSZ + 2 * VSZ + 2 * FSZ) * sizeof(float);
    hipMemsetAsync(rs1, 0, zbytes, stream);

    split2_kernel<<<2400, 256, 0, stream>>>(x1, xh1, xl1, x2, xh2, xl2,
                                            (int)(XSZ / 4));
    split_kernel<<<192, 256, 0, stream>>>(qkv_w, wh, wl, (int)(WSZ / 4));

    qkv_mfma_kernel<<<dim3(75, 24, 2), 128, 0, stream>>>(
        xh1, xl1, qb1, kb1, vc1, xh2, xl2, qb2, kb2, vc2, wh, wl);
    pos_kernel<<<19, 256, 0, stream>>>(vc1, vc2);

    // fundamental_1 = f(q2, k1, vc1); fundamental_2 = f(q1, k2, vc2)
    cs_kernel<<<dim3(75, 5, 16), 128, 0, stream>>>(qb2, kb1, cs1,
                                                   qb1, kb2, cs2);
    vctu_kernel<<<dim3(75, 16), 256, 0, stream>>>(vc1, cs1, vct1,
                                                  vc2, cs2, vct2);
    tprime_mfma_kernel<<<dim3(75, 5, 16), 128, 0, stream>>>(
        qb2, kb1, vct1, rs1, T1, qb1, kb2, vct2, rs2, T2);
    fgemm_kernel<<<dim3(16, 75), 256, 0, stream>>>(vc1, rs1, T1, f1,
                                                   vc2, rs2, T2, f2);
    out_kernel<<<dim3(38, 2), 256, 0, stream>>>(f1, f2, proj_w, proj_b, out);
}

// Round 5
// 351.349 us; speedup vs baseline: 4.4902x; 1.1759x over previous
//
#include <hip/hip_runtime.h>
#include <stdint.h>
#include <math.h>

#define N_TOK 4800
#define NH 8
#define HD 32
#define DP 40          // padded vc/T' leading dim (D=38 -> 40)
#define DD 38
#define NTILES 150     // 32-wide m tiles
#define FRAG 2048      // shorts per (h,mtile) fragment: 4 blocks x 64 lanes x 8
#define SCALE 0.17677669529663687f            // 32^-0.5
#define QSCALE (0.17677669529663687f * 1.4426950408889634f)  // SCALE*log2(e)

typedef float f32x16 __attribute__((ext_vector_type(16)));
typedef short s8v __attribute__((ext_vector_type(8)));
typedef int i2v __attribute__((ext_vector_type(2)));

#if __has_builtin(__builtin_amdgcn_exp2f)
#define EXP2F(x) __builtin_amdgcn_exp2f(x)
#else
#define EXP2F(x) exp2f(x)
#endif

__device__ __forceinline__ unsigned short f2bf(float x) {
    union { float f; uint32_t u; } v; v.f = x;
    uint32_t r = v.u + 0x7FFFu + ((v.u >> 16) & 1u);
    return (unsigned short)(r >> 16);
}
__device__ __forceinline__ float bf2f(unsigned short h) {
    union { uint32_t u; float f; } v; v.u = ((uint32_t)h) << 16;
    return v.f;
}
__device__ __forceinline__ int cvtpk(float lo, float hi) {
    int r;
    asm("v_cvt_pk_bf16_f32 %0, %1, %2" : "=v"(r) : "v"(lo), "v"(hi));
    return r;
}
__device__ __forceinline__ s8v mk_s8(int a, int b, int c, int d) {
    union { int i[4]; s8v s; } u;
    u.i[0] = a; u.i[1] = b; u.i[2] = c; u.i[3] = d;
    return u.s;
}

// bijective XCD-aware block remap: blocks sharing an (y,z) work-group stay on
// one XCD (total blocks % 8 == 0 in all uses).
template<int NX, int NY>
__device__ __forceinline__ void swzdec(int& x, int& y, int& z) {
    const int L = blockIdx.x + NX * (blockIdx.y + NY * blockIdx.z);
    constexpr int cpx = NX * NY * 16 / 8;
    const int s = (L & 7) * cpx + (L >> 3);
    x = s % NX;
    const int r = s / NX;
    y = r % NY;
    z = r / NY;
}

#define MFMA(a, b, c) __builtin_amdgcn_mfma_f32_32x32x16_bf16((a), (b), (c), 0, 0, 0)

// ---------------------------------------------------------------------------
// split fp32 -> bf16 hi + lo for two tensors in one launch (x1, x2)
// ---------------------------------------------------------------------------
__global__ __launch_bounds__(256) void split2_kernel(
    const float* __restrict__ s1, unsigned short* __restrict__ h1,
    unsigned short* __restrict__ l1,
    const float* __restrict__ s2, unsigned short* __restrict__ h2,
    unsigned short* __restrict__ l2, int n4)
{
    int i = blockIdx.x * 256 + threadIdx.x;
    const float* src; unsigned short* hi; unsigned short* lo;
    if (i >= n4) { i -= n4; src = s2; hi = h2; lo = l2; }
    else         { src = s1; hi = h1; lo = l1; }
    if (i >= n4) return;
    const float4 v = ((const float4*)src)[i];
    ushort4 h, l;
    h.x = f2bf(v.x); l.x = f2bf(v.x - bf2f(h.x));
    h.y = f2bf(v.y); l.y = f2bf(v.y - bf2f(h.y));
    h.z = f2bf(v.z); l.z = f2bf(v.z - bf2f(h.z));
    h.w = f2bf(v.w); l.w = f2bf(v.w - bf2f(h.w));
    ((ushort4*)hi)[i] = h;
    ((ushort4*)lo)[i] = l;
}

__global__ __launch_bounds__(256) void split_kernel(
    const float* __restrict__ src, unsigned short* __restrict__ hi,
    unsigned short* __restrict__ lo, int n4)
{
    const int i = blockIdx.x * 256 + threadIdx.x;
    if (i >= n4) return;
    const float4 v = ((const float4*)src)[i];
    ushort4 h, l;
    h.x = f2bf(v.x); l.x = f2bf(v.x - bf2f(h.x));
    h.y = f2bf(v.y); l.y = f2bf(v.y - bf2f(h.y));
    h.z = f2bf(v.z); l.z = f2bf(v.z - bf2f(h.z));
    h.w = f2bf(v.w); l.w = f2bf(v.w - bf2f(h.w));
    ((ushort4*)hi)[i] = h;
    ((ushort4*)lo)[i] = l;
}

// ---------------------------------------------------------------------------
// QKV GEMM via split-bf16 MFMA, both inputs in one launch (blockIdx.z).
// Epilogue: q -> bf16 scaled by SCALE*log2e; k -> bf16; v -> vc fp32 [.,0:32].
// ---------------------------------------------------------------------------
__global__ __launch_bounds__(128) void qkv_mfma_kernel(
    const unsigned short* __restrict__ xhA, const unsigned short* __restrict__ xlA,
    unsigned short* __restrict__ qbA, unsigned short* __restrict__ kbA,
    float* __restrict__ vcbA,
    const unsigned short* __restrict__ xhB, const unsigned short* __restrict__ xlB,
    unsigned short* __restrict__ qbB, unsigned short* __restrict__ kbB,
    float* __restrict__ vcbB,
    const unsigned short* __restrict__ wh, const unsigned short* __restrict__ wl)
{
    const int sel = blockIdx.z;
    const unsigned short* xh = sel ? xhB : xhA;
    const unsigned short* xl = sel ? xlB : xlA;
    unsigned short* qb = sel ? qbB : qbA;
    unsigned short* kb = sel ? kbB : kbA;
    float* vcb = sel ? vcbB : vcbA;
    const int lane = threadIdx.x & 63;
    const int wid = threadIdx.x >> 6;
    const int n0 = blockIdx.x * 64 + wid * 32;
    const int j0 = blockIdx.y * 32;
    const int lr = lane & 31, hi5 = lane >> 5;
    const unsigned short* xhp = xh + (n0 + lr) * 256 + 8 * hi5;
    const unsigned short* xlp = xl + (n0 + lr) * 256 + 8 * hi5;
    const unsigned short* whp = wh + (j0 + lr) * 256 + 8 * hi5;
    const unsigned short* wlp = wl + (j0 + lr) * 256 + 8 * hi5;
    f32x16 acc = {};
#pragma unroll 4
    for (int c = 0; c < 16; ++c) {
        const s8v aH = *(const s8v*)(xhp + 16 * c);
        const s8v aL = *(const s8v*)(xlp + 16 * c);
        const s8v bH = *(const s8v*)(whp + 16 * c);
        const s8v bL = *(const s8v*)(wlp + 16 * c);
        acc = MFMA(aH, bH, acc);
        acc = MFMA(aH, bL, acc);
        acc = MFMA(aL, bH, acc);
    }
    const int s = j0 >> 8, h = (j0 >> 5) & 7, d = lr;
#pragma unroll
    for (int r = 0; r < 16; ++r) {
        const int n = n0 + (r & 3) + 8 * (r >> 2) + 4 * hi5;
        const float v = acc[r];
        if (s == 2)      vcb[(h * N_TOK + n) * DP + d] = v;
        else if (s == 0) qb[(h * N_TOK + n) * HD + d] = f2bf(v * QSCALE);
        else             kb[(h * N_TOK + n) * HD + d] = f2bf(v);
    }
}

// ---------------------------------------------------------------------------
// Fill vc[..., 32:40] with positional encodings (cols 38,39 zero pad).
// ---------------------------------------------------------------------------
__global__ void pos_kernel(float* __restrict__ vc1, float* __restrict__ vc2)
{
    const int n = blockIdx.x * 256 + threadIdx.x;
    if (n >= N_TOK) return;
    const int row = n / 80, col = n % 80;
    const float y = -1.0f + 2.0f * (float)row / 59.0f;
    const float x = -1.0f + 2.0f * (float)col / 79.0f;
    const float p3 = y * (240.0f / 517.0f);
    const float p4 = x * (360.0f / 517.0f);
    const float pv[8] = {p3 * p3, p4 * p4, p3 * p4, p3, p4, 1.0f, 0.0f, 0.0f};
#pragma unroll
    for (int h = 0; h < NH; ++h) {
        const size_t base = (size_t)(h * N_TOK + n) * DP + 32;
#pragma unroll
        for (int p = 0; p < 8; ++p) {
            vc1[base + p] = pv[p];
            vc2[base + p] = pv[p];
        }
    }
}

// ---------------------------------------------------------------------------
// Pass 1 (both fundamentals): S' = Q'.K^T via bf16 MFMA; cs[m] += sum_n 2^S'.
// grid (75 m-blocks, 5 n-chunks, 16), XCD-swizzled. 128 threads (2 waves).
// ---------------------------------------------------------------------------
__global__ __launch_bounds__(128) void cs_kernel(
    const unsigned short* __restrict__ qbA, const unsigned short* __restrict__ kbA,
    float* __restrict__ csA,
    const unsigned short* __restrict__ qbB, const unsigned short* __restrict__ kbB,
    float* __restrict__ csB)
{
    int bx, by, bz;
    swzdec<75, 5>(bx, by, bz);
    const int sel = bz >> 3;
    const unsigned short* qb = sel ? qbB : qbA;
    const unsigned short* kb = sel ? kbB : kbA;
    float* cs = sel ? csB : csA;
    const int lane = threadIdx.x & 63;
    const int wid = threadIdx.x >> 6;
    const int h = bz & 7;
    const int m0 = bx * 64 + wid * 32;
    const int lr = lane & 31, hi5 = lane >> 5;
    const int hbase = h * N_TOK;
    const unsigned short* kp = kb + (hbase + m0 + lr) * HD + 8 * hi5;
    const s8v bK0 = *(const s8v*)(kp);
    const s8v bK1 = *(const s8v*)(kp + 16);
    const int nt0 = by * 30;
    const unsigned short* qp = qb + (hbase + nt0 * 32 + lr) * HD + 8 * hi5;
    s8v a0 = *(const s8v*)(qp);
    s8v a1 = *(const s8v*)(qp + 16);
    float csa = 0.f, csb = 0.f;
#pragma unroll 2
    for (int it = 0; it < 30; ++it) {
        const int adv = (it < 29) ? (32 * HD) : 0;
        const unsigned short* qpn = qp + adv;
        const s8v na0 = *(const s8v*)(qpn);
        const s8v na1 = *(const s8v*)(qpn + 16);
        f32x16 acc = {};
        acc = MFMA(a0, bK0, acc);
        acc = MFMA(a1, bK1, acc);
#pragma unroll
        for (int r = 0; r < 16; r += 2) {
            csa += EXP2F(acc[r]);
            csb += EXP2F(acc[r + 1]);
        }
        a0 = na0; a1 = na1; qp = qpn;
    }
    float csacc = csa + csb;
    csacc += __shfl_xor(csacc, 32);
    if (lane < 32) atomicAdd(&cs[hbase + m0 + lane], csacc);
}

// ---------------------------------------------------------------------------
// vc fp32 [h][4800][40] + u=1/cs -> fragment-major bf16 vfrag layout:
// [h][mtile][b][lane][8], b: (d-half, k-half) so tprime loads are 1KiB/instr.
// Both fundamentals: grid (150, 16), 256 threads.
// ---------------------------------------------------------------------------
__global__ __launch_bounds__(256) void vfrag_kernel(
    const float* __restrict__ vcA, const float* __restrict__ csA,
    unsigned short* __restrict__ vfA,
    const float* __restrict__ vcB, const float* __restrict__ csB,
    unsigned short* __restrict__ vfB)
{
    const int sel = blockIdx.y >> 3;
    const float* vc = sel ? vcB : vcA;
    const float* cs = sel ? csB : csA;
    unsigned short* vf = sel ? vfB : vfA;
    __shared__ float vl[32][41];
    __shared__ float ul[32];
    const int mt = blockIdx.x;
    const int h = blockIdx.y & 7;
    const int t = threadIdx.x;
    const int m0 = mt * 32;
    const float* vcbase = vc + (size_t)(h * N_TOK + m0) * DP;
    for (int e = t; e < 32 * DP; e += 256) vl[e / DP][e % DP] = vcbase[e];
    if (t < 32) ul[t] = 1.0f / cs[(size_t)h * N_TOK + m0 + t];
    __syncthreads();
    const int b = t >> 6, lane = t & 63;
    const int hi5 = lane >> 5, lr = lane & 31;
    const int d = (b >> 1) * 32 + lr;       // 0..63 (>=40 zero pad)
    const int mb = (b & 1) * 16 + hi5 * 8;  // k-offset within tile
    union { unsigned short s[8]; s8v v; } pk;
#pragma unroll
    for (int j = 0; j < 8; ++j) {
        const int mo = mb + j;
        const float v = (d < DP) ? vl[mo][d] * ul[mo] : 0.0f;
        pk.s[j] = f2bf(v);
    }
    *(s8v*)(vf + ((size_t)(h * NTILES + mt) * 4 + b) * 512 + lane * 8) = pk.v;
}

// ---------------------------------------------------------------------------
// Pass 2 (both fundamentals): S'^T = K.Q'^T; e = 2^S'; rs += e in-lane;
// P' = e*e packed in-register; T' += P'.vfrag via MFMA. 2 m-chunks with
// separate T partial buffers (plain stores, no atomics).
// grid (75 n-blocks, 2 m-chunks, 16), XCD-swizzled. 128 threads (2 waves).
// ---------------------------------------------------------------------------
__global__ __launch_bounds__(128, 3) void tprime_mfma_kernel(
    const unsigned short* __restrict__ qbA, const unsigned short* __restrict__ kbA,
    const unsigned short* __restrict__ vfA,
    float* __restrict__ rsA, float* __restrict__ TA0, float* __restrict__ TA1,
    const unsigned short* __restrict__ qbB, const unsigned short* __restrict__ kbB,
    const unsigned short* __restrict__ vfB,
    float* __restrict__ rsB, float* __restrict__ TB0, float* __restrict__ TB1)
{
    int bx, by, bz;
    swzdec<75, 2>(bx, by, bz);
    const int sel = bz >> 3;
    const unsigned short* qb = sel ? qbB : qbA;
    const unsigned short* kb = sel ? kbB : kbA;
    const unsigned short* vf = sel ? vfB : vfA;
    float* rs = sel ? rsB : rsA;
    float* T = sel ? (by ? TB1 : TB0) : (by ? TA1 : TA0);
    const int lane = threadIdx.x & 63;
    const int wid = threadIdx.x >> 6;
    const int h = bz & 7;
    const int n0 = bx * 64 + wid * 32;
    const int lr = lane & 31, hi5 = lane >> 5;
    const int hbase = h * N_TOK;
    // Q as B operand (hoisted across the m-loop)
    const unsigned short* qp = qb + (hbase + n0 + lr) * HD + 8 * hi5;
    const s8v bQ0 = *(const s8v*)(qp);
    const s8v bQ1 = *(const s8v*)(qp + 16);
    f32x16 t0 = {}, t1 = {};
    float rsa = 0.f, rsb = 0.f;
    const int mt0 = by * 75;
    const unsigned short* kp = kb + (hbase + mt0 * 32 + lr) * HD + 8 * hi5;
    const unsigned short* vp = vf + ((size_t)(h * NTILES) + mt0) * FRAG + lane * 8;
    s8v a0 = *(const s8v*)(kp);
    s8v a1 = *(const s8v*)(kp + 16);
    s8v v00 = *(const s8v*)(vp);
    s8v v01 = *(const s8v*)(vp + 512);
    s8v v10 = *(const s8v*)(vp + 1024);
    s8v v11 = *(const s8v*)(vp + 1536);
#pragma unroll 3
    for (int it = 0; it < 75; ++it) {
        // prefetch next tile's K and V fragments (all coalesced 1KiB loads)
        const int adv = (it < 74) ? 1 : 0;
        const unsigned short* kpn = kp + adv * 32 * HD;
        const unsigned short* vpn = vp + adv * FRAG;
        const s8v na0 = *(const s8v*)(kpn);
        const s8v na1 = *(const s8v*)(kpn + 16);
        const s8v nv00 = *(const s8v*)(vpn);
        const s8v nv01 = *(const s8v*)(vpn + 512);
        const s8v nv10 = *(const s8v*)(vpn + 1024);
        const s8v nv11 = *(const s8v*)(vpn + 1536);
        f32x16 s = {};
        s = MFMA(a0, bQ0, s);
        s = MFMA(a1, bQ1, s);
        float p[16];
#pragma unroll
        for (int r = 0; r < 16; r += 2) {
            const float e0 = EXP2F(s[r]);
            const float e1 = EXP2F(s[r + 1]);
            rsa += e0; rsb += e1;
            p[r] = e0 * e0; p[r + 1] = e1 * e1;
        }
        const int L0 = cvtpk(p[0], p[1]),   L1 = cvtpk(p[2], p[3]);
        const int H0 = cvtpk(p[4], p[5]),   H1 = cvtpk(p[6], p[7]);
        const int L2 = cvtpk(p[8], p[9]),   L3 = cvtpk(p[10], p[11]);
        const int H2 = cvtpk(p[12], p[13]), H3 = cvtpk(p[14], p[15]);
        const i2v s0 = __builtin_amdgcn_permlane32_swap(L0, H0, false, false);
        const i2v s1 = __builtin_amdgcn_permlane32_swap(L1, H1, false, false);
        const i2v s2 = __builtin_amdgcn_permlane32_swap(L2, H2, false, false);
        const i2v s3 = __builtin_amdgcn_permlane32_swap(L3, H3, false, false);
        const s8v pa0 = mk_s8(s0[0], s1[0], s0[1], s1[1]);   // k = 0..15
        const s8v pa1 = mk_s8(s2[0], s3[0], s2[1], s3[1]);   // k = 16..31
        t0 = MFMA(pa0, v00, t0);
        t0 = MFMA(pa1, v01, t0);
        t1 = MFMA(pa0, v10, t1);
        t1 = MFMA(pa1, v11, t1);
        a0 = na0; a1 = na1; kp = kpn;
        v00 = nv00; v01 = nv01; v10 = nv10; v11 = nv11; vp = vpn;
    }
    float rsacc = rsa + rsb;
    rsacc += __shfl_xor(rsacc, 32);
    if (lane < 32) atomicAdd(&rs[hbase + n0 + lane], rsacc);
#pragma unroll
    for (int r = 0; r < 16; ++r) {
        const int n = n0 + (r & 3) + 8 * (r >> 2) + 4 * hi5;
        T[(size_t)(hbase + n) * DP + lr] = t0[r];
    }
    if (lr < 8) {
#pragma unroll
        for (int r = 0; r < 16; ++r) {
            const int n = n0 + (r & 3) + 8 * (r >> 2) + 4 * hi5;
            T[(size_t)(hbase + n) * DP + 32 + lr] = t1[r];
        }
    }
}

// ---------------------------------------------------------------------------
// f[h,c,d] = sum_n (vc[n,c]/rs[n]) * (T0'[n,d]+T1'[n,d]) per 64-row chunk.
// Both fundamentals: grid (16, 75).
// ---------------------------------------------------------------------------
__global__ __launch_bounds__(256) void fgemm_kernel(
    const float* __restrict__ VCA, const float* __restrict__ rsA,
    const float* __restrict__ TA0, const float* __restrict__ TA1,
    float* __restrict__ fA,
    const float* __restrict__ VCB, const float* __restrict__ rsB,
    const float* __restrict__ TB0, const float* __restrict__ TB1,
    float* __restrict__ fB)
{
    const int sel = blockIdx.x >> 3;
    const float* VC = sel ? VCB : VCA;
    const float* rs = sel ? rsB : rsA;
    const float* Ta = sel ? TB0 : TA0;
    const float* Tb = sel ? TB1 : TA1;
    float* f = sel ? fB : fA;
    __shared__ __align__(16) float wvcl[64 * DP];
    __shared__ __align__(16) float tl[64 * DP];
    __shared__ float wl[64];
    const int h = blockIdx.x & 7, n0 = blockIdx.y * 64;
    const int t = threadIdx.x;
    if (t < 64) wl[t] = 1.0f / rs[(size_t)h * N_TOK + n0 + t];
    __syncthreads();
    const float* vcbase = VC + (size_t)(h * N_TOK + n0) * DP;
    const float* tabase = Ta + (size_t)(h * N_TOK + n0) * DP;
    const float* tbbase = Tb + (size_t)(h * N_TOK + n0) * DP;
    for (int e = t; e < 64 * DP; e += 256) {
        wvcl[e] = vcbase[e] * wl[e / DP];
        tl[e] = tabase[e] + tbbase[e];
    }
    __syncthreads();
    for (int p = t; p < DD * DD; p += 256) {
        const int c = p / DD, d = p % DD;
        float s = 0.f;
#pragma unroll 8
        for (int n = 0; n < 64; ++n) s += wvcl[n * DP + c] * tl[n * DP + d];
        atomicAdd(&f[(size_t)(h * DD + c) * DP + d], s);
    }
}

// ---------------------------------------------------------------------------
// out[d,e] = sum_j f[j,d] * proj_w[e,j] + proj_b[e]. Both fundamentals:
// grid (38, 2); y=0 -> f1 -> out+DD*256, y=1 -> f2 -> out.
// ---------------------------------------------------------------------------
__global__ __launch_bounds__(256) void out_kernel(
    const float* __restrict__ f1, const float* __restrict__ f2,
    const float* __restrict__ pw, const float* __restrict__ pb,
    float* __restrict__ out)
{
    const int sel = blockIdx.y;
    const float* f = sel ? f2 : f1;
    float* dst = sel ? out : (out + DD * 256);
    __shared__ __align__(16) float flds[304];
    const int d = blockIdx.x, t = threadIdx.x;
    for (int j = t; j < 304; j += 256) flds[j] = f[(size_t)j * DP + d];
    __syncthreads();
    float acc = pb[t];
    const float* pwrow = pw + (size_t)t * 304;
#pragma unroll 4
    for (int j = 0; j < 304; j += 4) {
        const float4 p4 = *(const float4*)&pwrow[j];
        const float4 f4 = *(const float4*)&flds[j];
        acc += p4.x * f4.x + p4.y * f4.y + p4.z * f4.z + p4.w * f4.w;
    }
    dst[(size_t)d * 256 + t] = acc;
}

extern "C" void kernel_launch(void* const* d_in, const int* in_sizes, int n_in,
                              void* d_out, int out_size, void* d_ws, size_t ws_size,
                              hipStream_t stream)
{
    const float* x1 = (const float*)d_in[0];
    const float* x2 = (const float*)d_in[1];
    const float* qkv_w = (const float*)d_in[2];
    const float* proj_w = (const float*)d_in[3];
    const float* proj_b = (const float*)d_in[4];
    float* out = (float*)d_out;

    const size_t QSZ = (size_t)NH * N_TOK * HD;          // 1,228,800
    const size_t VSZ = (size_t)NH * N_TOK * DP;          // 1,536,000
    const size_t SSZ = (size_t)NH * N_TOK;               //    38,400
    const size_t FSZ = (size_t)NH * DD * DP;             //    12,160
    const size_t XSZ = (size_t)N_TOK * 256;              // 1,228,800
    const size_t WSZ = (size_t)768 * 256;                //   196,608
    const size_t VTSZ = (size_t)NH * NTILES * FRAG;      // 2,457,600

    // fp32 region
    float* vc1 = (float*)d_ws;
    float* vc2 = vc1 + VSZ;
    float* rs1 = vc2 + VSZ;   // zeroed region starts here
    float* cs1 = rs1 + SSZ;
    float* rs2 = cs1 + SSZ;
    float* cs2 = rs2 + SSZ;
    float* f1 = cs2 + SSZ;
    float* f2 = f1 + FSZ;     // zeroed region ends at f2 + FSZ
    float* T1a = f2 + FSZ;    // T partials: fully overwritten, no init needed
    float* T1b = T1a + VSZ;
    float* T2a = T1b + VSZ;
    float* T2b = T2a + VSZ;
    // bf16 region
    unsigned short* xh1 = (unsigned short*)(T2b + VSZ);
    unsigned short* xl1 = xh1 + XSZ;
    unsigned short* xh2 = xl1 + XSZ;
    unsigned short* xl2 = xh2 + XSZ;
    unsigned short* wh = xl2 + XSZ;
    unsigned short* wl = wh + WSZ;
    unsigned short* qb1 = wl + WSZ;
    unsigned short* kb1 = qb1 + QSZ;
    unsigned short* qb2 = kb1 + QSZ;
    unsigned short* kb2 = qb2 + QSZ;
    unsigned short* vf1 = kb2 + QSZ;
    unsigned short* vf2 = vf1 + VTSZ;

    const size_t zbytes = (4 * SSZ + 2 * FSZ) * sizeof(float);
    hipMemsetAsync(rs1, 0, zbytes, stream);

    split2_kernel<<<2400, 256, 0, stream>>>(x1, xh1, xl1, x2, xh2, xl2,
                                            (int)(XSZ / 4));
    split_kernel<<<192, 256, 0, stream>>>(qkv_w, wh, wl, (int)(WSZ / 4));

    qkv_mfma_kernel<<<dim3(75, 24, 2), 128, 0, stream>>>(
        xh1, xl1, qb1, kb1, vc1, xh2, xl2, qb2, kb2, vc2, wh, wl);
    pos_kernel<<<19, 256, 0, stream>>>(vc1, vc2);

    // fundamental_1 = f(q2, k1, vc1); fundamental_2 = f(q1, k2, vc2)
    cs_kernel<<<dim3(75, 5, 16), 128, 0, stream>>>(qb2, kb1, cs1,
                                                   qb1, kb2, cs2);
    vfrag_kernel<<<dim3(150, 16), 256, 0, stream>>>(vc1, cs1, vf1,
                                                    vc2, cs2, vf2);
    tprime_mfma_kernel<<<dim3(75, 2, 16), 128, 0, stream>>>(
        qb2, kb1, vf1, rs1, T1a, T1b,
        qb1, kb2, vf2, rs2, T2a, T2b);
    fgemm_kernel<<<dim3(16, 75), 256, 0, stream>>>(vc1, rs1, T1a, T1b, f1,
                                                   vc2, rs2, T2a, T2b, f2);
    out_kernel<<<dim3(38, 2), 256, 0, stream>>>(f1, f2, proj_w, proj_b, out);
}

// Round 6
// 244.309 us; speedup vs baseline: 6.4576x; 1.4381x over previous
//
#include <hip/hip_runtime.h>
#include <stdint.h>
#include <math.h>

#define N_TOK 4800
#define NH 8
#define HD 32
#define DP 40          // padded vc/T' leading dim (D=38 -> 40)
#define DD 38
#define NTILES 150     // 32-wide m tiles
#define MCHUNK 3       // m-chunks in tprime (50 tiles each)
#define FRAG 2048      // shorts per (h,mtile) fragment: 4 blocks x 64 lanes x 8
#define SCALE 0.17677669529663687f            // 32^-0.5
#define QSCALE (0.17677669529663687f * 1.4426950408889634f)  // SCALE*log2(e)

typedef float f32x16 __attribute__((ext_vector_type(16)));
typedef short s8v __attribute__((ext_vector_type(8)));
typedef int i2v __attribute__((ext_vector_type(2)));

#if __has_builtin(__builtin_amdgcn_exp2f)
#define EXP2F(x) __builtin_amdgcn_exp2f(x)
#else
#define EXP2F(x) exp2f(x)
#endif

__device__ __forceinline__ unsigned short f2bf(float x) {
    union { float f; uint32_t u; } v; v.f = x;
    uint32_t r = v.u + 0x7FFFu + ((v.u >> 16) & 1u);
    return (unsigned short)(r >> 16);
}
__device__ __forceinline__ float bf2f(unsigned short h) {
    union { uint32_t u; float f; } v; v.u = ((uint32_t)h) << 16;
    return v.f;
}
__device__ __forceinline__ int cvtpk(float lo, float hi) {
    int r;
    asm("v_cvt_pk_bf16_f32 %0, %1, %2" : "=v"(r) : "v"(lo), "v"(hi));
    return r;
}
__device__ __forceinline__ s8v mk_s8(int a, int b, int c, int d) {
    union { int i[4]; s8v s; } u;
    u.i[0] = a; u.i[1] = b; u.i[2] = c; u.i[3] = d;
    return u.s;
}

// bijective XCD-aware block remap: blocks sharing a (y,z) work-group stay on
// one XCD (total blocks % 8 == 0 in all uses).
template<int NX, int NY>
__device__ __forceinline__ void swzdec(int& x, int& y, int& z) {
    const int L = blockIdx.x + NX * (blockIdx.y + NY * blockIdx.z);
    constexpr int cpx = NX * NY * 16 / 8;
    const int s = (L & 7) * cpx + (L >> 3);
    x = s % NX;
    const int r = s / NX;
    y = r % NY;
    z = r / NY;
}

#define MFMA(a, b, c) __builtin_amdgcn_mfma_f32_32x32x16_bf16((a), (b), (c), 0, 0, 0)

// ---------------------------------------------------------------------------
// fp32 [R][256] -> fragment-major bf16 hi/lo: [tile][c(16)][hi5(2)][lr(32)][8]
// so qkv MFMA loads are contiguous 1KiB wave-loads. Handles x1, x2, w in one
// launch: grid (150 + 150 + 24).
// ---------------------------------------------------------------------------
__global__ __launch_bounds__(256) void frag_kernel(
    const float* __restrict__ x1, unsigned short* __restrict__ xh1,
    unsigned short* __restrict__ xl1,
    const float* __restrict__ x2, unsigned short* __restrict__ xh2,
    unsigned short* __restrict__ xl2,
    const float* __restrict__ w, unsigned short* __restrict__ wh,
    unsigned short* __restrict__ wl)
{
    int b = blockIdx.x;
    const float* src; unsigned short* dh; unsigned short* dl;
    if (b < 150)      { src = x1 + b * 8192; dh = xh1 + b * 8192; dl = xl1 + b * 8192; }
    else if (b < 300) { b -= 150; src = x2 + b * 8192; dh = xh2 + b * 8192; dl = xl2 + b * 8192; }
    else              { b -= 300; src = w + b * 8192; dh = wh + b * 8192; dl = wl + b * 8192; }
    const int t = threadIdx.x;
#pragma unroll
    for (int k = 0; k < 4; ++k) {
        const int f = k * 256 + t;            // 16B-chunk index, 1024 per tile
        const int c = f >> 6;
        const int rem = f & 63;
        const int hi5 = rem >> 5, lr = rem & 31;
        const float* sp = src + lr * 256 + c * 16 + hi5 * 8;
        const float4 a = *(const float4*)(sp);
        const float4 bb = *(const float4*)(sp + 4);
        const float vv[8] = {a.x, a.y, a.z, a.w, bb.x, bb.y, bb.z, bb.w};
        union { unsigned short s[8]; s8v v; } H, L;
#pragma unroll
        for (int j = 0; j < 8; ++j) {
            H.s[j] = f2bf(vv[j]);
            L.s[j] = f2bf(vv[j] - bf2f(H.s[j]));
        }
        *(s8v*)(dh + f * 8) = H.v;
        *(s8v*)(dl + f * 8) = L.v;
    }
}

// ---------------------------------------------------------------------------
// QKV GEMM via split-bf16 MFMA on fragment-major inputs; both tensors in one
// launch (blockIdx.z). Epilogue: q -> bf16 scaled; k -> bf16; v -> vc fp32.
// ---------------------------------------------------------------------------
__global__ __launch_bounds__(128) void qkv_mfma_kernel(
    const unsigned short* __restrict__ xhA, const unsigned short* __restrict__ xlA,
    unsigned short* __restrict__ qbA, unsigned short* __restrict__ kbA,
    float* __restrict__ vcbA,
    const unsigned short* __restrict__ xhB, const unsigned short* __restrict__ xlB,
    unsigned short* __restrict__ qbB, unsigned short* __restrict__ kbB,
    float* __restrict__ vcbB,
    const unsigned short* __restrict__ wh, const unsigned short* __restrict__ wl)
{
    const int sel = blockIdx.z;
    const unsigned short* xh = sel ? xhB : xhA;
    const unsigned short* xl = sel ? xlB : xlA;
    unsigned short* qb = sel ? qbB : qbA;
    unsigned short* kb = sel ? kbB : kbA;
    float* vcb = sel ? vcbB : vcbA;
    const int lane = threadIdx.x & 63;
    const int wid = threadIdx.x >> 6;
    const int xtile = blockIdx.x * 2 + wid;
    const int n0 = xtile * 32;
    const int j0 = blockIdx.y * 32;
    const int lr = lane & 31, hi5 = lane >> 5;
    const unsigned short* xhp = xh + (size_t)xtile * 8192 + lane * 8;
    const unsigned short* xlp = xl + (size_t)xtile * 8192 + lane * 8;
    const unsigned short* whp = wh + (size_t)blockIdx.y * 8192 + lane * 8;
    const unsigned short* wlp = wl + (size_t)blockIdx.y * 8192 + lane * 8;
    f32x16 acc = {};
#pragma unroll 4
    for (int c = 0; c < 16; ++c) {
        const s8v aH = *(const s8v*)(xhp + c * 512);
        const s8v aL = *(const s8v*)(xlp + c * 512);
        const s8v bH = *(const s8v*)(whp + c * 512);
        const s8v bL = *(const s8v*)(wlp + c * 512);
        acc = MFMA(aH, bH, acc);
        acc = MFMA(aH, bL, acc);
        acc = MFMA(aL, bH, acc);
    }
    const int s = j0 >> 8, h = (j0 >> 5) & 7, d = lr;
#pragma unroll
    for (int r = 0; r < 16; ++r) {
        const int n = n0 + (r & 3) + 8 * (r >> 2) + 4 * hi5;
        const float v = acc[r];
        if (s == 2)      vcb[(h * N_TOK + n) * DP + d] = v;
        else if (s == 0) qb[(h * N_TOK + n) * HD + d] = f2bf(v * QSCALE);
        else             kb[(h * N_TOK + n) * HD + d] = f2bf(v);
    }
}

// ---------------------------------------------------------------------------
// Fill vc[..., 32:40] with positional encodings (cols 38,39 zero pad).
// ---------------------------------------------------------------------------
__global__ void pos_kernel(float* __restrict__ vc1, float* __restrict__ vc2)
{
    const int n = blockIdx.x * 256 + threadIdx.x;
    if (n >= N_TOK) return;
    const int row = n / 80, col = n % 80;
    const float y = -1.0f + 2.0f * (float)row / 59.0f;
    const float x = -1.0f + 2.0f * (float)col / 79.0f;
    const float p3 = y * (240.0f / 517.0f);
    const float p4 = x * (360.0f / 517.0f);
    const float pv[8] = {p3 * p3, p4 * p4, p3 * p4, p3, p4, 1.0f, 0.0f, 0.0f};
#pragma unroll
    for (int h = 0; h < NH; ++h) {
        const size_t base = (size_t)(h * N_TOK + n) * DP + 32;
#pragma unroll
        for (int p = 0; p < 8; ++p) {
            vc1[base + p] = pv[p];
            vc2[base + p] = pv[p];
        }
    }
}

// ---------------------------------------------------------------------------
// Pass 1 (both fundamentals): S' = Q'.K^T via bf16 MFMA; cs[m] += sum_n 2^S'.
// grid (75 m-blocks, 5 n-chunks, 16), XCD-swizzled. 128 threads (2 waves).
// ---------------------------------------------------------------------------
__global__ __launch_bounds__(128) void cs_kernel(
    const unsigned short* __restrict__ qbA, const unsigned short* __restrict__ kbA,
    float* __restrict__ csA,
    const unsigned short* __restrict__ qbB, const unsigned short* __restrict__ kbB,
    float* __restrict__ csB)
{
    int bx, by, bz;
    swzdec<75, 5>(bx, by, bz);
    const int sel = bz >> 3;
    const unsigned short* qb = sel ? qbB : qbA;
    const unsigned short* kb = sel ? kbB : kbA;
    float* cs = sel ? csB : csA;
    const int lane = threadIdx.x & 63;
    const int wid = threadIdx.x >> 6;
    const int h = bz & 7;
    const int m0 = bx * 64 + wid * 32;
    const int lr = lane & 31, hi5 = lane >> 5;
    const int hbase = h * N_TOK;
    const unsigned short* kp = kb + (hbase + m0 + lr) * HD + 8 * hi5;
    const s8v bK0 = *(const s8v*)(kp);
    const s8v bK1 = *(const s8v*)(kp + 16);
    const int nt0 = by * 30;
    const unsigned short* qp = qb + (hbase + nt0 * 32 + lr) * HD + 8 * hi5;
    s8v a0 = *(const s8v*)(qp);
    s8v a1 = *(const s8v*)(qp + 16);
    float csa = 0.f, csb = 0.f;
#pragma unroll 2
    for (int it = 0; it < 30; ++it) {
        const int adv = (it < 29) ? (32 * HD) : 0;
        const unsigned short* qpn = qp + adv;
        const s8v na0 = *(const s8v*)(qpn);
        const s8v na1 = *(const s8v*)(qpn + 16);
        f32x16 acc = {};
        acc = MFMA(a0, bK0, acc);
        acc = MFMA(a1, bK1, acc);
#pragma unroll
        for (int r = 0; r < 16; r += 2) {
            csa += EXP2F(acc[r]);
            csb += EXP2F(acc[r + 1]);
        }
        a0 = na0; a1 = na1; qp = qpn;
    }
    float csacc = csa + csb;
    csacc += __shfl_xor(csacc, 32);
    if (lane < 32) atomicAdd(&cs[hbase + m0 + lane], csacc);
}

// ---------------------------------------------------------------------------
// vc fp32 [h][4800][40] + u=1/cs -> fragment-major bf16 vfrag layout:
// [h][mtile][b][lane][8], b: (d-half, k-half) so tprime loads are 1KiB/instr.
// Both fundamentals: grid (150, 16), 256 threads.
// ---------------------------------------------------------------------------
__global__ __launch_bounds__(256) void vfrag_kernel(
    const float* __restrict__ vcA, const float* __restrict__ csA,
    unsigned short* __restrict__ vfA,
    const float* __restrict__ vcB, const float* __restrict__ csB,
    unsigned short* __restrict__ vfB)
{
    const int sel = blockIdx.y >> 3;
    const float* vc = sel ? vcB : vcA;
    const float* cs = sel ? csB : csA;
    unsigned short* vf = sel ? vfB : vfA;
    __shared__ float vl[32][41];
    __shared__ float ul[32];
    const int mt = blockIdx.x;
    const int h = blockIdx.y & 7;
    const int t = threadIdx.x;
    const int m0 = mt * 32;
    const float* vcbase = vc + (size_t)(h * N_TOK + m0) * DP;
    for (int e = t; e < 32 * DP; e += 256) vl[e / DP][e % DP] = vcbase[e];
    if (t < 32) ul[t] = 1.0f / cs[(size_t)h * N_TOK + m0 + t];
    __syncthreads();
    const int b = t >> 6, lane = t & 63;
    const int hi5 = lane >> 5, lr = lane & 31;
    const int d = (b >> 1) * 32 + lr;       // 0..63 (>=40 zero pad)
    const int mb = (b & 1) * 16 + hi5 * 8;  // k-offset within tile
    union { unsigned short s[8]; s8v v; } pk;
#pragma unroll
    for (int j = 0; j < 8; ++j) {
        const int mo = mb + j;
        const float v = (d < DP) ? vl[mo][d] * ul[mo] : 0.0f;
        pk.s[j] = f2bf(v);
    }
    *(s8v*)(vf + ((size_t)(h * NTILES + mt) * 4 + b) * 512 + lane * 8) = pk.v;
}

// ---------------------------------------------------------------------------
// Pass 2 (both fundamentals): S'^T = K.Q'^T; e = 2^S'; rs += e in-lane;
// P' = e*e packed in-register; T' += P'.vfrag via MFMA. 3 m-chunks (50 tiles)
// with separate T partial buffers (plain stores, no atomics).
// grid (75 n-blocks, 3 m-chunks, 16), XCD-swizzled. 128 threads (2 waves).
// ---------------------------------------------------------------------------
__global__ __launch_bounds__(128, 3) void tprime_mfma_kernel(
    const unsigned short* __restrict__ qbA, const unsigned short* __restrict__ kbA,
    const unsigned short* __restrict__ vfA, float* __restrict__ rsA,
    float* __restrict__ TA0, float* __restrict__ TA1, float* __restrict__ TA2,
    const unsigned short* __restrict__ qbB, const unsigned short* __restrict__ kbB,
    const unsigned short* __restrict__ vfB, float* __restrict__ rsB,
    float* __restrict__ TB0, float* __restrict__ TB1, float* __restrict__ TB2)
{
    int bx, by, bz;
    swzdec<75, MCHUNK>(bx, by, bz);
    const int sel = bz >> 3;
    const unsigned short* qb = sel ? qbB : qbA;
    const unsigned short* kb = sel ? kbB : kbA;
    const unsigned short* vf = sel ? vfB : vfA;
    float* rs = sel ? rsB : rsA;
    float* T = sel ? (by == 0 ? TB0 : (by == 1 ? TB1 : TB2))
                   : (by == 0 ? TA0 : (by == 1 ? TA1 : TA2));
    const int lane = threadIdx.x & 63;
    const int wid = threadIdx.x >> 6;
    const int h = bz & 7;
    const int n0 = bx * 64 + wid * 32;
    const int lr = lane & 31, hi5 = lane >> 5;
    const int hbase = h * N_TOK;
    // Q as B operand (hoisted across the m-loop)
    const unsigned short* qp = qb + (hbase + n0 + lr) * HD + 8 * hi5;
    const s8v bQ0 = *(const s8v*)(qp);
    const s8v bQ1 = *(const s8v*)(qp + 16);
    f32x16 t0 = {}, t1 = {};
    float rsa = 0.f, rsb = 0.f;
    const int mt0 = by * 50;
    const unsigned short* kp = kb + (hbase + mt0 * 32 + lr) * HD + 8 * hi5;
    const unsigned short* vp = vf + ((size_t)(h * NTILES) + mt0) * FRAG + lane * 8;
    s8v a0 = *(const s8v*)(kp);
    s8v a1 = *(const s8v*)(kp + 16);
    s8v v00 = *(const s8v*)(vp);
    s8v v01 = *(const s8v*)(vp + 512);
    s8v v10 = *(const s8v*)(vp + 1024);
    s8v v11 = *(const s8v*)(vp + 1536);
#pragma unroll 2
    for (int it = 0; it < 50; ++it) {
        // prefetch next tile's K and V fragments (all coalesced 1KiB loads)
        const int adv = (it < 49) ? 1 : 0;
        const unsigned short* kpn = kp + adv * 32 * HD;
        const unsigned short* vpn = vp + adv * FRAG;
        const s8v na0 = *(const s8v*)(kpn);
        const s8v na1 = *(const s8v*)(kpn + 16);
        const s8v nv00 = *(const s8v*)(vpn);
        const s8v nv01 = *(const s8v*)(vpn + 512);
        const s8v nv10 = *(const s8v*)(vpn + 1024);
        const s8v nv11 = *(const s8v*)(vpn + 1536);
        f32x16 s = {};
        s = MFMA(a0, bQ0, s);
        s = MFMA(a1, bQ1, s);
        float p[16];
#pragma unroll
        for (int r = 0; r < 16; r += 2) {
            const float e0 = EXP2F(s[r]);
            const float e1 = EXP2F(s[r + 1]);
            rsa += e0; rsb += e1;
            p[r] = e0 * e0; p[r + 1] = e1 * e1;
        }
        const int L0 = cvtpk(p[0], p[1]),   L1 = cvtpk(p[2], p[3]);
        const int H0 = cvtpk(p[4], p[5]),   H1 = cvtpk(p[6], p[7]);
        const int L2 = cvtpk(p[8], p[9]),   L3 = cvtpk(p[10], p[11]);
        const int H2 = cvtpk(p[12], p[13]), H3 = cvtpk(p[14], p[15]);
        const i2v s0 = __builtin_amdgcn_permlane32_swap(L0, H0, false, false);
        const i2v s1 = __builtin_amdgcn_permlane32_swap(L1, H1, false, false);
        const i2v s2 = __builtin_amdgcn_permlane32_swap(L2, H2, false, false);
        const i2v s3 = __builtin_amdgcn_permlane32_swap(L3, H3, false, false);
        const s8v pa0 = mk_s8(s0[0], s1[0], s0[1], s1[1]);   // k = 0..15
        const s8v pa1 = mk_s8(s2[0], s3[0], s2[1], s3[1]);   // k = 16..31
        __builtin_amdgcn_s_setprio(1);
        t0 = MFMA(pa0, v00, t0);
        t0 = MFMA(pa1, v01, t0);
        t1 = MFMA(pa0, v10, t1);
        t1 = MFMA(pa1, v11, t1);
        __builtin_amdgcn_s_setprio(0);
        a0 = na0; a1 = na1; kp = kpn;
        v00 = nv00; v01 = nv01; v10 = nv10; v11 = nv11; vp = vpn;
    }
    float rsacc = rsa + rsb;
    rsacc += __shfl_xor(rsacc, 32);
    if (lane < 32) atomicAdd(&rs[hbase + n0 + lane], rsacc);
#pragma unroll
    for (int r = 0; r < 16; ++r) {
        const int n = n0 + (r & 3) + 8 * (r >> 2) + 4 * hi5;
        T[(size_t)(hbase + n) * DP + lr] = t0[r];
    }
    if (lr < 8) {
#pragma unroll
        for (int r = 0; r < 16; ++r) {
            const int n = n0 + (r & 3) + 8 * (r >> 2) + 4 * hi5;
            T[(size_t)(hbase + n) * DP + 32 + lr] = t1[r];
        }
    }
}

// ---------------------------------------------------------------------------
// f[h,c,d] = sum_n (vc[n,c]/rs[n]) * (T0'+T1'+T2')[n,d] per 64-row chunk.
// Both fundamentals: grid (16, 75).
// ---------------------------------------------------------------------------
__global__ __launch_bounds__(256) void fgemm_kernel(
    const float* __restrict__ VCA, const float* __restrict__ rsA,
    const float* __restrict__ TA0, const float* __restrict__ TA1,
    const float* __restrict__ TA2, float* __restrict__ fA,
    const float* __restrict__ VCB, const float* __restrict__ rsB,
    const float* __restrict__ TB0, const float* __restrict__ TB1,
    const float* __restrict__ TB2, float* __restrict__ fB)
{
    const int sel = blockIdx.x >> 3;
    const float* VC = sel ? VCB : VCA;
    const float* rs = sel ? rsB : rsA;
    const float* Ta = sel ? TB0 : TA0;
    const float* Tb = sel ? TB1 : TA1;
    const float* Tc = sel ? TB2 : TA2;
    float* f = sel ? fB : fA;
    __shared__ __align__(16) float wvcl[64 * DP];
    __shared__ __align__(16) float tl[64 * DP];
    __shared__ float wl[64];
    const int h = blockIdx.x & 7, n0 = blockIdx.y * 64;
    const int t = threadIdx.x;
    if (t < 64) wl[t] = 1.0f / rs[(size_t)h * N_TOK + n0 + t];
    __syncthreads();
    const float* vcbase = VC + (size_t)(h * N_TOK + n0) * DP;
    const float* tabase = Ta + (size_t)(h * N_TOK + n0) * DP;
    const float* tbbase = Tb + (size_t)(h * N_TOK + n0) * DP;
    const float* tcbase = Tc + (size_t)(h * N_TOK + n0) * DP;
    for (int e = t; e < 64 * DP; e += 256) {
        wvcl[e] = vcbase[e] * wl[e / DP];
        tl[e] = tabase[e] + tbbase[e] + tcbase[e];
    }
    __syncthreads();
    for (int p = t; p < DD * DD; p += 256) {
        const int c = p / DD, d = p % DD;
        float s = 0.f;
#pragma unroll 8
        for (int n = 0; n < 64; ++n) s += wvcl[n * DP + c] * tl[n * DP + d];
        atomicAdd(&f[(size_t)(h * DD + c) * DP + d], s);
    }
}

// ---------------------------------------------------------------------------
// out[d,e] = sum_j f[j,d] * proj_w[e,j] + proj_b[e]. Both fundamentals:
// grid (38, 2); y=0 -> f1 -> out+DD*256, y=1 -> f2 -> out.
// ---------------------------------------------------------------------------
__global__ __launch_bounds__(256) void out_kernel(
    const float* __restrict__ f1, const float* __restrict__ f2,
    const float* __restrict__ pw, const float* __restrict__ pb,
    float* __restrict__ out)
{
    const int sel = blockIdx.y;
    const float* f = sel ? f2 : f1;
    float* dst = sel ? out : (out + DD * 256);
    __shared__ __align__(16) float flds[304];
    const int d = blockIdx.x, t = threadIdx.x;
    for (int j = t; j < 304; j += 256) flds[j] = f[(size_t)j * DP + d];
    __syncthreads();
    float acc = pb[t];
    const float* pwrow = pw + (size_t)t * 304;
#pragma unroll 4
    for (int j = 0; j < 304; j += 4) {
        const float4 p4 = *(const float4*)&pwrow[j];
        const float4 f4 = *(const float4*)&flds[j];
        acc += p4.x * f4.x + p4.y * f4.y + p4.z * f4.z + p4.w * f4.w;
    }
    dst[(size_t)d * 256 + t] = acc;
}

extern "C" void kernel_launch(void* const* d_in, const int* in_sizes, int n_in,
                              void* d_out, int out_size, void* d_ws, size_t ws_size,
                              hipStream_t stream)
{
    const float* x1 = (const float*)d_in[0];
    const float* x2 = (const float*)d_in[1];
    const float* qkv_w = (const float*)d_in[2];
    const float* proj_w = (const float*)d_in[3];
    const float* proj_b = (const float*)d_in[4];
    float* out = (float*)d_out;

    const size_t QSZ = (size_t)NH * N_TOK * HD;          // 1,228,800
    const size_t VSZ = (size_t)NH * N_TOK * DP;          // 1,536,000
    const size_t SSZ = (size_t)NH * N_TOK;               //    38,400
    const size_t FSZ = (size_t)NH * DD * DP;             //    12,160
    const size_t XSZ = (size_t)N_TOK * 256;              // 1,228,800
    const size_t WSZ = (size_t)768 * 256;                //   196,608
    const size_t VTSZ = (size_t)NH * NTILES * FRAG;      // 2,457,600

    // fp32 region
    float* vc1 = (float*)d_ws;
    float* vc2 = vc1 + VSZ;
    float* rs1 = vc2 + VSZ;   // zeroed region starts here
    float* cs1 = rs1 + SSZ;
    float* rs2 = cs1 + SSZ;
    float* cs2 = rs2 + SSZ;
    float* f1 = cs2 + SSZ;
    float* f2 = f1 + FSZ;     // zeroed region ends at f2 + FSZ
    float* T1a = f2 + FSZ;    // T partials: fully overwritten, no init needed
    float* T1b = T1a + VSZ;
    float* T1c = T1b + VSZ;
    float* T2a = T1c + VSZ;
    float* T2b = T2a + VSZ;
    float* T2c = T2b + VSZ;
    // bf16 region
    unsigned short* xh1 = (unsigned short*)(T2c + VSZ);
    unsigned short* xl1 = xh1 + XSZ;
    unsigned short* xh2 = xl1 + XSZ;
    unsigned short* xl2 = xh2 + XSZ;
    unsigned short* wh = xl2 + XSZ;
    unsigned short* wl = wh + WSZ;
    unsigned short* qb1 = wl + WSZ;
    unsigned short* kb1 = qb1 + QSZ;
    unsigned short* qb2 = kb1 + QSZ;
    unsigned short* kb2 = qb2 + QSZ;
    unsigned short* vf1 = kb2 + QSZ;
    unsigned short* vf2 = vf1 + VTSZ;

    const size_t zbytes = (4 * SSZ + 2 * FSZ) * sizeof(float);
    hipMemsetAsync(rs1, 0, zbytes, stream);

    frag_kernel<<<324, 256, 0, stream>>>(x1, xh1, xl1, x2, xh2, xl2,
                                         qkv_w, wh, wl);

    qkv_mfma_kernel<<<dim3(75, 24, 2), 128, 0, stream>>>(
        xh1, xl1, qb1, kb1, vc1, xh2, xl2, qb2, kb2, vc2, wh, wl);
    pos_kernel<<<19, 256, 0, stream>>>(vc1, vc2);

    // fundamental_1 = f(q2, k1, vc1); fundamental_2 = f(q1, k2, vc2)
    cs_kernel<<<dim3(75, 5, 16), 128, 0, stream>>>(qb2, kb1, cs1,
                                                   qb1, kb2, cs2);
    vfrag_kernel<<<dim3(150, 16), 256, 0, stream>>>(vc1, cs1, vf1,
                                                    vc2, cs2, vf2);
    tprime_mfma_kernel<<<dim3(75, MCHUNK, 16), 128, 0, stream>>>(
        qb2, kb1, vf1, rs1, T1a, T1b, T1c,
        qb1, kb2, vf2, rs2, T2a, T2b, T2c);
    fgemm_kernel<<<dim3(16, 75), 256, 0, stream>>>(
        vc1, rs1, T1a, T1b, T1c, f1,
        vc2, rs2, T2a, T2b, T2c, f2);
    out_kernel<<<dim3(38, 2), 256, 0, stream>>>(f1, f2, proj_w, proj_b, out);
}

// Round 7
// 230.444 us; speedup vs baseline: 6.8461x; 1.0602x over previous
//
#include <hip/hip_runtime.h>
#include <stdint.h>
#include <math.h>

#define N_TOK 4800
#define NH 8
#define HD 32
#define DP 40          // T' padded leading dim (D=38 -> 40)
#define DD 38
#define NTILES 150     // 32-wide m tiles
#define MCHUNK 3       // m-chunks in tprime (50 tiles each)
#define FRAG 2048      // shorts per (h,mtile) V fragment: 4 blocks x 64 lanes x 8
#define SCALE 0.17677669529663687f            // 32^-0.5
#define QSCALE (0.17677669529663687f * 1.4426950408889634f)  // SCALE*log2(e)

typedef float f32x16 __attribute__((ext_vector_type(16)));
typedef short s8v __attribute__((ext_vector_type(8)));
typedef int i2v __attribute__((ext_vector_type(2)));

#if __has_builtin(__builtin_amdgcn_exp2f)
#define EXP2F(x) __builtin_amdgcn_exp2f(x)
#else
#define EXP2F(x) exp2f(x)
#endif

__device__ __forceinline__ unsigned short f2bf(float x) {
    union { float f; uint32_t u; } v; v.f = x;
    uint32_t r = v.u + 0x7FFFu + ((v.u >> 16) & 1u);
    return (unsigned short)(r >> 16);
}
__device__ __forceinline__ int cvtpk(float lo, float hi) {
    int r;
    asm("v_cvt_pk_bf16_f32 %0, %1, %2" : "=v"(r) : "v"(lo), "v"(hi));
    return r;
}
__device__ __forceinline__ s8v mk_s8(int a, int b, int c, int d) {
    union { int i[4]; s8v s; } u;
    u.i[0] = a; u.i[1] = b; u.i[2] = c; u.i[3] = d;
    return u.s;
}
// positional encoding component idx (0..5) for token m
__device__ __forceinline__ float posv(int m, int idx) {
    const int rrow = m / 80, rcol = m % 80;
    const float y = -1.0f + (float)rrow * (2.0f / 59.0f);
    const float x = -1.0f + (float)rcol * (2.0f / 79.0f);
    const float p3 = y * (240.0f / 517.0f);
    const float p4 = x * (360.0f / 517.0f);
    if (idx == 0) return p3 * p3;
    if (idx == 1) return p4 * p4;
    if (idx == 2) return p3 * p4;
    if (idx == 3) return p3;
    if (idx == 4) return p4;
    return 1.0f;
}

// bijective XCD-aware block remap (total blocks % 8 == 0 in all uses):
// blocks with consecutive bx (sharing by/bz operand streams) stay on one XCD.
template<int NX, int NY, int NZ>
__device__ __forceinline__ void swzdec(int& x, int& y, int& z) {
    const int L = blockIdx.x + NX * (blockIdx.y + NY * blockIdx.z);
    constexpr int cpx = NX * NY * NZ / 8;
    const int s = (L & 7) * cpx + (L >> 3);
    x = s % NX;
    const int r = s / NX;
    y = r % NY;
    z = r / NY;
}

#define MFMA(a, b, c) __builtin_amdgcn_mfma_f32_32x32x16_bf16((a), (b), (c), 0, 0, 0)

// ---------------------------------------------------------------------------
// fp32 [R][256] -> fragment-major bf16: [tile][c(16)][lane(64)][8] so qkv MFMA
// loads are contiguous 1KiB wave-loads. x1 (150 tiles), x2 (150), w (24).
// ---------------------------------------------------------------------------
__global__ __launch_bounds__(256) void frag_kernel(
    const float* __restrict__ x1, unsigned short* __restrict__ xh1,
    const float* __restrict__ x2, unsigned short* __restrict__ xh2,
    const float* __restrict__ w, unsigned short* __restrict__ wh)
{
    int b = blockIdx.x;
    const float* src; unsigned short* dh;
    if (b < 150)      { src = x1 + b * 8192; dh = xh1 + b * 8192; }
    else if (b < 300) { b -= 150; src = x2 + b * 8192; dh = xh2 + b * 8192; }
    else              { b -= 300; src = w + b * 8192; dh = wh + b * 8192; }
    const int t = threadIdx.x;
#pragma unroll
    for (int k = 0; k < 4; ++k) {
        const int f = k * 256 + t;            // 16B-chunk index, 1024 per tile
        const int c = f >> 6;
        const int rem = f & 63;
        const float* sp = src + (rem & 31) * 256 + c * 16 + (rem >> 5) * 8;
        const float4 a = *(const float4*)(sp);
        const float4 bb = *(const float4*)(sp + 4);
        const float vv[8] = {a.x, a.y, a.z, a.w, bb.x, bb.y, bb.z, bb.w};
        union { unsigned short s[8]; s8v v; } H;
#pragma unroll
        for (int j = 0; j < 8; ++j) H.s[j] = f2bf(vv[j]);
        *(s8v*)(dh + f * 8) = H.v;
    }
}

// ---------------------------------------------------------------------------
// QKV GEMM, plain bf16 MFMA on fragment-major inputs. Each wave: one x-tile
// (32 n) x 2 w-tiles (64 j). grid (75, 12, 2) XCD-swizzled, 128 threads.
// Epilogue: q -> bf16 scaled by SCALE*log2e; k -> bf16; v -> vc fp32 [.,0:32].
// ---------------------------------------------------------------------------
__global__ __launch_bounds__(128, 4) void qkv_mfma_kernel(
    const unsigned short* __restrict__ xhA, unsigned short* __restrict__ qbA,
    unsigned short* __restrict__ kbA, float* __restrict__ vcbA,
    const unsigned short* __restrict__ xhB, unsigned short* __restrict__ qbB,
    unsigned short* __restrict__ kbB, float* __restrict__ vcbB,
    const unsigned short* __restrict__ wh)
{
    int bx, by, bz;
    swzdec<75, 12, 2>(bx, by, bz);
    const int sel = bz;
    const unsigned short* xh = sel ? xhB : xhA;
    unsigned short* qb = sel ? qbB : qbA;
    unsigned short* kb = sel ? kbB : kbA;
    float* vcb = sel ? vcbB : vcbA;
    const int lane = threadIdx.x & 63;
    const int wid = threadIdx.x >> 6;
    const int xtile = bx * 2 + wid;
    const unsigned short* xp = xh + (size_t)xtile * 8192 + lane * 8;
    const unsigned short* wp0 = wh + (size_t)(by * 2) * 8192 + lane * 8;
    const unsigned short* wp1 = wp0 + 8192;
    f32x16 acc0 = {}, acc1 = {};
#pragma unroll
    for (int c = 0; c < 16; ++c) {
        const s8v aH = *(const s8v*)(xp + c * 512);
        const s8v b0 = *(const s8v*)(wp0 + c * 512);
        const s8v b1 = *(const s8v*)(wp1 + c * 512);
        acc0 = MFMA(aH, b0, acc0);
        acc1 = MFMA(aH, b1, acc1);
    }
    const int lr = lane & 31, hi5 = lane >> 5;
    {
        const int jt = by * 2, s = jt >> 3, h = jt & 7;
#pragma unroll
        for (int r = 0; r < 16; ++r) {
            const int n = xtile * 32 + (r & 3) + 8 * (r >> 2) + 4 * hi5;
            const float v = acc0[r];
            if (s == 2)      vcb[(h * N_TOK + n) * HD + lr] = v;
            else if (s == 0) qb[(h * N_TOK + n) * HD + lr] = f2bf(v * QSCALE);
            else             kb[(h * N_TOK + n) * HD + lr] = f2bf(v);
        }
    }
    {
        const int jt = by * 2 + 1, s = jt >> 3, h = jt & 7;
#pragma unroll
        for (int r = 0; r < 16; ++r) {
            const int n = xtile * 32 + (r & 3) + 8 * (r >> 2) + 4 * hi5;
            const float v = acc1[r];
            if (s == 2)      vcb[(h * N_TOK + n) * HD + lr] = v;
            else if (s == 0) qb[(h * N_TOK + n) * HD + lr] = f2bf(v * QSCALE);
            else             kb[(h * N_TOK + n) * HD + lr] = f2bf(v);
        }
    }
}

// ---------------------------------------------------------------------------
// Pass 1 (both fundamentals): S' = Q'.K^T via bf16 MFMA; cs[m] += sum_n 2^S'.
// 3-wave blocks (96 m-rows) share the Q stream via L1. grid (50, 5, 16)
// XCD-swizzled, 192 threads. NOTE: last iter prefetches 1 row-tile past the
// q buffer -- layout guarantees the next buffer is allocated (pad rule).
// ---------------------------------------------------------------------------
__global__ __launch_bounds__(192, 4) void cs_kernel(
    const unsigned short* __restrict__ qbA, const unsigned short* __restrict__ kbA,
    float* __restrict__ csA,
    const unsigned short* __restrict__ qbB, const unsigned short* __restrict__ kbB,
    float* __restrict__ csB)
{
    int bx, by, bz;
    swzdec<50, 5, 16>(bx, by, bz);
    const int sel = bz >> 3;
    const unsigned short* qb = sel ? qbB : qbA;
    const unsigned short* kb = sel ? kbB : kbA;
    float* cs = sel ? csB : csA;
    const int lane = threadIdx.x & 63;
    const int wid = threadIdx.x >> 6;
    const int h = bz & 7;
    const int m0 = bx * 96 + wid * 32;
    const int lr = lane & 31, hi5 = lane >> 5;
    const int hbase = h * N_TOK;
    const unsigned short* kp = kb + (hbase + m0 + lr) * HD + 8 * hi5;
    const s8v bK0 = *(const s8v*)(kp);
    const s8v bK1 = *(const s8v*)(kp + 16);
    const unsigned short* qp = qb + (hbase + by * 960 + lr) * HD + 8 * hi5;
    s8v a0 = *(const s8v*)(qp);
    s8v a1 = *(const s8v*)(qp + 16);
    float csa = 0.f, csb = 0.f;
#pragma unroll 2
    for (int it = 0; it < 30; ++it) {
        qp += 32 * HD;
        const s8v na0 = *(const s8v*)(qp);
        const s8v na1 = *(const s8v*)(qp + 16);
        f32x16 acc = {};
        acc = MFMA(a0, bK0, acc);
        acc = MFMA(a1, bK1, acc);
#pragma unroll
        for (int r = 0; r < 16; r += 2) {
            csa += EXP2F(acc[r]);
            csb += EXP2F(acc[r + 1]);
        }
        a0 = na0; a1 = na1;
    }
    float csacc = csa + csb;
    csacc += __shfl_xor(csacc, 32);
    if (lane < 32) atomicAdd(&cs[hbase + m0 + lane], csacc);
}

// ---------------------------------------------------------------------------
// vc fp32 [h][4800][32] + inline pos + u=1/cs -> fragment-major bf16 vfrag
// [h][mtile][b][lane][8]. Both fundamentals: grid (150, 16), 256 threads.
// ---------------------------------------------------------------------------
__global__ __launch_bounds__(256) void vfrag_kernel(
    const float* __restrict__ vcA, const float* __restrict__ csA,
    unsigned short* __restrict__ vfA,
    const float* __restrict__ vcB, const float* __restrict__ csB,
    unsigned short* __restrict__ vfB)
{
    const int sel = blockIdx.y >> 3;
    const float* vc = sel ? vcB : vcA;
    const float* cs = sel ? csB : csA;
    unsigned short* vf = sel ? vfB : vfA;
    __shared__ float vl[32][33];
    __shared__ float ul[32];
    const int mt = blockIdx.x;
    const int h = blockIdx.y & 7;
    const int t = threadIdx.x;
    const int m0 = mt * 32;
    const float* vcbase = vc + (size_t)(h * N_TOK + m0) * HD;
    for (int e = t; e < 32 * HD; e += 256) vl[e >> 5][e & 31] = vcbase[e];
    if (t < 32) ul[t] = 1.0f / cs[(size_t)h * N_TOK + m0 + t];
    __syncthreads();
    const int b = t >> 6, lane = t & 63;
    const int hi5 = lane >> 5, lr = lane & 31;
    const int d = (b >> 1) * 32 + lr;       // 0..63 (>=38 zero pad)
    const int mb = (b & 1) * 16 + hi5 * 8;  // k-offset within tile
    union { unsigned short s[8]; s8v v; } pk;
#pragma unroll
    for (int j = 0; j < 8; ++j) {
        const int mo = mb + j;
        float v;
        if (d < 32)      v = vl[mo][d];
        else if (d < 38) v = posv(m0 + mo, d - 32);
        else             v = 0.0f;
        pk.s[j] = f2bf(v * ul[mo]);
    }
    *(s8v*)(vf + ((size_t)(h * NTILES + mt) * 4 + b) * 512 + lane * 8) = pk.v;
}

// ---------------------------------------------------------------------------
// Pass 2 (both fundamentals): S'^T = K.Q'^T; e = 2^S'; rs += e in-lane;
// P' = e*e packed in-register (cvt_pk + permlane32_swap); T' += P'.vfrag via
// MFMA. 3-wave blocks (96 n) share K/V streams via L1; 3 m-chunks with
// separate T partials (plain stores). grid (50, 3, 16) XCD-swizzled, 192 thr.
// Last iter prefetches 1 tile past the chunk -- buffers padded/ordered for it.
// ---------------------------------------------------------------------------
__global__ __launch_bounds__(192, 4) void tprime_mfma_kernel(
    const unsigned short* __restrict__ qbA, const unsigned short* __restrict__ kbA,
    const unsigned short* __restrict__ vfA, float* __restrict__ rsA,
    float* __restrict__ TA0, float* __restrict__ TA1, float* __restrict__ TA2,
    const unsigned short* __restrict__ qbB, const unsigned short* __restrict__ kbB,
    const unsigned short* __restrict__ vfB, float* __restrict__ rsB,
    float* __restrict__ TB0, float* __restrict__ TB1, float* __restrict__ TB2)
{
    int bx, by, bz;
    swzdec<50, MCHUNK, 16>(bx, by, bz);
    const int sel = bz >> 3;
    const unsigned short* qb = sel ? qbB : qbA;
    const unsigned short* kb = sel ? kbB : kbA;
    const unsigned short* vf = sel ? vfB : vfA;
    float* rs = sel ? rsB : rsA;
    float* T = sel ? (by == 0 ? TB0 : (by == 1 ? TB1 : TB2))
                   : (by == 0 ? TA0 : (by == 1 ? TA1 : TA2));
    const int lane = threadIdx.x & 63;
    const int wid = threadIdx.x >> 6;
    const int h = bz & 7;
    const int n0 = bx * 96 + wid * 32;
    const int lr = lane & 31, hi5 = lane >> 5;
    const int hbase = h * N_TOK;
    // Q as B operand (hoisted across the m-loop)
    const unsigned short* qp = qb + (hbase + n0 + lr) * HD + 8 * hi5;
    const s8v bQ0 = *(const s8v*)(qp);
    const s8v bQ1 = *(const s8v*)(qp + 16);
    f32x16 t0 = {}, t1 = {};
    float rsa = 0.f, rsb = 0.f;
    const int mt0 = by * 50;
    const unsigned short* kp = kb + (hbase + mt0 * 32 + lr) * HD + 8 * hi5;
    const unsigned short* vp = vf + (size_t)(h * NTILES + mt0) * FRAG + lane * 8;
    s8v a0 = *(const s8v*)(kp);
    s8v a1 = *(const s8v*)(kp + 16);
    s8v v00 = *(const s8v*)(vp);
    s8v v01 = *(const s8v*)(vp + 512);
    s8v v10 = *(const s8v*)(vp + 1024);
    s8v v11 = *(const s8v*)(vp + 1536);
#pragma unroll 2
    for (int it = 0; it < 50; ++it) {
        // unconditional next-tile prefetch (coalesced 1KiB loads; pad covers end)
        kp += 32 * HD; vp += FRAG;
        const s8v na0 = *(const s8v*)(kp);
        const s8v na1 = *(const s8v*)(kp + 16);
        const s8v nv00 = *(const s8v*)(vp);
        const s8v nv01 = *(const s8v*)(vp + 512);
        const s8v nv10 = *(const s8v*)(vp + 1024);
        const s8v nv11 = *(const s8v*)(vp + 1536);
        f32x16 s = {};
        s = MFMA(a0, bQ0, s);
        s = MFMA(a1, bQ1, s);
        float p[16];
#pragma unroll
        for (int r = 0; r < 16; r += 2) {
            const float e0 = EXP2F(s[r]);
            const float e1 = EXP2F(s[r + 1]);
            rsa += e0; rsb += e1;
            p[r] = e0 * e0; p[r + 1] = e1 * e1;
        }
        const int L0 = cvtpk(p[0], p[1]),   L1 = cvtpk(p[2], p[3]);
        const int H0 = cvtpk(p[4], p[5]),   H1 = cvtpk(p[6], p[7]);
        const int L2 = cvtpk(p[8], p[9]),   L3 = cvtpk(p[10], p[11]);
        const int H2 = cvtpk(p[12], p[13]), H3 = cvtpk(p[14], p[15]);
        const i2v s0 = __builtin_amdgcn_permlane32_swap(L0, H0, false, false);
        const i2v s1 = __builtin_amdgcn_permlane32_swap(L1, H1, false, false);
        const i2v s2 = __builtin_amdgcn_permlane32_swap(L2, H2, false, false);
        const i2v s3 = __builtin_amdgcn_permlane32_swap(L3, H3, false, false);
        const s8v pa0 = mk_s8(s0[0], s1[0], s0[1], s1[1]);   // k = 0..15
        const s8v pa1 = mk_s8(s2[0], s3[0], s2[1], s3[1]);   // k = 16..31
        __builtin_amdgcn_s_setprio(1);
        t0 = MFMA(pa0, v00, t0);
        t0 = MFMA(pa1, v01, t0);
        t1 = MFMA(pa0, v10, t1);
        t1 = MFMA(pa1, v11, t1);
        __builtin_amdgcn_s_setprio(0);
        a0 = na0; a1 = na1;
        v00 = nv00; v01 = nv01; v10 = nv10; v11 = nv11;
    }
    float rsacc = rsa + rsb;
    rsacc += __shfl_xor(rsacc, 32);
    if (lane < 32) atomicAdd(&rs[hbase + n0 + lane], rsacc);
#pragma unroll
    for (int r = 0; r < 16; ++r) {
        const int n = n0 + (r & 3) + 8 * (r >> 2) + 4 * hi5;
        T[(size_t)(hbase + n) * DP + lr] = t0[r];
    }
    if (lr < 8) {
#pragma unroll
        for (int r = 0; r < 16; ++r) {
            const int n = n0 + (r & 3) + 8 * (r >> 2) + 4 * hi5;
            T[(size_t)(hbase + n) * DP + 32 + lr] = t1[r];
        }
    }
}

// ---------------------------------------------------------------------------
// f[h,c,d] = sum_n (vc[n,c]/rs[n]) * (T0'+T1'+T2')[n,d] per 64-row chunk.
// vc cols 32..37 = inline pos. Both fundamentals: grid (16, 75).
// ---------------------------------------------------------------------------
__global__ __launch_bounds__(256) void fgemm_kernel(
    const float* __restrict__ VCA, const float* __restrict__ rsA,
    const float* __restrict__ TA0, const float* __restrict__ TA1,
    const float* __restrict__ TA2, float* __restrict__ fA,
    const float* __restrict__ VCB, const float* __restrict__ rsB,
    const float* __restrict__ TB0, const float* __restrict__ TB1,
    const float* __restrict__ TB2, float* __restrict__ fB)
{
    const int sel = blockIdx.x >> 3;
    const float* VC = sel ? VCB : VCA;
    const float* rs = sel ? rsB : rsA;
    const float* Ta = sel ? TB0 : TA0;
    const float* Tb = sel ? TB1 : TA1;
    const float* Tc = sel ? TB2 : TA2;
    float* f = sel ? fB : fA;
    __shared__ __align__(16) float wvcl[64 * DP];
    __shared__ __align__(16) float tl[64 * DP];
    __shared__ float wl[64];
    const int h = blockIdx.x & 7, n0 = blockIdx.y * 64;
    const int t = threadIdx.x;
    if (t < 64) wl[t] = 1.0f / rs[(size_t)h * N_TOK + n0 + t];
    __syncthreads();
    const float* vcbase = VC + (size_t)(h * N_TOK + n0) * HD;
    const float* tabase = Ta + (size_t)(h * N_TOK + n0) * DP;
    const float* tbbase = Tb + (size_t)(h * N_TOK + n0) * DP;
    const float* tcbase = Tc + (size_t)(h * N_TOK + n0) * DP;
    for (int e = t; e < 64 * DP; e += 256) {
        const int row = e / DP, c = e - row * DP;
        float v;
        if (c < 32)      v = vcbase[row * HD + c];
        else if (c < 38) v = posv(n0 + row, c - 32);
        else             v = 0.0f;
        wvcl[e] = v * wl[row];
        tl[e] = tabase[e] + tbbase[e] + tcbase[e];
    }
    __syncthreads();
    for (int p = t; p < DD * DD; p += 256) {
        const int c = p / DD, d = p % DD;
        float s = 0.f;
#pragma unroll 8
        for (int n = 0; n < 64; ++n) s += wvcl[n * DP + c] * tl[n * DP + d];
        atomicAdd(&f[(size_t)(h * DD + c) * DP + d], s);
    }
}

// ---------------------------------------------------------------------------
// out[d,e] = sum_j f[j,d] * proj_w[e,j] + proj_b[e]. Both fundamentals:
// grid (38, 2); y=0 -> f1 -> out+DD*256, y=1 -> f2 -> out.
// ---------------------------------------------------------------------------
__global__ __launch_bounds__(256) void out_kernel(
    const float* __restrict__ f1, const float* __restrict__ f2,
    const float* __restrict__ pw, const float* __restrict__ pb,
    float* __restrict__ out)
{
    const int sel = blockIdx.y;
    const float* f = sel ? f2 : f1;
    float* dst = sel ? out : (out + DD * 256);
    __shared__ __align__(16) float flds[304];
    const int d = blockIdx.x, t = threadIdx.x;
    for (int j = t; j < 304; j += 256) flds[j] = f[(size_t)j * DP + d];
    __syncthreads();
    float acc = pb[t];
    const float* pwrow = pw + (size_t)t * 304;
#pragma unroll 4
    for (int j = 0; j < 304; j += 4) {
        const float4 p4 = *(const float4*)&pwrow[j];
        const float4 f4 = *(const float4*)&flds[j];
        acc += p4.x * f4.x + p4.y * f4.y + p4.z * f4.z + p4.w * f4.w;
    }
    dst[(size_t)d * 256 + t] = acc;
}

extern "C" void kernel_launch(void* const* d_in, const int* in_sizes, int n_in,
                              void* d_out, int out_size, void* d_ws, size_t ws_size,
                              hipStream_t stream)
{
    const float* x1 = (const float*)d_in[0];
    const float* x2 = (const float*)d_in[1];
    const float* qkv_w = (const float*)d_in[2];
    const float* proj_w = (const float*)d_in[3];
    const float* proj_b = (const float*)d_in[4];
    float* out = (float*)d_out;

    const size_t QSZ = (size_t)NH * N_TOK * HD;          // 1,228,800
    const size_t VSZ = (size_t)NH * N_TOK * DP;          // 1,536,000
    const size_t SSZ = (size_t)NH * N_TOK;               //    38,400
    const size_t FSZ = (size_t)NH * DD * DP;             //    12,160
    const size_t XSZ = (size_t)N_TOK * 256;              // 1,228,800
    const size_t WSZ = (size_t)768 * 256;                //   196,608
    const size_t VTSZ = (size_t)NH * NTILES * FRAG;      // 2,457,600

    // fp32 region
    float* vc1 = (float*)d_ws;          // [h][4800][32]
    float* vc2 = vc1 + QSZ;
    float* rs1 = vc2 + QSZ;   // zeroed region starts here
    float* cs1 = rs1 + SSZ;
    float* rs2 = cs1 + SSZ;
    float* cs2 = rs2 + SSZ;
    float* f1 = cs2 + SSZ;
    float* f2 = f1 + FSZ;     // zeroed region ends at f2 + FSZ
    float* T1a = f2 + FSZ;    // T partials: fully overwritten, no init needed
    float* T1b = T1a + VSZ;
    float* T1c = T1b + VSZ;
    float* T2a = T1c + VSZ;
    float* T2b = T2a + VSZ;
    float* T2c = T2b + VSZ;
    // bf16 region -- ORDER MATTERS: unconditional prefetches overrun each
    // buffer by <= 1 tile into the next allocated buffer (vf2 gets a pad).
    unsigned short* xh1 = (unsigned short*)(T2c + VSZ);
    unsigned short* xh2 = xh1 + XSZ;
    unsigned short* wh = xh2 + XSZ;
    unsigned short* qb1 = wh + WSZ;
    unsigned short* kb1 = qb1 + QSZ;    // qb1 overrun -> kb1
    unsigned short* qb2 = kb1 + QSZ;    // kb1 overrun -> qb2
    unsigned short* kb2 = qb2 + QSZ;    // qb2 overrun -> kb2
    unsigned short* vf1 = kb2 + QSZ;    // kb2 overrun -> vf1
    unsigned short* vf2 = vf1 + VTSZ;   // vf1 overrun -> vf2; vf2 -> pad

    const size_t zbytes = (4 * SSZ + 2 * FSZ) * sizeof(float);
    hipMemsetAsync(rs1, 0, zbytes, stream);

    frag_kernel<<<324, 256, 0, stream>>>(x1, xh1, x2, xh2, qkv_w, wh);

    qkv_mfma_kernel<<<dim3(75, 12, 2), 128, 0, stream>>>(
        xh1, qb1, kb1, vc1, xh2, qb2, kb2, vc2, wh);

    // fundamental_1 = f(q2, k1, vc1); fundamental_2 = f(q1, k2, vc2)
    cs_kernel<<<dim3(50, 5, 16), 192, 0, stream>>>(qb2, kb1, cs1,
                                                   qb1, kb2, cs2);
    vfrag_kernel<<<dim3(150, 16), 256, 0, stream>>>(vc1, cs1, vf1,
                                                    vc2, cs2, vf2);
    tprime_mfma_kernel<<<dim3(50, MCHUNK, 16), 192, 0, stream>>>(
        qb2, kb1, vf1, rs1, T1a, T1b, T1c,
        qb1, kb2, vf2, rs2, T2a, T2b, T2c);
    fgemm_kernel<<<dim3(16, 75), 256, 0, stream>>>(
        vc1, rs1, T1a, T1b, T1c, f1,
        vc2, rs2, T2a, T2b, T2c, f2);
    out_kernel<<<dim3(38, 2), 256, 0, stream>>>(f1, f2, proj_w, proj_b, out);
}

// Round 8
// 221.424 us; speedup vs baseline: 7.1250x; 1.0407x over previous
//
#include <hip/hip_runtime.h>
#include <stdint.h>
#include <math.h>

#define N_TOK 4800
#define NH 8
#define HD 32
#define DP 40          // T' padded leading dim (D=38 -> 40)
#define DD 38
#define NTILES 150     // 32-wide m tiles
#define MCHUNK 3       // m-chunks in tprime (50 tiles each)
#define FRAG 2048      // shorts per (h,mtile) V fragment: 4 blocks x 64 lanes x 8
#define SCALE 0.17677669529663687f            // 32^-0.5
#define QSCALE (0.17677669529663687f * 1.4426950408889634f)  // SCALE*log2(e)

typedef float f32x16 __attribute__((ext_vector_type(16)));
typedef short s8v __attribute__((ext_vector_type(8)));
typedef int i2v __attribute__((ext_vector_type(2)));

#if __has_builtin(__builtin_amdgcn_exp2f)
#define EXP2F(x) __builtin_amdgcn_exp2f(x)
#else
#define EXP2F(x) exp2f(x)
#endif

__device__ __forceinline__ unsigned short f2bf(float x) {
    union { float f; uint32_t u; } v; v.f = x;
    uint32_t r = v.u + 0x7FFFu + ((v.u >> 16) & 1u);
    return (unsigned short)(r >> 16);
}
__device__ __forceinline__ int cvtpk(float lo, float hi) {
    int r;
    asm("v_cvt_pk_bf16_f32 %0, %1, %2" : "=v"(r) : "v"(lo), "v"(hi));
    return r;
}
__device__ __forceinline__ s8v mk_s8(int a, int b, int c, int d) {
    union { int i[4]; s8v s; } u;
    u.i[0] = a; u.i[1] = b; u.i[2] = c; u.i[3] = d;
    return u.s;
}
// positional encoding component idx (0..5) for token m
__device__ __forceinline__ float posv(int m, int idx) {
    const int rrow = m / 80, rcol = m % 80;
    const float y = -1.0f + (float)rrow * (2.0f / 59.0f);
    const float x = -1.0f + (float)rcol * (2.0f / 79.0f);
    const float p3 = y * (240.0f / 517.0f);
    const float p4 = x * (360.0f / 517.0f);
    if (idx == 0) return p3 * p3;
    if (idx == 1) return p4 * p4;
    if (idx == 2) return p3 * p4;
    if (idx == 3) return p3;
    if (idx == 4) return p4;
    return 1.0f;
}

// bijective XCD-aware remap, x-fastest within an XCD: blocks sharing (y,z)
// operand streams stay on one XCD. (total blocks % 8 == 0)
template<int NX, int NY, int NZ>
__device__ __forceinline__ void swzdec(int& x, int& y, int& z) {
    const int L = blockIdx.x + NX * (blockIdx.y + NY * blockIdx.z);
    constexpr int cpx = NX * NY * NZ / 8;
    const int s = (L & 7) * cpx + (L >> 3);
    x = s % NX;
    const int r = s / NX;
    y = r % NY;
    z = r / NY;
}
// variant: x-OUTER (y,z fastest) -- each XCD owns a contiguous x-range and
// sweeps all (y,z) for it. Used where x selects the big streamed operand.
template<int NX, int NY, int NZ>
__device__ __forceinline__ void swzdec_xo(int& x, int& y, int& z) {
    const int L = blockIdx.x + NX * (blockIdx.y + NY * blockIdx.z);
    constexpr int cpx = NX * NY * NZ / 8;
    const int s = (L & 7) * cpx + (L >> 3);
    x = s / (NY * NZ);
    const int r = s % (NY * NZ);
    y = r % NY;
    z = r / NY;
}

#define MFMA(a, b, c) __builtin_amdgcn_mfma_f32_32x32x16_bf16((a), (b), (c), 0, 0, 0)

// ---------------------------------------------------------------------------
// fp32 [R][256] -> fragment-major bf16: [tile][c(16)][lane(64)][8] so qkv MFMA
// loads are contiguous 1KiB wave-loads. x1 (150 tiles), x2 (150), w (24).
// ---------------------------------------------------------------------------
__global__ __launch_bounds__(256) void frag_kernel(
    const float* __restrict__ x1, unsigned short* __restrict__ xh1,
    const float* __restrict__ x2, unsigned short* __restrict__ xh2,
    const float* __restrict__ w, unsigned short* __restrict__ wh)
{
    int b = blockIdx.x;
    const float* src; unsigned short* dh;
    if (b < 150)      { src = x1 + b * 8192; dh = xh1 + b * 8192; }
    else if (b < 300) { b -= 150; src = x2 + b * 8192; dh = xh2 + b * 8192; }
    else              { b -= 300; src = w + b * 8192; dh = wh + b * 8192; }
    const int t = threadIdx.x;
#pragma unroll
    for (int k = 0; k < 4; ++k) {
        const int f = k * 256 + t;            // 16B-chunk index, 1024 per tile
        const int c = f >> 6;
        const int rem = f & 63;
        const float* sp = src + (rem & 31) * 256 + c * 16 + (rem >> 5) * 8;
        const float4 a = *(const float4*)(sp);
        const float4 bb = *(const float4*)(sp + 4);
        const float vv[8] = {a.x, a.y, a.z, a.w, bb.x, bb.y, bb.z, bb.w};
        union { unsigned short s[8]; s8v v; } H;
#pragma unroll
        for (int j = 0; j < 8; ++j) H.s[j] = f2bf(vv[j]);
        *(s8v*)(dh + f * 8) = H.v;
    }
}

// ---------------------------------------------------------------------------
// QKV GEMM, plain bf16 MFMA on fragment-major inputs. Each wave: one x-tile
// (32 n) x 2 w-tiles (64 j). grid (75, 12, 2), x-outer XCD swizzle so each
// XCD reads its x-range once. Epilogue goes through a per-wave LDS transpose
// so all global writes are contiguous full-line regions (2KB bf16 / 4KB f32).
// ---------------------------------------------------------------------------
__global__ __launch_bounds__(128, 4) void qkv_mfma_kernel(
    const unsigned short* __restrict__ xhA, unsigned short* __restrict__ qbA,
    unsigned short* __restrict__ kbA, float* __restrict__ vcbA,
    const unsigned short* __restrict__ xhB, unsigned short* __restrict__ qbB,
    unsigned short* __restrict__ kbB, float* __restrict__ vcbB,
    const unsigned short* __restrict__ wh)
{
    __shared__ float tlbuf[2][32][33];
    int bx, by, bz;
    swzdec_xo<75, 12, 2>(bx, by, bz);
    const int sel = bz;
    const unsigned short* xh = sel ? xhB : xhA;
    unsigned short* qb = sel ? qbB : qbA;
    unsigned short* kb = sel ? kbB : kbA;
    float* vcb = sel ? vcbB : vcbA;
    const int lane = threadIdx.x & 63;
    const int wid = threadIdx.x >> 6;
    const int xtile = bx * 2 + wid;
    const unsigned short* xp = xh + (size_t)xtile * 8192 + lane * 8;
    const unsigned short* wp0 = wh + (size_t)(by * 2) * 8192 + lane * 8;
    const unsigned short* wp1 = wp0 + 8192;
    f32x16 acc0 = {}, acc1 = {};
#pragma unroll
    for (int c = 0; c < 16; ++c) {
        const s8v aH = *(const s8v*)(xp + c * 512);
        const s8v b0 = *(const s8v*)(wp0 + c * 512);
        const s8v b1 = *(const s8v*)(wp1 + c * 512);
        acc0 = MFMA(aH, b0, acc0);
        acc1 = MFMA(aH, b1, acc1);
    }
    const int lr = lane & 31, hi5 = lane >> 5;
    const int row = lane >> 1, ch = (lane & 1) * 16;
    float (*T)[33] = tlbuf[wid];
#pragma unroll
    for (int jj = 0; jj < 2; ++jj) {
        // stage this j-tile's C fragment into LDS (wave-private buffer;
        // compiler inserts the lgkmcnt waits for the ds write->read dep)
#pragma unroll
        for (int r = 0; r < 16; ++r) {
            const float v = jj ? acc1[r] : acc0[r];
            T[(r & 3) + 8 * (r >> 2) + 4 * hi5][lr] = v;
        }
        const int jt = by * 2 + jj, s = jt >> 3, h = jt & 7;
        const int n = xtile * 32 + row;
        if (s == 2) {
            float4* dst = (float4*)&vcb[(size_t)(h * N_TOK + n) * HD + ch];
#pragma unroll
            for (int k = 0; k < 4; ++k) {
                dst[k] = make_float4(T[row][ch + 4 * k + 0], T[row][ch + 4 * k + 1],
                                     T[row][ch + 4 * k + 2], T[row][ch + 4 * k + 3]);
            }
        } else {
            const float m = (s == 0) ? QSCALE : 1.0f;
            unsigned short* dst = (s == 0 ? qb : kb)
                                  + (size_t)(h * N_TOK + n) * HD + ch;
            union { unsigned short u[8]; s8v v; } o0, o1;
#pragma unroll
            for (int i = 0; i < 8; ++i) {
                o0.u[i] = f2bf(T[row][ch + i] * m);
                o1.u[i] = f2bf(T[row][ch + 8 + i] * m);
            }
            *(s8v*)dst = o0.v;
            *(s8v*)(dst + 8) = o1.v;
        }
    }
}

// ---------------------------------------------------------------------------
// Pass 1 (both fundamentals): S' = Q'.K^T via bf16 MFMA; cs[m] += sum_n 2^S'.
// 3-wave blocks (96 m-rows) share the Q stream via L1. grid (50, 5, 16)
// XCD-swizzled, 192 threads. NOTE: last iter prefetches 1 row-tile past the
// q buffer -- layout guarantees the next buffer is allocated (pad rule).
// ---------------------------------------------------------------------------
__global__ __launch_bounds__(192, 4) void cs_kernel(
    const unsigned short* __restrict__ qbA, const unsigned short* __restrict__ kbA,
    float* __restrict__ csA,
    const unsigned short* __restrict__ qbB, const unsigned short* __restrict__ kbB,
    float* __restrict__ csB)
{
    int bx, by, bz;
    swzdec<50, 5, 16>(bx, by, bz);
    const int sel = bz >> 3;
    const unsigned short* qb = sel ? qbB : qbA;
    const unsigned short* kb = sel ? kbB : kbA;
    float* cs = sel ? csB : csA;
    const int lane = threadIdx.x & 63;
    const int wid = threadIdx.x >> 6;
    const int h = bz & 7;
    const int m0 = bx * 96 + wid * 32;
    const int lr = lane & 31, hi5 = lane >> 5;
    const int hbase = h * N_TOK;
    const unsigned short* kp = kb + (hbase + m0 + lr) * HD + 8 * hi5;
    const s8v bK0 = *(const s8v*)(kp);
    const s8v bK1 = *(const s8v*)(kp + 16);
    const unsigned short* qp = qb + (hbase + by * 960 + lr) * HD + 8 * hi5;
    s8v a0 = *(const s8v*)(qp);
    s8v a1 = *(const s8v*)(qp + 16);
    float csa = 0.f, csb = 0.f;
#pragma unroll 2
    for (int it = 0; it < 30; ++it) {
        qp += 32 * HD;
        const s8v na0 = *(const s8v*)(qp);
        const s8v na1 = *(const s8v*)(qp + 16);
        f32x16 acc = {};
        acc = MFMA(a0, bK0, acc);
        acc = MFMA(a1, bK1, acc);
#pragma unroll
        for (int r = 0; r < 16; r += 2) {
            csa += EXP2F(acc[r]);
            csb += EXP2F(acc[r + 1]);
        }
        a0 = na0; a1 = na1;
    }
    float csacc = csa + csb;
    csacc += __shfl_xor(csacc, 32);
    if (lane < 32) atomicAdd(&cs[hbase + m0 + lane], csacc);
}

// ---------------------------------------------------------------------------
// vc fp32 [h][4800][32] + inline pos + u=1/cs -> fragment-major bf16 vfrag
// [h][mtile][b][lane][8]. Both fundamentals: grid (150, 16), 256 threads.
// ---------------------------------------------------------------------------
__global__ __launch_bounds__(256) void vfrag_kernel(
    const float* __restrict__ vcA, const float* __restrict__ csA,
    unsigned short* __restrict__ vfA,
    const float* __restrict__ vcB, const float* __restrict__ csB,
    unsigned short* __restrict__ vfB)
{
    const int sel = blockIdx.y >> 3;
    const float* vc = sel ? vcB : vcA;
    const float* cs = sel ? csB : csA;
    unsigned short* vf = sel ? vfB : vfA;
    __shared__ float vl[32][33];
    __shared__ float ul[32];
    const int mt = blockIdx.x;
    const int h = blockIdx.y & 7;
    const int t = threadIdx.x;
    const int m0 = mt * 32;
    const float* vcbase = vc + (size_t)(h * N_TOK + m0) * HD;
    for (int e = t; e < 32 * HD; e += 256) vl[e >> 5][e & 31] = vcbase[e];
    if (t < 32) ul[t] = 1.0f / cs[(size_t)h * N_TOK + m0 + t];
    __syncthreads();
    const int b = t >> 6, lane = t & 63;
    const int hi5 = lane >> 5, lr = lane & 31;
    const int d = (b >> 1) * 32 + lr;       // 0..63 (>=38 zero pad)
    const int mb = (b & 1) * 16 + hi5 * 8;  // k-offset within tile
    union { unsigned short s[8]; s8v v; } pk;
#pragma unroll
    for (int j = 0; j < 8; ++j) {
        const int mo = mb + j;
        float v;
        if (d < 32)      v = vl[mo][d];
        else if (d < 38) v = posv(m0 + mo, d - 32);
        else             v = 0.0f;
        pk.s[j] = f2bf(v * ul[mo]);
    }
    *(s8v*)(vf + ((size_t)(h * NTILES + mt) * 4 + b) * 512 + lane * 8) = pk.v;
}

// ---------------------------------------------------------------------------
// Pass 2 (both fundamentals): S'^T = K.Q'^T; e = 2^S'; rs += e in-lane;
// P' = e*e packed in-register (cvt_pk + permlane32_swap); T' += P'.vfrag via
// MFMA. 3-wave blocks (96 n) share K/V streams via L1; 3 m-chunks with
// separate T partials (plain stores). grid (50, 3, 16) XCD-swizzled, 192 thr.
// Last iter prefetches 1 tile past the chunk -- buffers padded/ordered for it.
// ---------------------------------------------------------------------------
__global__ __launch_bounds__(192, 4) void tprime_mfma_kernel(
    const unsigned short* __restrict__ qbA, const unsigned short* __restrict__ kbA,
    const unsigned short* __restrict__ vfA, float* __restrict__ rsA,
    float* __restrict__ TA0, float* __restrict__ TA1, float* __restrict__ TA2,
    const unsigned short* __restrict__ qbB, const unsigned short* __restrict__ kbB,
    const unsigned short* __restrict__ vfB, float* __restrict__ rsB,
    float* __restrict__ TB0, float* __restrict__ TB1, float* __restrict__ TB2)
{
    int bx, by, bz;
    swzdec<50, MCHUNK, 16>(bx, by, bz);
    const int sel = bz >> 3;
    const unsigned short* qb = sel ? qbB : qbA;
    const unsigned short* kb = sel ? kbB : kbA;
    const unsigned short* vf = sel ? vfB : vfA;
    float* rs = sel ? rsB : rsA;
    float* T = sel ? (by == 0 ? TB0 : (by == 1 ? TB1 : TB2))
                   : (by == 0 ? TA0 : (by == 1 ? TA1 : TA2));
    const int lane = threadIdx.x & 63;
    const int wid = threadIdx.x >> 6;
    const int h = bz & 7;
    const int n0 = bx * 96 + wid * 32;
    const int lr = lane & 31, hi5 = lane >> 5;
    const int hbase = h * N_TOK;
    // Q as B operand (hoisted across the m-loop)
    const unsigned short* qp = qb + (hbase + n0 + lr) * HD + 8 * hi5;
    const s8v bQ0 = *(const s8v*)(qp);
    const s8v bQ1 = *(const s8v*)(qp + 16);
    f32x16 t0 = {}, t1 = {};
    float rsa = 0.f, rsb = 0.f;
    const int mt0 = by * 50;
    const unsigned short* kp = kb + (hbase + mt0 * 32 + lr) * HD + 8 * hi5;
    const unsigned short* vp = vf + (size_t)(h * NTILES + mt0) * FRAG + lane * 8;
    s8v a0 = *(const s8v*)(kp);
    s8v a1 = *(const s8v*)(kp + 16);
    s8v v00 = *(const s8v*)(vp);
    s8v v01 = *(const s8v*)(vp + 512);
    s8v v10 = *(const s8v*)(vp + 1024);
    s8v v11 = *(const s8v*)(vp + 1536);
#pragma unroll 2
    for (int it = 0; it < 50; ++it) {
        // unconditional next-tile prefetch (coalesced 1KiB loads; pad covers end)
        kp += 32 * HD; vp += FRAG;
        const s8v na0 = *(const s8v*)(kp);
        const s8v na1 = *(const s8v*)(kp + 16);
        const s8v nv00 = *(const s8v*)(vp);
        const s8v nv01 = *(const s8v*)(vp + 512);
        const s8v nv10 = *(const s8v*)(vp + 1024);
        const s8v nv11 = *(const s8v*)(vp + 1536);
        f32x16 s = {};
        s = MFMA(a0, bQ0, s);
        s = MFMA(a1, bQ1, s);
        float p[16];
#pragma unroll
        for (int r = 0; r < 16; r += 2) {
            const float e0 = EXP2F(s[r]);
            const float e1 = EXP2F(s[r + 1]);
            rsa += e0; rsb += e1;
            p[r] = e0 * e0; p[r + 1] = e1 * e1;
        }
        const int L0 = cvtpk(p[0], p[1]),   L1 = cvtpk(p[2], p[3]);
        const int H0 = cvtpk(p[4], p[5]),   H1 = cvtpk(p[6], p[7]);
        const int L2 = cvtpk(p[8], p[9]),   L3 = cvtpk(p[10], p[11]);
        const int H2 = cvtpk(p[12], p[13]), H3 = cvtpk(p[14], p[15]);
        const i2v s0 = __builtin_amdgcn_permlane32_swap(L0, H0, false, false);
        const i2v s1 = __builtin_amdgcn_permlane32_swap(L1, H1, false, false);
        const i2v s2 = __builtin_amdgcn_permlane32_swap(L2, H2, false, false);
        const i2v s3 = __builtin_amdgcn_permlane32_swap(L3, H3, false, false);
        const s8v pa0 = mk_s8(s0[0], s1[0], s0[1], s1[1]);   // k = 0..15
        const s8v pa1 = mk_s8(s2[0], s3[0], s2[1], s3[1]);   // k = 16..31
        __builtin_amdgcn_s_setprio(1);
        t0 = MFMA(pa0, v00, t0);
        t0 = MFMA(pa1, v01, t0);
        t1 = MFMA(pa0, v10, t1);
        t1 = MFMA(pa1, v11, t1);
        __builtin_amdgcn_s_setprio(0);
        a0 = na0; a1 = na1;
        v00 = nv00; v01 = nv01; v10 = nv10; v11 = nv11;
    }
    float rsacc = rsa + rsb;
    rsacc += __shfl_xor(rsacc, 32);
    if (lane < 32) atomicAdd(&rs[hbase + n0 + lane], rsacc);
#pragma unroll
    for (int r = 0; r < 16; ++r) {
        const int n = n0 + (r & 3) + 8 * (r >> 2) + 4 * hi5;
        T[(size_t)(hbase + n) * DP + lr] = t0[r];
    }
    if (lr < 8) {
#pragma unroll
        for (int r = 0; r < 16; ++r) {
            const int n = n0 + (r & 3) + 8 * (r >> 2) + 4 * hi5;
            T[(size_t)(hbase + n) * DP + 32 + lr] = t1[r];
        }
    }
}

// ---------------------------------------------------------------------------
// f[h,c,d] = sum_n (vc[n,c]/rs[n]) * (T0'+T1'+T2')[n,d] per 64-row chunk.
// vc cols 32..37 = inline pos. Both fundamentals: grid (16, 75).
// ---------------------------------------------------------------------------
__global__ __launch_bounds__(256) void fgemm_kernel(
    const float* __restrict__ VCA, const float* __restrict__ rsA,
    const float* __restrict__ TA0, const float* __restrict__ TA1,
    const float* __restrict__ TA2, float* __restrict__ fA,
    const float* __restrict__ VCB, const float* __restrict__ rsB,
    const float* __restrict__ TB0, const float* __restrict__ TB1,
    const float* __restrict__ TB2, float* __restrict__ fB)
{
    const int sel = blockIdx.x >> 3;
    const float* VC = sel ? VCB : VCA;
    const float* rs = sel ? rsB : rsA;
    const float* Ta = sel ? TB0 : TA0;
    const float* Tb = sel ? TB1 : TA1;
    const float* Tc = sel ? TB2 : TA2;
    float* f = sel ? fB : fA;
    __shared__ __align__(16) float wvcl[64 * DP];
    __shared__ __align__(16) float tl[64 * DP];
    __shared__ float wl[64];
    const int h = blockIdx.x & 7, n0 = blockIdx.y * 64;
    const int t = threadIdx.x;
    if (t < 64) wl[t] = 1.0f / rs[(size_t)h * N_TOK + n0 + t];
    __syncthreads();
    const float* vcbase = VC + (size_t)(h * N_TOK + n0) * HD;
    const float* tabase = Ta + (size_t)(h * N_TOK + n0) * DP;
    const float* tbbase = Tb + (size_t)(h * N_TOK + n0) * DP;
    const float* tcbase = Tc + (size_t)(h * N_TOK + n0) * DP;
    for (int e = t; e < 64 * DP; e += 256) {
        const int row = e / DP, c = e - row * DP;
        float v;
        if (c < 32)      v = vcbase[row * HD + c];
        else if (c < 38) v = posv(n0 + row, c - 32);
        else             v = 0.0f;
        wvcl[e] = v * wl[row];
        tl[e] = tabase[e] + tbbase[e] + tcbase[e];
    }
    __syncthreads();
    for (int p = t; p < DD * DD; p += 256) {
        const int c = p / DD, d = p % DD;
        float s = 0.f;
#pragma unroll 8
        for (int n = 0; n < 64; ++n) s += wvcl[n * DP + c] * tl[n * DP + d];
        atomicAdd(&f[(size_t)(h * DD + c) * DP + d], s);
    }
}

// ---------------------------------------------------------------------------
// out[d,e] = sum_j f[j,d] * proj_w[e,j] + proj_b[e]. Both fundamentals:
// grid (38, 2); y=0 -> f1 -> out+DD*256, y=1 -> f2 -> out.
// ---------------------------------------------------------------------------
__global__ __launch_bounds__(256) void out_kernel(
    const float* __restrict__ f1, const float* __restrict__ f2,
    const float* __restrict__ pw, const float* __restrict__ pb,
    float* __restrict__ out)
{
    const int sel = blockIdx.y;
    const float* f = sel ? f2 : f1;
    float* dst = sel ? out : (out + DD * 256);
    __shared__ __align__(16) float flds[304];
    const int d = blockIdx.x, t = threadIdx.x;
    for (int j = t; j < 304; j += 256) flds[j] = f[(size_t)j * DP + d];
    __syncthreads();
    float acc = pb[t];
    const float* pwrow = pw + (size_t)t * 304;
#pragma unroll 4
    for (int j = 0; j < 304; j += 4) {
        const float4 p4 = *(const float4*)&pwrow[j];
        const float4 f4 = *(const float4*)&flds[j];
        acc += p4.x * f4.x + p4.y * f4.y + p4.z * f4.z + p4.w * f4.w;
    }
    dst[(size_t)d * 256 + t] = acc;
}

extern "C" void kernel_launch(void* const* d_in, const int* in_sizes, int n_in,
                              void* d_out, int out_size, void* d_ws, size_t ws_size,
                              hipStream_t stream)
{
    const float* x1 = (const float*)d_in[0];
    const float* x2 = (const float*)d_in[1];
    const float* qkv_w = (const float*)d_in[2];
    const float* proj_w = (const float*)d_in[3];
    const float* proj_b = (const float*)d_in[4];
    float* out = (float*)d_out;

    const size_t QSZ = (size_t)NH * N_TOK * HD;          // 1,228,800
    const size_t VSZ = (size_t)NH * N_TOK * DP;          // 1,536,000
    const size_t SSZ = (size_t)NH * N_TOK;               //    38,400
    const size_t FSZ = (size_t)NH * DD * DP;             //    12,160
    const size_t XSZ = (size_t)N_TOK * 256;              // 1,228,800
    const size_t WSZ = (size_t)768 * 256;                //   196,608
    const size_t VTSZ = (size_t)NH * NTILES * FRAG;      // 2,457,600

    // fp32 region
    float* vc1 = (float*)d_ws;          // [h][4800][32]
    float* vc2 = vc1 + QSZ;
    float* rs1 = vc2 + QSZ;   // zeroed region starts here
    float* cs1 = rs1 + SSZ;
    float* rs2 = cs1 + SSZ;
    float* cs2 = rs2 + SSZ;
    float* f1 = cs2 + SSZ;
    float* f2 = f1 + FSZ;     // zeroed region ends at f2 + FSZ
    float* T1a = f2 + FSZ;    // T partials: fully overwritten, no init needed
    float* T1b = T1a + VSZ;
    float* T1c = T1b + VSZ;
    float* T2a = T1c + VSZ;
    float* T2b = T2a + VSZ;
    float* T2c = T2b + VSZ;
    // bf16 region -- ORDER MATTERS: unconditional prefetches overrun each
    // buffer by <= 1 tile into the next allocated buffer (vf2 gets a pad).
    unsigned short* xh1 = (unsigned short*)(T2c + VSZ);
    unsigned short* xh2 = xh1 + XSZ;
    unsigned short* wh = xh2 + XSZ;
    unsigned short* qb1 = wh + WSZ;
    unsigned short* kb1 = qb1 + QSZ;    // qb1 overrun -> kb1
    unsigned short* qb2 = kb1 + QSZ;    // kb1 overrun -> qb2
    unsigned short* kb2 = qb2 + QSZ;    // qb2 overrun -> kb2
    unsigned short* vf1 = kb2 + QSZ;    // kb2 overrun -> vf1
    unsigned short* vf2 = vf1 + VTSZ;   // vf1 overrun -> vf2; vf2 -> pad

    const size_t zbytes = (4 * SSZ + 2 * FSZ) * sizeof(float);
    hipMemsetAsync(rs1, 0, zbytes, stream);

    frag_kernel<<<324, 256, 0, stream>>>(x1, xh1, x2, xh2, qkv_w, wh);

    qkv_mfma_kernel<<<dim3(75, 12, 2), 128, 0, stream>>>(
        xh1, qb1, kb1, vc1, xh2, qb2, kb2, vc2, wh);

    // fundamental_1 = f(q2, k1, vc1); fundamental_2 = f(q1, k2, vc2)
    cs_kernel<<<dim3(50, 5, 16), 192, 0, stream>>>(qb2, kb1, cs1,
                                                   qb1, kb2, cs2);
    vfrag_kernel<<<dim3(150, 16), 256, 0, stream>>>(vc1, cs1, vf1,
                                                    vc2, cs2, vf2);
    tprime_mfma_kernel<<<dim3(50, MCHUNK, 16), 192, 0, stream>>>(
        qb2, kb1, vf1, rs1, T1a, T1b, T1c,
        qb1, kb2, vf2, rs2, T2a, T2b, T2c);
    fgemm_kernel<<<dim3(16, 75), 256, 0, stream>>>(
        vc1, rs1, T1a, T1b, T1c, f1,
        vc2, rs2, T2a, T2b, T2c, f2);
    out_kernel<<<dim3(38, 2), 256, 0, stream>>>(f1, f2, proj_w, proj_b, out);
}

// Round 9
// 212.515 us; speedup vs baseline: 7.4237x; 1.0419x over previous
//
#include <hip/hip_runtime.h>
#include <stdint.h>
#include <math.h>

#define N_TOK 4800
#define NH 8
#define HD 32
#define DP 40          // T' padded leading dim (D=38 -> 40)
#define DD 38
#define NTILES 150     // 32-wide m tiles
#define MCHUNK 3       // m-chunks in tprime (50 tiles each)
#define FRAG 2048      // shorts per (h,mtile) V fragment: 4 blocks x 64 lanes x 8
#define SCALE 0.17677669529663687f            // 32^-0.5
#define QSCALE (0.17677669529663687f * 1.4426950408889634f)  // SCALE*log2(e)

typedef float f32x16 __attribute__((ext_vector_type(16)));
typedef short s8v __attribute__((ext_vector_type(8)));
typedef int i2v __attribute__((ext_vector_type(2)));

#if __has_builtin(__builtin_amdgcn_exp2f)
#define EXP2F(x) __builtin_amdgcn_exp2f(x)
#else
#define EXP2F(x) exp2f(x)
#endif

__device__ __forceinline__ unsigned short f2bf(float x) {
    union { float f; uint32_t u; } v; v.f = x;
    uint32_t r = v.u + 0x7FFFu + ((v.u >> 16) & 1u);
    return (unsigned short)(r >> 16);
}
__device__ __forceinline__ float bf2f(unsigned short h) {
    union { uint32_t u; float f; } v; v.u = ((uint32_t)h) << 16;
    return v.f;
}
__device__ __forceinline__ int cvtpk(float lo, float hi) {
    int r;
    asm("v_cvt_pk_bf16_f32 %0, %1, %2" : "=v"(r) : "v"(lo), "v"(hi));
    return r;
}
__device__ __forceinline__ s8v mk_s8(int a, int b, int c, int d) {
    union { int i[4]; s8v s; } u;
    u.i[0] = a; u.i[1] = b; u.i[2] = c; u.i[3] = d;
    return u.s;
}
// positional encoding component idx (0..5) for token m
__device__ __forceinline__ float posv(int m, int idx) {
    const int rrow = m / 80, rcol = m % 80;
    const float y = -1.0f + (float)rrow * (2.0f / 59.0f);
    const float x = -1.0f + (float)rcol * (2.0f / 79.0f);
    const float p3 = y * (240.0f / 517.0f);
    const float p4 = x * (360.0f / 517.0f);
    if (idx == 0) return p3 * p3;
    if (idx == 1) return p4 * p4;
    if (idx == 2) return p3 * p4;
    if (idx == 3) return p3;
    if (idx == 4) return p4;
    return 1.0f;
}

// bijective XCD-aware remap, x-fastest within an XCD: blocks sharing (y,z)
// operand streams stay on one XCD. (total blocks % 8 == 0)
template<int NX, int NY, int NZ>
__device__ __forceinline__ void swzdec(int& x, int& y, int& z) {
    const int L = blockIdx.x + NX * (blockIdx.y + NY * blockIdx.z);
    constexpr int cpx = NX * NY * NZ / 8;
    const int s = (L & 7) * cpx + (L >> 3);
    x = s % NX;
    const int r = s / NX;
    y = r % NY;
    z = r / NY;
}
// variant: x-OUTER (y,z fastest) -- each XCD owns a contiguous x-range and
// sweeps all (y,z) for it. Used where x selects the big streamed operand.
template<int NX, int NY, int NZ>
__device__ __forceinline__ void swzdec_xo(int& x, int& y, int& z) {
    const int L = blockIdx.x + NX * (blockIdx.y + NY * blockIdx.z);
    constexpr int cpx = NX * NY * NZ / 8;
    const int s = (L & 7) * cpx + (L >> 3);
    x = s / (NY * NZ);
    const int r = s % (NY * NZ);
    y = r % NY;
    z = r / NY;
}

#define MFMA(a, b, c) __builtin_amdgcn_mfma_f32_32x32x16_bf16((a), (b), (c), 0, 0, 0)

// ---------------------------------------------------------------------------
// fp32 [R][256] -> fragment-major bf16: [tile][c(16)][lane(64)][8] so qkv MFMA
// loads are contiguous 1KiB wave-loads. x1 (150 tiles), x2 (150), w (24).
// Blocks >= 324 zero the accumulator region (replaces the memset dispatch).
// ---------------------------------------------------------------------------
__global__ __launch_bounds__(256) void frag_kernel(
    const float* __restrict__ x1, unsigned short* __restrict__ xh1,
    const float* __restrict__ x2, unsigned short* __restrict__ xh2,
    const float* __restrict__ w, unsigned short* __restrict__ wh,
    float* __restrict__ zbase, int zn4)
{
    int b = blockIdx.x;
    const int t = threadIdx.x;
    if (b >= 324) {
        const int i = (b - 324) * 256 + t;
        if (i < zn4) ((float4*)zbase)[i] = make_float4(0.f, 0.f, 0.f, 0.f);
        return;
    }
    const float* src; unsigned short* dh;
    if (b < 150)      { src = x1 + b * 8192; dh = xh1 + b * 8192; }
    else if (b < 300) { b -= 150; src = x2 + b * 8192; dh = xh2 + b * 8192; }
    else              { b -= 300; src = w + b * 8192; dh = wh + b * 8192; }
#pragma unroll
    for (int k = 0; k < 4; ++k) {
        const int f = k * 256 + t;            // 16B-chunk index, 1024 per tile
        const int c = f >> 6;
        const int rem = f & 63;
        const float* sp = src + (rem & 31) * 256 + c * 16 + (rem >> 5) * 8;
        const float4 a = *(const float4*)(sp);
        const float4 bb = *(const float4*)(sp + 4);
        const float vv[8] = {a.x, a.y, a.z, a.w, bb.x, bb.y, bb.z, bb.w};
        union { unsigned short s[8]; s8v v; } H;
#pragma unroll
        for (int j = 0; j < 8; ++j) H.s[j] = f2bf(vv[j]);
        *(s8v*)(dh + f * 8) = H.v;
    }
}

// ---------------------------------------------------------------------------
// QKV GEMM, plain bf16 MFMA on fragment-major inputs. Each wave: one x-tile
// (32 n) x 2 w-tiles (64 j). grid (75, 12, 2), x-outer XCD swizzle so each
// XCD reads its x-range once. Epilogue goes through a per-wave LDS transpose
// so all global writes are contiguous full-line regions (2KB bf16 / 4KB f32).
// ---------------------------------------------------------------------------
__global__ __launch_bounds__(128, 4) void qkv_mfma_kernel(
    const unsigned short* __restrict__ xhA, unsigned short* __restrict__ qbA,
    unsigned short* __restrict__ kbA, float* __restrict__ vcbA,
    const unsigned short* __restrict__ xhB, unsigned short* __restrict__ qbB,
    unsigned short* __restrict__ kbB, float* __restrict__ vcbB,
    const unsigned short* __restrict__ wh)
{
    __shared__ float tlbuf[2][32][33];
    int bx, by, bz;
    swzdec_xo<75, 12, 2>(bx, by, bz);
    const int sel = bz;
    const unsigned short* xh = sel ? xhB : xhA;
    unsigned short* qb = sel ? qbB : qbA;
    unsigned short* kb = sel ? kbB : kbA;
    float* vcb = sel ? vcbB : vcbA;
    const int lane = threadIdx.x & 63;
    const int wid = threadIdx.x >> 6;
    const int xtile = bx * 2 + wid;
    const unsigned short* xp = xh + (size_t)xtile * 8192 + lane * 8;
    const unsigned short* wp0 = wh + (size_t)(by * 2) * 8192 + lane * 8;
    const unsigned short* wp1 = wp0 + 8192;
    f32x16 acc0 = {}, acc1 = {};
#pragma unroll
    for (int c = 0; c < 16; ++c) {
        const s8v aH = *(const s8v*)(xp + c * 512);
        const s8v b0 = *(const s8v*)(wp0 + c * 512);
        const s8v b1 = *(const s8v*)(wp1 + c * 512);
        acc0 = MFMA(aH, b0, acc0);
        acc1 = MFMA(aH, b1, acc1);
    }
    const int lr = lane & 31, hi5 = lane >> 5;
    const int row = lane >> 1, ch = (lane & 1) * 16;
    float (*T)[33] = tlbuf[wid];
#pragma unroll
    for (int jj = 0; jj < 2; ++jj) {
        // stage this j-tile's C fragment into LDS (wave-private buffer;
        // compiler inserts the lgkmcnt waits for the ds write->read dep)
#pragma unroll
        for (int r = 0; r < 16; ++r) {
            const float v = jj ? acc1[r] : acc0[r];
            T[(r & 3) + 8 * (r >> 2) + 4 * hi5][lr] = v;
        }
        const int jt = by * 2 + jj, s = jt >> 3, h = jt & 7;
        const int n = xtile * 32 + row;
        if (s == 2) {
            float4* dst = (float4*)&vcb[(size_t)(h * N_TOK + n) * HD + ch];
#pragma unroll
            for (int k = 0; k < 4; ++k) {
                dst[k] = make_float4(T[row][ch + 4 * k + 0], T[row][ch + 4 * k + 1],
                                     T[row][ch + 4 * k + 2], T[row][ch + 4 * k + 3]);
            }
        } else {
            const float m = (s == 0) ? QSCALE : 1.0f;
            unsigned short* dst = (s == 0 ? qb : kb)
                                  + (size_t)(h * N_TOK + n) * HD + ch;
            union { unsigned short u[8]; s8v v; } o0, o1;
#pragma unroll
            for (int i = 0; i < 8; ++i) {
                o0.u[i] = f2bf(T[row][ch + i] * m);
                o1.u[i] = f2bf(T[row][ch + 8 + i] * m);
            }
            *(s8v*)dst = o0.v;
            *(s8v*)(dst + 8) = o1.v;
        }
    }
}

// ---------------------------------------------------------------------------
// Pass 1 (both fundamentals): S' = Q'.K^T via bf16 MFMA; cs[m] += sum_n 2^S'.
// Each wave owns TWO fixed K-tiles (64 m) so the Q stream + loop overhead is
// amortized over 2x scores. 3-wave blocks (192 m). grid (25, 5, 16),
// XCD-swizzled, 192 threads. Last iter prefetches 1 row-tile past the q
// buffer -- layout guarantees the next buffer is allocated (pad rule).
// ---------------------------------------------------------------------------
__global__ __launch_bounds__(192, 4) void cs_kernel(
    const unsigned short* __restrict__ qbA, const unsigned short* __restrict__ kbA,
    float* __restrict__ csA,
    const unsigned short* __restrict__ qbB, const unsigned short* __restrict__ kbB,
    float* __restrict__ csB)
{
    int bx, by, bz;
    swzdec<25, 5, 16>(bx, by, bz);
    const int sel = bz >> 3;
    const unsigned short* qb = sel ? qbB : qbA;
    const unsigned short* kb = sel ? kbB : kbA;
    float* cs = sel ? csB : csA;
    const int lane = threadIdx.x & 63;
    const int wid = threadIdx.x >> 6;
    const int h = bz & 7;
    const int m0 = bx * 192 + wid * 64;       // two 32-tiles: m0, m0+32
    const int lr = lane & 31, hi5 = lane >> 5;
    const int hbase = h * N_TOK;
    const unsigned short* kp = kb + (hbase + m0 + lr) * HD + 8 * hi5;
    const s8v bK0 = *(const s8v*)(kp);
    const s8v bK1 = *(const s8v*)(kp + 16);
    const s8v bK2 = *(const s8v*)(kp + 32 * HD);
    const s8v bK3 = *(const s8v*)(kp + 32 * HD + 16);
    const unsigned short* qp = qb + (hbase + by * 960 + lr) * HD + 8 * hi5;
    s8v a0 = *(const s8v*)(qp);
    s8v a1 = *(const s8v*)(qp + 16);
    float c0 = 0.f, c1 = 0.f, c2 = 0.f, c3 = 0.f;
#pragma unroll 2
    for (int it = 0; it < 30; ++it) {
        qp += 32 * HD;
        const s8v na0 = *(const s8v*)(qp);
        const s8v na1 = *(const s8v*)(qp + 16);
        f32x16 accA = {}, accB = {};
        accA = MFMA(a0, bK0, accA);
        accB = MFMA(a0, bK2, accB);
        accA = MFMA(a1, bK1, accA);
        accB = MFMA(a1, bK3, accB);
#pragma unroll
        for (int r = 0; r < 16; r += 2) {
            c0 += EXP2F(accA[r]);
            c1 += EXP2F(accA[r + 1]);
            c2 += EXP2F(accB[r]);
            c3 += EXP2F(accB[r + 1]);
        }
        a0 = na0; a1 = na1;
    }
    float cA = c0 + c1, cB = c2 + c3;
    cA += __shfl_xor(cA, 32);
    cB += __shfl_xor(cB, 32);
    if (lane < 32) {
        atomicAdd(&cs[hbase + m0 + lane], cA);
        atomicAdd(&cs[hbase + m0 + 32 + lane], cB);
    }
}

// ---------------------------------------------------------------------------
// vc fp32 [h][4800][32] + inline pos + u=1/cs -> fragment-major bf16 vfrag
// [h][mtile][b][lane][8]. Both fundamentals: grid (150, 16), 256 threads.
// ---------------------------------------------------------------------------
__global__ __launch_bounds__(256) void vfrag_kernel(
    const float* __restrict__ vcA, const float* __restrict__ csA,
    unsigned short* __restrict__ vfA,
    const float* __restrict__ vcB, const float* __restrict__ csB,
    unsigned short* __restrict__ vfB)
{
    const int sel = blockIdx.y >> 3;
    const float* vc = sel ? vcB : vcA;
    const float* cs = sel ? csB : csA;
    unsigned short* vf = sel ? vfB : vfA;
    __shared__ float vl[32][33];
    __shared__ float ul[32];
    const int mt = blockIdx.x;
    const int h = blockIdx.y & 7;
    const int t = threadIdx.x;
    const int m0 = mt * 32;
    const float* vcbase = vc + (size_t)(h * N_TOK + m0) * HD;
    for (int e = t; e < 32 * HD; e += 256) vl[e >> 5][e & 31] = vcbase[e];
    if (t < 32) ul[t] = 1.0f / cs[(size_t)h * N_TOK + m0 + t];
    __syncthreads();
    const int b = t >> 6, lane = t & 63;
    const int hi5 = lane >> 5, lr = lane & 31;
    const int d = (b >> 1) * 32 + lr;       // 0..63 (>=38 zero pad)
    const int mb = (b & 1) * 16 + hi5 * 8;  // k-offset within tile
    union { unsigned short s[8]; s8v v; } pk;
#pragma unroll
    for (int j = 0; j < 8; ++j) {
        const int mo = mb + j;
        float v;
        if (d < 32)      v = vl[mo][d];
        else if (d < 38) v = posv(m0 + mo, d - 32);
        else             v = 0.0f;
        pk.s[j] = f2bf(v * ul[mo]);
    }
    *(s8v*)(vf + ((size_t)(h * NTILES + mt) * 4 + b) * 512 + lane * 8) = pk.v;
}

// ---------------------------------------------------------------------------
// Pass 2 (both fundamentals): S'^T = K.Q'^T; e = 2^S'; rs += e in-lane;
// P' = e*e packed in-register (cvt_pk + permlane32_swap); T' += P'.vfrag via
// MFMA. 3-wave blocks (96 n) share K/V streams via L1; 3 m-chunks with
// separate T partials, stored as bf16 (lane-pair packed, plain stores).
// grid (50, 3, 16) XCD-swizzled, 192 thr. Last iter prefetches 1 tile past
// the chunk -- buffers padded/ordered for it.
// ---------------------------------------------------------------------------
__global__ __launch_bounds__(192, 4) void tprime_mfma_kernel(
    const unsigned short* __restrict__ qbA, const unsigned short* __restrict__ kbA,
    const unsigned short* __restrict__ vfA, float* __restrict__ rsA,
    unsigned short* __restrict__ TA0, unsigned short* __restrict__ TA1,
    unsigned short* __restrict__ TA2,
    const unsigned short* __restrict__ qbB, const unsigned short* __restrict__ kbB,
    const unsigned short* __restrict__ vfB, float* __restrict__ rsB,
    unsigned short* __restrict__ TB0, unsigned short* __restrict__ TB1,
    unsigned short* __restrict__ TB2)
{
    int bx, by, bz;
    swzdec<50, MCHUNK, 16>(bx, by, bz);
    const int sel = bz >> 3;
    const unsigned short* qb = sel ? qbB : qbA;
    const unsigned short* kb = sel ? kbB : kbA;
    const unsigned short* vf = sel ? vfB : vfA;
    float* rs = sel ? rsB : rsA;
    unsigned short* T = sel ? (by == 0 ? TB0 : (by == 1 ? TB1 : TB2))
                            : (by == 0 ? TA0 : (by == 1 ? TA1 : TA2));
    const int lane = threadIdx.x & 63;
    const int wid = threadIdx.x >> 6;
    const int h = bz & 7;
    const int n0 = bx * 96 + wid * 32;
    const int lr = lane & 31, hi5 = lane >> 5;
    const int hbase = h * N_TOK;
    // Q as B operand (hoisted across the m-loop)
    const unsigned short* qp = qb + (hbase + n0 + lr) * HD + 8 * hi5;
    const s8v bQ0 = *(const s8v*)(qp);
    const s8v bQ1 = *(const s8v*)(qp + 16);
    f32x16 t0 = {}, t1 = {};
    float rsa = 0.f, rsb = 0.f;
    const int mt0 = by * 50;
    const unsigned short* kp = kb + (hbase + mt0 * 32 + lr) * HD + 8 * hi5;
    const unsigned short* vp = vf + (size_t)(h * NTILES + mt0) * FRAG + lane * 8;
    s8v a0 = *(const s8v*)(kp);
    s8v a1 = *(const s8v*)(kp + 16);
    s8v v00 = *(const s8v*)(vp);
    s8v v01 = *(const s8v*)(vp + 512);
    s8v v10 = *(const s8v*)(vp + 1024);
    s8v v11 = *(const s8v*)(vp + 1536);
#pragma unroll 2
    for (int it = 0; it < 50; ++it) {
        // unconditional next-tile prefetch (coalesced 1KiB loads; pad covers end)
        kp += 32 * HD; vp += FRAG;
        const s8v na0 = *(const s8v*)(kp);
        const s8v na1 = *(const s8v*)(kp + 16);
        const s8v nv00 = *(const s8v*)(vp);
        const s8v nv01 = *(const s8v*)(vp + 512);
        const s8v nv10 = *(const s8v*)(vp + 1024);
        const s8v nv11 = *(const s8v*)(vp + 1536);
        f32x16 s = {};
        s = MFMA(a0, bQ0, s);
        s = MFMA(a1, bQ1, s);
        float p[16];
#pragma unroll
        for (int r = 0; r < 16; r += 2) {
            const float e0 = EXP2F(s[r]);
            const float e1 = EXP2F(s[r + 1]);
            rsa += e0; rsb += e1;
            p[r] = e0 * e0; p[r + 1] = e1 * e1;
        }
        const int L0 = cvtpk(p[0], p[1]),   L1 = cvtpk(p[2], p[3]);
        const int H0 = cvtpk(p[4], p[5]),   H1 = cvtpk(p[6], p[7]);
        const int L2 = cvtpk(p[8], p[9]),   L3 = cvtpk(p[10], p[11]);
        const int H2 = cvtpk(p[12], p[13]), H3 = cvtpk(p[14], p[15]);
        const i2v s0 = __builtin_amdgcn_permlane32_swap(L0, H0, false, false);
        const i2v s1 = __builtin_amdgcn_permlane32_swap(L1, H1, false, false);
        const i2v s2 = __builtin_amdgcn_permlane32_swap(L2, H2, false, false);
        const i2v s3 = __builtin_amdgcn_permlane32_swap(L3, H3, false, false);
        const s8v pa0 = mk_s8(s0[0], s1[0], s0[1], s1[1]);   // k = 0..15
        const s8v pa1 = mk_s8(s2[0], s3[0], s2[1], s3[1]);   // k = 16..31
        __builtin_amdgcn_s_setprio(1);
        t0 = MFMA(pa0, v00, t0);
        t0 = MFMA(pa1, v01, t0);
        t1 = MFMA(pa0, v10, t1);
        t1 = MFMA(pa1, v11, t1);
        __builtin_amdgcn_s_setprio(0);
        a0 = na0; a1 = na1;
        v00 = nv00; v01 = nv01; v10 = nv10; v11 = nv11;
    }
    float rsacc = rsa + rsb;
    rsacc += __shfl_xor(rsacc, 32);
    if (lane < 32) atomicAdd(&rs[hbase + n0 + lane], rsacc);
    // T stored bf16: pair d=(2j,2j+1) packed via lane-xor-1 exchange,
    // even lanes store one dword (row layout [n][DP] bf16, DP/2 dwords/row)
    unsigned int* Tw = (unsigned int*)T;
#pragma unroll
    for (int r = 0; r < 16; ++r) {
        const int n = n0 + (r & 3) + 8 * (r >> 2) + 4 * hi5;
        const float par0 = __shfl_xor(t0[r], 1);
        const float par1 = __shfl_xor(t1[r], 1);
        if (!(lr & 1)) {
            Tw[(size_t)(hbase + n) * (DP / 2) + (lr >> 1)] =
                (unsigned int)cvtpk(t0[r], par0);
            if (lr < 8)
                Tw[(size_t)(hbase + n) * (DP / 2) + 16 + (lr >> 1)] =
                    (unsigned int)cvtpk(t1[r], par1);
        }
    }
}

// ---------------------------------------------------------------------------
// f[h,c,d] = sum_n (vc[n,c]/rs[n]) * (T0'+T1'+T2')[n,d] per 64-row chunk.
// T partials are bf16. vc cols 32..37 = inline pos. grid (16, 75).
// ---------------------------------------------------------------------------
__global__ __launch_bounds__(256) void fgemm_kernel(
    const float* __restrict__ VCA, const float* __restrict__ rsA,
    const unsigned short* __restrict__ TA0, const unsigned short* __restrict__ TA1,
    const unsigned short* __restrict__ TA2, float* __restrict__ fA,
    const float* __restrict__ VCB, const float* __restrict__ rsB,
    const unsigned short* __restrict__ TB0, const unsigned short* __restrict__ TB1,
    const unsigned short* __restrict__ TB2, float* __restrict__ fB)
{
    const int sel = blockIdx.x >> 3;
    const float* VC = sel ? VCB : VCA;
    const float* rs = sel ? rsB : rsA;
    const unsigned short* Ta = sel ? TB0 : TA0;
    const unsigned short* Tb = sel ? TB1 : TA1;
    const unsigned short* Tc = sel ? TB2 : TA2;
    float* f = sel ? fB : fA;
    __shared__ __align__(16) float wvcl[64 * DP];
    __shared__ __align__(16) float tl[64 * DP];
    __shared__ float wl[64];
    const int h = blockIdx.x & 7, n0 = blockIdx.y * 64;
    const int t = threadIdx.x;
    if (t < 64) wl[t] = 1.0f / rs[(size_t)h * N_TOK + n0 + t];
    __syncthreads();
    const float* vcbase = VC + (size_t)(h * N_TOK + n0) * HD;
    const ushort4* ta4 = (const ushort4*)(Ta + (size_t)(h * N_TOK + n0) * DP);
    const ushort4* tb4 = (const ushort4*)(Tb + (size_t)(h * N_TOK + n0) * DP);
    const ushort4* tc4 = (const ushort4*)(Tc + (size_t)(h * N_TOK + n0) * DP);
    for (int e4 = t; e4 < 64 * DP / 4; e4 += 256) {
        const ushort4 a4 = ta4[e4];
        const ushort4 b4 = tb4[e4];
        const ushort4 c4 = tc4[e4];
        tl[e4 * 4 + 0] = bf2f(a4.x) + bf2f(b4.x) + bf2f(c4.x);
        tl[e4 * 4 + 1] = bf2f(a4.y) + bf2f(b4.y) + bf2f(c4.y);
        tl[e4 * 4 + 2] = bf2f(a4.z) + bf2f(b4.z) + bf2f(c4.z);
        tl[e4 * 4 + 3] = bf2f(a4.w) + bf2f(b4.w) + bf2f(c4.w);
    }
    for (int e = t; e < 64 * DP; e += 256) {
        const int row = e / DP, c = e - row * DP;
        float v;
        if (c < 32)      v = vcbase[row * HD + c];
        else if (c < 38) v = posv(n0 + row, c - 32);
        else             v = 0.0f;
        wvcl[e] = v * wl[row];
    }
    __syncthreads();
    for (int p = t; p < DD * DD; p += 256) {
        const int c = p / DD, d = p % DD;
        float s = 0.f;
#pragma unroll 8
        for (int n = 0; n < 64; ++n) s += wvcl[n * DP + c] * tl[n * DP + d];
        atomicAdd(&f[(size_t)(h * DD + c) * DP + d], s);
    }
}

// ---------------------------------------------------------------------------
// out[d,e] = sum_j f[j,d] * proj_w[e,j] + proj_b[e]. Both fundamentals:
// grid (38, 2); y=0 -> f1 -> out+DD*256, y=1 -> f2 -> out.
// ---------------------------------------------------------------------------
__global__ __launch_bounds__(256) void out_kernel(
    const float* __restrict__ f1, const float* __restrict__ f2,
    const float* __restrict__ pw, const float* __restrict__ pb,
    float* __restrict__ out)
{
    const int sel = blockIdx.y;
    const float* f = sel ? f2 : f1;
    float* dst = sel ? out : (out + DD * 256);
    __shared__ __align__(16) float flds[304];
    const int d = blockIdx.x, t = threadIdx.x;
    for (int j = t; j < 304; j += 256) flds[j] = f[(size_t)j * DP + d];
    __syncthreads();
    float acc = pb[t];
    const float* pwrow = pw + (size_t)t * 304;
#pragma unroll 4
    for (int j = 0; j < 304; j += 4) {
        const float4 p4 = *(const float4*)&pwrow[j];
        const float4 f4 = *(const float4*)&flds[j];
        acc += p4.x * f4.x + p4.y * f4.y + p4.z * f4.z + p4.w * f4.w;
    }
    dst[(size_t)d * 256 + t] = acc;
}

extern "C" void kernel_launch(void* const* d_in, const int* in_sizes, int n_in,
                              void* d_out, int out_size, void* d_ws, size_t ws_size,
                              hipStream_t stream)
{
    const float* x1 = (const float*)d_in[0];
    const float* x2 = (const float*)d_in[1];
    const float* qkv_w = (const float*)d_in[2];
    const float* proj_w = (const float*)d_in[3];
    const float* proj_b = (const float*)d_in[4];
    float* out = (float*)d_out;

    const size_t QSZ = (size_t)NH * N_TOK * HD;          // 1,228,800
    const size_t VSZ = (size_t)NH * N_TOK * DP;          // 1,536,000
    const size_t SSZ = (size_t)NH * N_TOK;               //    38,400
    const size_t FSZ = (size_t)NH * DD * DP;             //    12,160
    const size_t XSZ = (size_t)N_TOK * 256;              // 1,228,800
    const size_t WSZ = (size_t)768 * 256;                //   196,608
    const size_t VTSZ = (size_t)NH * NTILES * FRAG;      // 2,457,600

    // fp32 region
    float* vc1 = (float*)d_ws;          // [h][4800][32]
    float* vc2 = vc1 + QSZ;
    float* rs1 = vc2 + QSZ;   // zeroed region starts here
    float* cs1 = rs1 + SSZ;
    float* rs2 = cs1 + SSZ;
    float* cs2 = rs2 + SSZ;
    float* f1 = cs2 + SSZ;
    float* f2 = f1 + FSZ;     // zeroed region ends at f2 + FSZ
    // bf16 region -- ORDER MATTERS: unconditional prefetches overrun each
    // buffer by <= 1 tile into the next allocated buffer.
    unsigned short* xh1 = (unsigned short*)(f2 + FSZ);
    unsigned short* xh2 = xh1 + XSZ;
    unsigned short* wh = xh2 + XSZ;
    unsigned short* qb1 = wh + WSZ;
    unsigned short* kb1 = qb1 + QSZ;    // qb1 overrun -> kb1
    unsigned short* qb2 = kb1 + QSZ;    // kb1 overrun -> qb2
    unsigned short* kb2 = qb2 + QSZ;    // qb2 overrun -> kb2
    unsigned short* vf1 = kb2 + QSZ;    // kb2 overrun -> vf1
    unsigned short* vf2 = vf1 + VTSZ;   // vf1 overrun -> vf2
    unsigned short* T1a = vf2 + VTSZ;   // vf2 overrun -> T1a (values unused)
    unsigned short* T1b = T1a + VSZ;    // T partials (bf16), fully overwritten
    unsigned short* T1c = T1b + VSZ;
    unsigned short* T2a = T1c + VSZ;
    unsigned short* T2b = T2a + VSZ;
    unsigned short* T2c = T2b + VSZ;

    const int zn4 = (int)((4 * SSZ + 2 * FSZ) / 4);   // float4 count to zero

    frag_kernel<<<324 + 174, 256, 0, stream>>>(x1, xh1, x2, xh2, qkv_w, wh,
                                               rs1, zn4);

    qkv_mfma_kernel<<<dim3(75, 12, 2), 128, 0, stream>>>(
        xh1, qb1, kb1, vc1, xh2, qb2, kb2, vc2, wh);

    // fundamental_1 = f(q2, k1, vc1); fundamental_2 = f(q1, k2, vc2)
    cs_kernel<<<dim3(25, 5, 16), 192, 0, stream>>>(qb2, kb1, cs1,
                                                   qb1, kb2, cs2);
    vfrag_kernel<<<dim3(150, 16), 256, 0, stream>>>(vc1, cs1, vf1,
                                                    vc2, cs2, vf2);
    tprime_mfma_kernel<<<dim3(50, MCHUNK, 16), 192, 0, stream>>>(
        qb2, kb1, vf1, rs1, T1a, T1b, T1c,
        qb1, kb2, vf2, rs2, T2a, T2b, T2c);
    fgemm_kernel<<<dim3(16, 75), 256, 0, stream>>>(
        vc1, rs1, T1a, T1b, T1c, f1,
        vc2, rs2, T2a, T2b, T2c, f2);
    out_kernel<<<dim3(38, 2), 256, 0, stream>>>(f1, f2, proj_w, proj_b, out);
}

// Round 10
// 212.031 us; speedup vs baseline: 7.4406x; 1.0023x over previous
//
#include <hip/hip_runtime.h>
#include <stdint.h>
#include <math.h>

#define N_TOK 4800
#define NH 8
#define HD 32
#define DP 40          // T' padded leading dim (D=38 -> 40)
#define DD 38
#define NTILES 150     // 32-wide m tiles
#define MCHUNK 3       // m-chunks in tprime (50 tiles each)
#define FRAG 2048      // shorts per (h,mtile) V fragment: 4 blocks x 64 lanes x 8
#define SCALE 0.17677669529663687f            // 32^-0.5
#define QSCALE (0.17677669529663687f * 1.4426950408889634f)  // SCALE*log2(e)

typedef float f32x16 __attribute__((ext_vector_type(16)));
typedef float f32x2 __attribute__((ext_vector_type(2)));
typedef short s8v __attribute__((ext_vector_type(8)));
typedef int i2v __attribute__((ext_vector_type(2)));

#if __has_builtin(__builtin_amdgcn_exp2f)
#define EXP2F(x) __builtin_amdgcn_exp2f(x)
#else
#define EXP2F(x) exp2f(x)
#endif

__device__ __forceinline__ unsigned short f2bf(float x) {
    union { float f; uint32_t u; } v; v.f = x;
    uint32_t r = v.u + 0x7FFFu + ((v.u >> 16) & 1u);
    return (unsigned short)(r >> 16);
}
__device__ __forceinline__ float bf2f(unsigned short h) {
    union { uint32_t u; float f; } v; v.u = ((uint32_t)h) << 16;
    return v.f;
}
__device__ __forceinline__ int cvtpk(float lo, float hi) {
    int r;
    asm("v_cvt_pk_bf16_f32 %0, %1, %2" : "=v"(r) : "v"(lo), "v"(hi));
    return r;
}
__device__ __forceinline__ s8v mk_s8(int a, int b, int c, int d) {
    union { int i[4]; s8v s; } u;
    u.i[0] = a; u.i[1] = b; u.i[2] = c; u.i[3] = d;
    return u.s;
}
// positional encoding component idx (0..5) for token m
__device__ __forceinline__ float posv(int m, int idx) {
    const int rrow = m / 80, rcol = m % 80;
    const float y = -1.0f + (float)rrow * (2.0f / 59.0f);
    const float x = -1.0f + (float)rcol * (2.0f / 79.0f);
    const float p3 = y * (240.0f / 517.0f);
    const float p4 = x * (360.0f / 517.0f);
    if (idx == 0) return p3 * p3;
    if (idx == 1) return p4 * p4;
    if (idx == 2) return p3 * p4;
    if (idx == 3) return p3;
    if (idx == 4) return p4;
    return 1.0f;
}

// bijective XCD-aware remap, x-fastest within an XCD: blocks sharing (y,z)
// operand streams stay on one XCD. (total blocks % 8 == 0)
template<int NX, int NY, int NZ>
__device__ __forceinline__ void swzdec(int& x, int& y, int& z) {
    const int L = blockIdx.x + NX * (blockIdx.y + NY * blockIdx.z);
    constexpr int cpx = NX * NY * NZ / 8;
    const int s = (L & 7) * cpx + (L >> 3);
    x = s % NX;
    const int r = s / NX;
    y = r % NY;
    z = r / NY;
}
// variant: x-OUTER (y,z fastest) -- each XCD owns a contiguous x-range and
// sweeps all (y,z) for it. Used where x selects the big streamed operand.
template<int NX, int NY, int NZ>
__device__ __forceinline__ void swzdec_xo(int& x, int& y, int& z) {
    const int L = blockIdx.x + NX * (blockIdx.y + NY * blockIdx.z);
    constexpr int cpx = NX * NY * NZ / 8;
    const int s = (L & 7) * cpx + (L >> 3);
    x = s / (NY * NZ);
    const int r = s % (NY * NZ);
    y = r % NY;
    z = r / NY;
}

#define MFMA(a, b, c) __builtin_amdgcn_mfma_f32_32x32x16_bf16((a), (b), (c), 0, 0, 0)

// ---------------------------------------------------------------------------
// fp32 [R][256] -> fragment-major bf16: [tile][c(16)][lane(64)][8] so qkv MFMA
// loads are contiguous 1KiB wave-loads. x1 (150 tiles), x2 (150), w (24).
// Blocks >= 324 zero the accumulator region (replaces the memset dispatch).
// ---------------------------------------------------------------------------
__global__ __launch_bounds__(256) void frag_kernel(
    const float* __restrict__ x1, unsigned short* __restrict__ xh1,
    const float* __restrict__ x2, unsigned short* __restrict__ xh2,
    const float* __restrict__ w, unsigned short* __restrict__ wh,
    float* __restrict__ zbase, int zn4)
{
    int b = blockIdx.x;
    const int t = threadIdx.x;
    if (b >= 324) {
        const int i = (b - 324) * 256 + t;
        if (i < zn4) ((float4*)zbase)[i] = make_float4(0.f, 0.f, 0.f, 0.f);
        return;
    }
    const float* src; unsigned short* dh;
    if (b < 150)      { src = x1 + b * 8192; dh = xh1 + b * 8192; }
    else if (b < 300) { b -= 150; src = x2 + b * 8192; dh = xh2 + b * 8192; }
    else              { b -= 300; src = w + b * 8192; dh = wh + b * 8192; }
#pragma unroll
    for (int k = 0; k < 4; ++k) {
        const int f = k * 256 + t;            // 16B-chunk index, 1024 per tile
        const int c = f >> 6;
        const int rem = f & 63;
        const float* sp = src + (rem & 31) * 256 + c * 16 + (rem >> 5) * 8;
        const float4 a = *(const float4*)(sp);
        const float4 bb = *(const float4*)(sp + 4);
        const float vv[8] = {a.x, a.y, a.z, a.w, bb.x, bb.y, bb.z, bb.w};
        union { unsigned short s[8]; s8v v; } H;
#pragma unroll
        for (int j = 0; j < 8; ++j) H.s[j] = f2bf(vv[j]);
        *(s8v*)(dh + f * 8) = H.v;
    }
}

// ---------------------------------------------------------------------------
// QKV GEMM, plain bf16 MFMA on fragment-major inputs. Each wave: one x-tile
// (32 n) x 2 w-tiles (64 j). grid (75, 12, 2), x-outer XCD swizzle so each
// XCD reads its x-range once. Epilogue goes through a per-wave LDS transpose
// so all global writes are contiguous full-line regions (2KB bf16 / 4KB f32).
// ---------------------------------------------------------------------------
__global__ __launch_bounds__(128, 4) void qkv_mfma_kernel(
    const unsigned short* __restrict__ xhA, unsigned short* __restrict__ qbA,
    unsigned short* __restrict__ kbA, float* __restrict__ vcbA,
    const unsigned short* __restrict__ xhB, unsigned short* __restrict__ qbB,
    unsigned short* __restrict__ kbB, float* __restrict__ vcbB,
    const unsigned short* __restrict__ wh)
{
    __shared__ float tlbuf[2][32][33];
    int bx, by, bz;
    swzdec_xo<75, 12, 2>(bx, by, bz);
    const int sel = bz;
    const unsigned short* xh = sel ? xhB : xhA;
    unsigned short* qb = sel ? qbB : qbA;
    unsigned short* kb = sel ? kbB : kbA;
    float* vcb = sel ? vcbB : vcbA;
    const int lane = threadIdx.x & 63;
    const int wid = threadIdx.x >> 6;
    const int xtile = bx * 2 + wid;
    const unsigned short* xp = xh + (size_t)xtile * 8192 + lane * 8;
    const unsigned short* wp0 = wh + (size_t)(by * 2) * 8192 + lane * 8;
    const unsigned short* wp1 = wp0 + 8192;
    f32x16 acc0 = {}, acc1 = {};
#pragma unroll
    for (int c = 0; c < 16; ++c) {
        const s8v aH = *(const s8v*)(xp + c * 512);
        const s8v b0 = *(const s8v*)(wp0 + c * 512);
        const s8v b1 = *(const s8v*)(wp1 + c * 512);
        acc0 = MFMA(aH, b0, acc0);
        acc1 = MFMA(aH, b1, acc1);
    }
    const int lr = lane & 31, hi5 = lane >> 5;
    const int row = lane >> 1, ch = (lane & 1) * 16;
    float (*T)[33] = tlbuf[wid];
#pragma unroll
    for (int jj = 0; jj < 2; ++jj) {
        // stage this j-tile's C fragment into LDS (wave-private buffer;
        // compiler inserts the lgkmcnt waits for the ds write->read dep)
#pragma unroll
        for (int r = 0; r < 16; ++r) {
            const float v = jj ? acc1[r] : acc0[r];
            T[(r & 3) + 8 * (r >> 2) + 4 * hi5][lr] = v;
        }
        const int jt = by * 2 + jj, s = jt >> 3, h = jt & 7;
        const int n = xtile * 32 + row;
        if (s == 2) {
            float4* dst = (float4*)&vcb[(size_t)(h * N_TOK + n) * HD + ch];
#pragma unroll
            for (int k = 0; k < 4; ++k) {
                dst[k] = make_float4(T[row][ch + 4 * k + 0], T[row][ch + 4 * k + 1],
                                     T[row][ch + 4 * k + 2], T[row][ch + 4 * k + 3]);
            }
        } else {
            const float m = (s == 0) ? QSCALE : 1.0f;
            unsigned short* dst = (s == 0 ? qb : kb)
                                  + (size_t)(h * N_TOK + n) * HD + ch;
            union { unsigned short u[8]; s8v v; } o0, o1;
#pragma unroll
            for (int i = 0; i < 8; ++i) {
                o0.u[i] = f2bf(T[row][ch + i] * m);
                o1.u[i] = f2bf(T[row][ch + 8 + i] * m);
            }
            *(s8v*)dst = o0.v;
            *(s8v*)(dst + 8) = o1.v;
        }
    }
}

// ---------------------------------------------------------------------------
// Pass 1 (both fundamentals): S' = Q'.K^T via bf16 MFMA; cs[m] += sum_n 2^S'.
// Each wave owns TWO fixed K-tiles (64 m); packed f32 accumulate; 2-slot
// software pipeline (compute slot c, then refill slot c with tile it+2) for
// ~2-iteration load-latency cover. grid (25, 5, 16), XCD-swizzled, 192 thr.
// Overruns q buffer by <= 2 row-tiles -- layout pad rule covers it.
// ---------------------------------------------------------------------------
__global__ __launch_bounds__(192, 4) void cs_kernel(
    const unsigned short* __restrict__ qbA, const unsigned short* __restrict__ kbA,
    float* __restrict__ csA,
    const unsigned short* __restrict__ qbB, const unsigned short* __restrict__ kbB,
    float* __restrict__ csB)
{
    int bx, by, bz;
    swzdec<25, 5, 16>(bx, by, bz);
    const int sel = bz >> 3;
    const unsigned short* qb = sel ? qbB : qbA;
    const unsigned short* kb = sel ? kbB : kbA;
    float* cs = sel ? csB : csA;
    const int lane = threadIdx.x & 63;
    const int wid = threadIdx.x >> 6;
    const int h = bz & 7;
    const int m0 = bx * 192 + wid * 64;       // two 32-tiles: m0, m0+32
    const int lr = lane & 31, hi5 = lane >> 5;
    const int hbase = h * N_TOK;
    const unsigned short* kp = kb + (hbase + m0 + lr) * HD + 8 * hi5;
    const s8v bK0 = *(const s8v*)(kp);
    const s8v bK1 = *(const s8v*)(kp + 16);
    const s8v bK2 = *(const s8v*)(kp + 32 * HD);
    const s8v bK3 = *(const s8v*)(kp + 32 * HD + 16);
    const unsigned short* qp = qb + (hbase + by * 960 + lr) * HD + 8 * hi5;
    s8v qa0[2], qa1[2];
    qa0[0] = *(const s8v*)(qp);
    qa1[0] = *(const s8v*)(qp + 16);
    qp += 32 * HD;
    qa0[1] = *(const s8v*)(qp);
    qa1[1] = *(const s8v*)(qp + 16);
    qp += 32 * HD;
    f32x2 cA0 = {0.f, 0.f}, cA1 = {0.f, 0.f};
    f32x2 cB0 = {0.f, 0.f}, cB1 = {0.f, 0.f};
#pragma unroll 2
    for (int it = 0; it < 30; ++it) {
        const int c = it & 1;
        f32x16 accA = {}, accB = {};
        accA = MFMA(qa0[c], bK0, accA);
        accB = MFMA(qa0[c], bK2, accB);
        accA = MFMA(qa1[c], bK1, accA);
        accB = MFMA(qa1[c], bK3, accB);
#pragma unroll
        for (int k = 0; k < 8; ++k) {
            f32x2 eA, eB;
            eA.x = EXP2F(accA[2 * k]);
            eA.y = EXP2F(accA[2 * k + 1]);
            eB.x = EXP2F(accB[2 * k]);
            eB.y = EXP2F(accB[2 * k + 1]);
            if (k & 1) { cA1 += eA; cB1 += eB; }
            else       { cA0 += eA; cB0 += eB; }
        }
        // refill slot c with tile it+2 (unconditional; pad rule covers end)
        qa0[c] = *(const s8v*)(qp);
        qa1[c] = *(const s8v*)(qp + 16);
        qp += 32 * HD;
    }
    float cA = cA0.x + cA0.y + cA1.x + cA1.y;
    float cB = cB0.x + cB0.y + cB1.x + cB1.y;
    cA += __shfl_xor(cA, 32);
    cB += __shfl_xor(cB, 32);
    if (lane < 32) {
        atomicAdd(&cs[hbase + m0 + lane], cA);
        atomicAdd(&cs[hbase + m0 + 32 + lane], cB);
    }
}

// ---------------------------------------------------------------------------
// vc fp32 [h][4800][32] + inline pos + u=1/cs -> fragment-major bf16 vfrag
// [h][mtile][b][lane][8]. Both fundamentals: grid (150, 16), 256 threads.
// ---------------------------------------------------------------------------
__global__ __launch_bounds__(256) void vfrag_kernel(
    const float* __restrict__ vcA, const float* __restrict__ csA,
    unsigned short* __restrict__ vfA,
    const float* __restrict__ vcB, const float* __restrict__ csB,
    unsigned short* __restrict__ vfB)
{
    const int sel = blockIdx.y >> 3;
    const float* vc = sel ? vcB : vcA;
    const float* cs = sel ? csB : csA;
    unsigned short* vf = sel ? vfB : vfA;
    __shared__ float vl[32][33];
    __shared__ float ul[32];
    const int mt = blockIdx.x;
    const int h = blockIdx.y & 7;
    const int t = threadIdx.x;
    const int m0 = mt * 32;
    const float* vcbase = vc + (size_t)(h * N_TOK + m0) * HD;
    for (int e = t; e < 32 * HD; e += 256) vl[e >> 5][e & 31] = vcbase[e];
    if (t < 32) ul[t] = 1.0f / cs[(size_t)h * N_TOK + m0 + t];
    __syncthreads();
    const int b = t >> 6, lane = t & 63;
    const int hi5 = lane >> 5, lr = lane & 31;
    const int d = (b >> 1) * 32 + lr;       // 0..63 (>=38 zero pad)
    const int mb = (b & 1) * 16 + hi5 * 8;  // k-offset within tile
    union { unsigned short s[8]; s8v v; } pk;
#pragma unroll
    for (int j = 0; j < 8; ++j) {
        const int mo = mb + j;
        float v;
        if (d < 32)      v = vl[mo][d];
        else if (d < 38) v = posv(m0 + mo, d - 32);
        else             v = 0.0f;
        pk.s[j] = f2bf(v * ul[mo]);
    }
    *(s8v*)(vf + ((size_t)(h * NTILES + mt) * 4 + b) * 512 + lane * 8) = pk.v;
}

// ---------------------------------------------------------------------------
// Pass 2 (both fundamentals): S'^T = K.Q'^T; e = 2^S'; rs += e (packed f32);
// P' = e*e packed in-register (cvt_pk + permlane32_swap); T' += P'.vfrag via
// MFMA. 2-slot software pipeline: compute slot c, refill slot c with tile
// it+2 (~2-iter latency cover). 3-wave blocks share K/V streams via L1;
// 3 m-chunks with separate bf16 T partials (lane-pair packed plain stores).
// grid (50, 3, 16) XCD-swizzled, 192 thr. Overruns <= 2 tiles -- pad rule.
// ---------------------------------------------------------------------------
__global__ __launch_bounds__(192, 4) void tprime_mfma_kernel(
    const unsigned short* __restrict__ qbA, const unsigned short* __restrict__ kbA,
    const unsigned short* __restrict__ vfA, float* __restrict__ rsA,
    unsigned short* __restrict__ TA0, unsigned short* __restrict__ TA1,
    unsigned short* __restrict__ TA2,
    const unsigned short* __restrict__ qbB, const unsigned short* __restrict__ kbB,
    const unsigned short* __restrict__ vfB, float* __restrict__ rsB,
    unsigned short* __restrict__ TB0, unsigned short* __restrict__ TB1,
    unsigned short* __restrict__ TB2)
{
    int bx, by, bz;
    swzdec<50, MCHUNK, 16>(bx, by, bz);
    const int sel = bz >> 3;
    const unsigned short* qb = sel ? qbB : qbA;
    const unsigned short* kb = sel ? kbB : kbA;
    const unsigned short* vf = sel ? vfB : vfA;
    float* rs = sel ? rsB : rsA;
    unsigned short* T = sel ? (by == 0 ? TB0 : (by == 1 ? TB1 : TB2))
                            : (by == 0 ? TA0 : (by == 1 ? TA1 : TA2));
    const int lane = threadIdx.x & 63;
    const int wid = threadIdx.x >> 6;
    const int h = bz & 7;
    const int n0 = bx * 96 + wid * 32;
    const int lr = lane & 31, hi5 = lane >> 5;
    const int hbase = h * N_TOK;
    // Q as B operand (hoisted across the m-loop)
    const unsigned short* qp = qb + (hbase + n0 + lr) * HD + 8 * hi5;
    const s8v bQ0 = *(const s8v*)(qp);
    const s8v bQ1 = *(const s8v*)(qp + 16);
    f32x16 t0 = {}, t1 = {};
    const int mt0 = by * 50;
    const unsigned short* kp = kb + (hbase + mt0 * 32 + lr) * HD + 8 * hi5;
    const unsigned short* vp = vf + (size_t)(h * NTILES + mt0) * FRAG + lane * 8;
    s8v a0[2], a1[2], v00[2], v01[2], v10[2], v11[2];
#pragma unroll
    for (int j = 0; j < 2; ++j) {
        a0[j] = *(const s8v*)(kp);
        a1[j] = *(const s8v*)(kp + 16);
        v00[j] = *(const s8v*)(vp);
        v01[j] = *(const s8v*)(vp + 512);
        v10[j] = *(const s8v*)(vp + 1024);
        v11[j] = *(const s8v*)(vp + 1536);
        kp += 32 * HD;
        vp += FRAG;
    }
    f32x2 rsa = {0.f, 0.f}, rsb = {0.f, 0.f};
#pragma unroll 2
    for (int it = 0; it < 50; ++it) {
        const int c = it & 1;
        f32x16 s = {};
        s = MFMA(a0[c], bQ0, s);
        s = MFMA(a1[c], bQ1, s);
        f32x2 p2[8];
#pragma unroll
        for (int k = 0; k < 8; ++k) {
            f32x2 e2;
            e2.x = EXP2F(s[2 * k]);
            e2.y = EXP2F(s[2 * k + 1]);
            if (k & 1) rsb += e2; else rsa += e2;
            p2[k] = e2 * e2;
        }
        const int L0 = cvtpk(p2[0].x, p2[0].y), L1 = cvtpk(p2[1].x, p2[1].y);
        const int H0 = cvtpk(p2[2].x, p2[2].y), H1 = cvtpk(p2[3].x, p2[3].y);
        const int L2 = cvtpk(p2[4].x, p2[4].y), L3 = cvtpk(p2[5].x, p2[5].y);
        const int H2 = cvtpk(p2[6].x, p2[6].y), H3 = cvtpk(p2[7].x, p2[7].y);
        const i2v s0 = __builtin_amdgcn_permlane32_swap(L0, H0, false, false);
        const i2v s1 = __builtin_amdgcn_permlane32_swap(L1, H1, false, false);
        const i2v s2 = __builtin_amdgcn_permlane32_swap(L2, H2, false, false);
        const i2v s3 = __builtin_amdgcn_permlane32_swap(L3, H3, false, false);
        const s8v pa0 = mk_s8(s0[0], s1[0], s0[1], s1[1]);   // k = 0..15
        const s8v pa1 = mk_s8(s2[0], s3[0], s2[1], s3[1]);   // k = 16..31
        __builtin_amdgcn_s_setprio(1);
        t0 = MFMA(pa0, v00[c], t0);
        t0 = MFMA(pa1, v01[c], t0);
        t1 = MFMA(pa0, v10[c], t1);
        t1 = MFMA(pa1, v11[c], t1);
        __builtin_amdgcn_s_setprio(0);
        // refill slot c with tile it+2 (unconditional; pad rule covers end)
        a0[c] = *(const s8v*)(kp);
        a1[c] = *(const s8v*)(kp + 16);
        v00[c] = *(const s8v*)(vp);
        v01[c] = *(const s8v*)(vp + 512);
        v10[c] = *(const s8v*)(vp + 1024);
        v11[c] = *(const s8v*)(vp + 1536);
        kp += 32 * HD;
        vp += FRAG;
    }
    float rsacc = rsa.x + rsa.y + rsb.x + rsb.y;
    rsacc += __shfl_xor(rsacc, 32);
    if (lane < 32) atomicAdd(&rs[hbase + n0 + lane], rsacc);
    // T stored bf16: pair d=(2j,2j+1) packed via lane-xor-1 exchange,
    // even lanes store one dword (row layout [n][DP] bf16, DP/2 dwords/row)
    unsigned int* Tw = (unsigned int*)T;
#pragma unroll
    for (int r = 0; r < 16; ++r) {
        const int n = n0 + (r & 3) + 8 * (r >> 2) + 4 * hi5;
        const float par0 = __shfl_xor(t0[r], 1);
        const float par1 = __shfl_xor(t1[r], 1);
        if (!(lr & 1)) {
            Tw[(size_t)(hbase + n) * (DP / 2) + (lr >> 1)] =
                (unsigned int)cvtpk(t0[r], par0);
            if (lr < 8)
                Tw[(size_t)(hbase + n) * (DP / 2) + 16 + (lr >> 1)] =
                    (unsigned int)cvtpk(t1[r], par1);
        }
    }
}

// ---------------------------------------------------------------------------
// f[h,c,d] = sum_n (vc[n,c]/rs[n]) * (T0'+T1'+T2')[n,d] per 64-row chunk.
// T partials are bf16. vc cols 32..37 = inline pos. grid (16, 75).
// ---------------------------------------------------------------------------
__global__ __launch_bounds__(256) void fgemm_kernel(
    const float* __restrict__ VCA, const float* __restrict__ rsA,
    const unsigned short* __restrict__ TA0, const unsigned short* __restrict__ TA1,
    const unsigned short* __restrict__ TA2, float* __restrict__ fA,
    const float* __restrict__ VCB, const float* __restrict__ rsB,
    const unsigned short* __restrict__ TB0, const unsigned short* __restrict__ TB1,
    const unsigned short* __restrict__ TB2, float* __restrict__ fB)
{
    const int sel = blockIdx.x >> 3;
    const float* VC = sel ? VCB : VCA;
    const float* rs = sel ? rsB : rsA;
    const unsigned short* Ta = sel ? TB0 : TA0;
    const unsigned short* Tb = sel ? TB1 : TA1;
    const unsigned short* Tc = sel ? TB2 : TA2;
    float* f = sel ? fB : fA;
    __shared__ __align__(16) float wvcl[64 * DP];
    __shared__ __align__(16) float tl[64 * DP];
    __shared__ float wl[64];
    const int h = blockIdx.x & 7, n0 = blockIdx.y * 64;
    const int t = threadIdx.x;
    if (t < 64) wl[t] = 1.0f / rs[(size_t)h * N_TOK + n0 + t];
    __syncthreads();
    const float* vcbase = VC + (size_t)(h * N_TOK + n0) * HD;
    const ushort4* ta4 = (const ushort4*)(Ta + (size_t)(h * N_TOK + n0) * DP);
    const ushort4* tb4 = (const ushort4*)(Tb + (size_t)(h * N_TOK + n0) * DP);
    const ushort4* tc4 = (const ushort4*)(Tc + (size_t)(h * N_TOK + n0) * DP);
    for (int e4 = t; e4 < 64 * DP / 4; e4 += 256) {
        const ushort4 a4 = ta4[e4];
        const ushort4 b4 = tb4[e4];
        const ushort4 c4 = tc4[e4];
        tl[e4 * 4 + 0] = bf2f(a4.x) + bf2f(b4.x) + bf2f(c4.x);
        tl[e4 * 4 + 1] = bf2f(a4.y) + bf2f(b4.y) + bf2f(c4.y);
        tl[e4 * 4 + 2] = bf2f(a4.z) + bf2f(b4.z) + bf2f(c4.z);
        tl[e4 * 4 + 3] = bf2f(a4.w) + bf2f(b4.w) + bf2f(c4.w);
    }
    for (int e = t; e < 64 * DP; e += 256) {
        const int row = e / DP, c = e - row * DP;
        float v;
        if (c < 32)      v = vcbase[row * HD + c];
        else if (c < 38) v = posv(n0 + row, c - 32);
        else             v = 0.0f;
        wvcl[e] = v * wl[row];
    }
    __syncthreads();
    for (int p = t; p < DD * DD; p += 256) {
        const int c = p / DD, d = p % DD;
        float s = 0.f;
#pragma unroll 8
        for (int n = 0; n < 64; ++n) s += wvcl[n * DP + c] * tl[n * DP + d];
        atomicAdd(&f[(size_t)(h * DD + c) * DP + d], s);
    }
}

// ---------------------------------------------------------------------------
// out[d,e] = sum_j f[j,d] * proj_w[e,j] + proj_b[e]. Both fundamentals:
// grid (38, 2); y=0 -> f1 -> out+DD*256, y=1 -> f2 -> out.
// ---------------------------------------------------------------------------
__global__ __launch_bounds__(256) void out_kernel(
    const float* __restrict__ f1, const float* __restrict__ f2,
    const float* __restrict__ pw, const float* __restrict__ pb,
    float* __restrict__ out)
{
    const int sel = blockIdx.y;
    const float* f = sel ? f2 : f1;
    float* dst = sel ? out : (out + DD * 256);
    __shared__ __align__(16) float flds[304];
    const int d = blockIdx.x, t = threadIdx.x;
    for (int j = t; j < 304; j += 256) flds[j] = f[(size_t)j * DP + d];
    __syncthreads();
    float acc = pb[t];
    const float* pwrow = pw + (size_t)t * 304;
#pragma unroll 4
    for (int j = 0; j < 304; j += 4) {
        const float4 p4 = *(const float4*)&pwrow[j];
        const float4 f4 = *(const float4*)&flds[j];
        acc += p4.x * f4.x + p4.y * f4.y + p4.z * f4.z + p4.w * f4.w;
    }
    dst[(size_t)d * 256 + t] = acc;
}

extern "C" void kernel_launch(void* const* d_in, const int* in_sizes, int n_in,
                              void* d_out, int out_size, void* d_ws, size_t ws_size,
                              hipStream_t stream)
{
    const float* x1 = (const float*)d_in[0];
    const float* x2 = (const float*)d_in[1];
    const float* qkv_w = (const float*)d_in[2];
    const float* proj_w = (const float*)d_in[3];
    const float* proj_b = (const float*)d_in[4];
    float* out = (float*)d_out;

    const size_t QSZ = (size_t)NH * N_TOK * HD;          // 1,228,800
    const size_t VSZ = (size_t)NH * N_TOK * DP;          // 1,536,000
    const size_t SSZ = (size_t)NH * N_TOK;               //    38,400
    const size_t FSZ = (size_t)NH * DD * DP;             //    12,160
    const size_t XSZ = (size_t)N_TOK * 256;              // 1,228,800
    const size_t WSZ = (size_t)768 * 256;                //   196,608
    const size_t VTSZ = (size_t)NH * NTILES * FRAG;      // 2,457,600

    // fp32 region
    float* vc1 = (float*)d_ws;          // [h][4800][32]
    float* vc2 = vc1 + QSZ;
    float* rs1 = vc2 + QSZ;   // zeroed region starts here
    float* cs1 = rs1 + SSZ;
    float* rs2 = cs1 + SSZ;
    float* cs2 = rs2 + SSZ;
    float* f1 = cs2 + SSZ;
    float* f2 = f1 + FSZ;     // zeroed region ends at f2 + FSZ
    // bf16 region -- ORDER MATTERS: unconditional prefetches overrun each
    // buffer by <= 2 tiles into the next allocated buffer.
    unsigned short* xh1 = (unsigned short*)(f2 + FSZ);
    unsigned short* xh2 = xh1 + XSZ;
    unsigned short* wh = xh2 + XSZ;
    unsigned short* qb1 = wh + WSZ;
    unsigned short* kb1 = qb1 + QSZ;    // qb1 overrun -> kb1
    unsigned short* qb2 = kb1 + QSZ;    // kb1 overrun -> qb2
    unsigned short* kb2 = qb2 + QSZ;    // qb2 overrun -> kb2
    unsigned short* vf1 = kb2 + QSZ;    // kb2 overrun -> vf1
    unsigned short* vf2 = vf1 + VTSZ;   // vf1 overrun -> vf2
    unsigned short* T1a = vf2 + VTSZ;   // vf2 overrun -> T1a (values unused)
    unsigned short* T1b = T1a + VSZ;    // T partials (bf16), fully overwritten
    unsigned short* T1c = T1b + VSZ;
    unsigned short* T2a = T1c + VSZ;
    unsigned short* T2b = T2a + VSZ;
    unsigned short* T2c = T2b + VSZ;

    const int zn4 = (int)((4 * SSZ + 2 * FSZ) / 4);   // float4 count to zero

    frag_kernel<<<324 + 174, 256, 0, stream>>>(x1, xh1, x2, xh2, qkv_w, wh,
                                               rs1, zn4);

    qkv_mfma_kernel<<<dim3(75, 12, 2), 128, 0, stream>>>(
        xh1, qb1, kb1, vc1, xh2, qb2, kb2, vc2, wh);

    // fundamental_1 = f(q2, k1, vc1); fundamental_2 = f(q1, k2, vc2)
    cs_kernel<<<dim3(25, 5, 16), 192, 0, stream>>>(qb2, kb1, cs1,
                                                   qb1, kb2, cs2);
    vfrag_kernel<<<dim3(150, 16), 256, 0, stream>>>(vc1, cs1, vf1,
                                                    vc2, cs2, vf2);
    tprime_mfma_kernel<<<dim3(50, MCHUNK, 16), 192, 0, stream>>>(
        qb2, kb1, vf1, rs1, T1a, T1b, T1c,
        qb1, kb2, vf2, rs2, T2a, T2b, T2c);
    fgemm_kernel<<<dim3(16, 75), 256, 0, stream>>>(
        vc1, rs1, T1a, T1b, T1c, f1,
        vc2, rs2, T2a, T2b, T2c, f2);
    out_kernel<<<dim3(38, 2), 256, 0, stream>>>(f1, f2, proj_w, proj_b, out);
}